// Round 6
// baseline (3863.198 us; speedup 1.0000x reference)
//
#include <hip/hip_runtime.h>
#include <cstdint>
#include <cstddef>

#define DMODEL 512
#define NHEAD 8
#define HD 64

typedef _Float16 half8 __attribute__((ext_vector_type(8)));
typedef float f32x4 __attribute__((ext_vector_type(4)));

// ---------------------------------------------------------------- threefry
__device__ __forceinline__ uint32_t rotl32(uint32_t x, int r) {
  return (x << r) | (x >> (32 - r));
}

__device__ __forceinline__ void tf_block(uint32_t k0, uint32_t k1,
                                         uint32_t& x0, uint32_t& x1) {
  uint32_t ks0 = k0, ks1 = k1, ks2 = k0 ^ k1 ^ 0x1BD11BDAu;
  x0 += ks0; x1 += ks1;
  x0 += x1; x1 = rotl32(x1, 13); x1 ^= x0;
  x0 += x1; x1 = rotl32(x1, 15); x1 ^= x0;
  x0 += x1; x1 = rotl32(x1, 26); x1 ^= x0;
  x0 += x1; x1 = rotl32(x1, 6);  x1 ^= x0;
  x0 += ks1; x1 += ks2 + 1u;
  x0 += x1; x1 = rotl32(x1, 17); x1 ^= x0;
  x0 += x1; x1 = rotl32(x1, 29); x1 ^= x0;
  x0 += x1; x1 = rotl32(x1, 16); x1 ^= x0;
  x0 += x1; x1 = rotl32(x1, 24); x1 ^= x0;
  x0 += ks2; x1 += ks0 + 2u;
  x0 += x1; x1 = rotl32(x1, 13); x1 ^= x0;
  x0 += x1; x1 = rotl32(x1, 15); x1 ^= x0;
  x0 += x1; x1 = rotl32(x1, 26); x1 ^= x0;
  x0 += x1; x1 = rotl32(x1, 6);  x1 ^= x0;
  x0 += ks0; x1 += ks1 + 3u;
  x0 += x1; x1 = rotl32(x1, 17); x1 ^= x0;
  x0 += x1; x1 = rotl32(x1, 29); x1 ^= x0;
  x0 += x1; x1 = rotl32(x1, 16); x1 ^= x0;
  x0 += x1; x1 = rotl32(x1, 24); x1 ^= x0;
  x0 += ks1; x1 += ks2 + 4u;
  x0 += x1; x1 = rotl32(x1, 13); x1 ^= x0;
  x0 += x1; x1 = rotl32(x1, 15); x1 ^= x0;
  x0 += x1; x1 = rotl32(x1, 26); x1 ^= x0;
  x0 += x1; x1 = rotl32(x1, 6);  x1 ^= x0;
  x0 += ks2; x1 += ks0 + 5u;
}

__global__ void idx_kernel(int* __restrict__ idxb, int n, int layer, int mask) {
  int e = blockIdx.x * 256 + threadIdx.x;
  if (e >= n) return;
  uint32_t f0 = 0u, f1 = (uint32_t)layer;
  tf_block(0u, 42u, f0, f1);
  uint32_t s0 = 0u, s1 = 1u;
  tf_block(f0, f1, s0, s1);
  uint32_t x0 = 0u, x1 = (uint32_t)e;
  tf_block(s0, s1, x0, x1);
  uint32_t bits = x0 ^ x1;
  idxb[e] = (int)(bits & (uint32_t)mask);
}

// ---------------------------------------------------------------- fp16 hi/lo split helpers
__device__ __forceinline__ void f2hsplit(float v, unsigned short& h,
                                         unsigned short& l) {
  _Float16 hh = (_Float16)v;          // RNE
  float r = v - (float)hh;            // exact
  _Float16 ll = (_Float16)r;
  h = __builtin_bit_cast(unsigned short, hh);
  l = __builtin_bit_cast(unsigned short, ll);
}

__device__ __forceinline__ float gelu_f(float v) {
  return 0.5f * v * (1.0f + erff(v * 0.7071067811865476f));
}

// address-space cast helpers for global_load_lds
#define AS1G(p) ((const __attribute__((address_space(1))) void*)(size_t)(p))
#define AS3L(p) ((__attribute__((address_space(3))) void*)(unsigned)(size_t)(p))
#define GLD16(g, l) __builtin_amdgcn_global_load_lds(AS1G(g), AS3L(l), 16, 0, 0)

// ---------------------------------------------------------------- fp32 -> fp16 hi/lo conversion (weights)
__global__ __launch_bounds__(256) void cvt_kernel(const float* __restrict__ X,
                                                  unsigned short* __restrict__ H,
                                                  unsigned short* __restrict__ Lo,
                                                  int n8) {
  int i = blockIdx.x * 256 + threadIdx.x;
  if (i >= n8) return;
  const float4* xp = (const float4*)X + 2 * (size_t)i;
  float4 a = xp[0], b = xp[1];
  float v[8] = {a.x, a.y, a.z, a.w, b.x, b.y, b.z, b.w};
  unsigned hu[4], lu[4];
#pragma unroll
  for (int q = 0; q < 4; ++q) {
    unsigned short h0, l0, h1, l1;
    f2hsplit(v[2 * q], h0, l0);
    f2hsplit(v[2 * q + 1], h1, l1);
    hu[q] = (unsigned)h0 | ((unsigned)h1 << 16);
    lu[q] = (unsigned)l0 | ((unsigned)l1 << 16);
  }
  uint4 hv; hv.x = hu[0]; hv.y = hu[1]; hv.z = hu[2]; hv.w = hu[3];
  uint4 lv; lv.x = lu[0]; lv.y = lu[1]; lv.z = lu[2]; lv.w = lu[3];
  *(uint4*)(H + 8 * (size_t)i) = hv;
  *(uint4*)(Lo + 8 * (size_t)i) = lv;
}

// conv weight pack + split: wp[o][w*512+c] = dw[o][c][w]
__global__ void packw2_kernel(const float* __restrict__ dw,
                              unsigned short* __restrict__ Hh,
                              unsigned short* __restrict__ Hl) {
  int gid = blockIdx.x * 256 + threadIdx.x;  // 512*1536
  int o = gid / 1536;
  int kk = gid - o * 1536;
  int ww = kk / 512;
  int c = kk - ww * 512;
  float v = dw[((size_t)o * 512 + c) * 3 + ww];
  unsigned short h, l;
  f2hsplit(v, h, l);
  Hh[gid] = h;
  Hl[gid] = l;
}

// ---------------------------------------------------------------- MFMA GEMM 128x128, split-fp16 3-product, BK=32
// LDS 32 KB -> 5 blocks/CU (160 KiB exactly). Row = 64 B (4x16B slots).
// Swizzle: slot ^= (row>>1)&3 (conflict-free; r3's row&3 was 4-way — r4 fix,
// SQ_LDS_BANK_CONFLICT 6.3M -> 0 measured). Source pre-swizzled for linear
// global_load_lds dest (rule #21); reads apply same XOR.
// PART: K-split partials (raw fp32, no bias/act) -> C + kb*M*N.
template <int ACT, int HASR, int CONV, int F16OUT, int QKV, int PART>
__global__ __launch_bounds__(256, 5) void gemm_mfma(
    const unsigned short* __restrict__ Ah, const unsigned short* __restrict__ Al,
    const unsigned short* __restrict__ Wh, const unsigned short* __restrict__ Wl,
    const float* __restrict__ bias, const float* __restrict__ bias2,
    const float* __restrict__ bias3, const float* __restrict__ Rres,
    float* __restrict__ C, float* __restrict__ C2, float* __restrict__ C3,
    unsigned short* __restrict__ Ch, unsigned short* __restrict__ Cl,
    int N, int K, int Lmask, int ntx, int nty, int kloop) {
  __shared__ __attribute__((aligned(16))) unsigned short AsH[4096];
  __shared__ __attribute__((aligned(16))) unsigned short AsL[4096];
  __shared__ __attribute__((aligned(16))) unsigned short WsH[4096];
  __shared__ __attribute__((aligned(16))) unsigned short WsL[4096];
  const int tid = threadIdx.x;
  int blk = blockIdx.x;
  int kb = 0;
  if (PART) {
    const int tiles = ntx * nty;
    kb = blk / tiles;
    blk -= kb * tiles;
  }
  const int koff = PART ? kb * kloop : 0;
  const int xcd = blk & 7;
  const int j = blk >> 3;
  const int jr = j / ntx;
  const int row_t = xcd * (nty >> 3) + jr;
  const int col_t = j - jr * ntx;
  const int row0 = row_t << 7, col0 = col_t << 7;
  const int lane = tid & 63;
  const int wv = tid >> 6;
  const int wr = wv >> 1, wc = wv & 1;  // wave's 64x64 quadrant
  const int srow = lane >> 2;                          // 0..15
  const int skoff = (((lane & 3) ^ ((lane >> 3) & 3)) << 3);
  const int l15 = lane & 15, lg = lane >> 4;
  const int slotx = ((lg ^ ((l15 >> 1) & 3)) << 4);
  int oa[4], ow[4];
#pragma unroll
  for (int t = 0; t < 4; ++t) {
    oa[t] = (((wr << 6) + (t << 4) + l15) << 6) + slotx;
    ow[t] = (((wc << 6) + (t << 4) + l15) << 6) + slotx;
  }
  f32x4 acc[4][4] = {};
  const int T = (PART ? kloop : K) >> 5;
  for (int it = 0; it < T; ++it) {
    const int k0 = koff + (it << 5);
    int wwin = 0, kc = k0;
    if (CONV) { wwin = k0 >> 9; kc = k0 & 511; }
#pragma unroll
    for (int g = 0; g < 2; ++g) {
      const int R0 = (wv << 5) + (g << 4);
      const int rr = R0 + srow;
      size_t aoff;
      if (CONV) {
        int t0 = row0 + rr;
        int tcv = t0 & Lmask, bb = t0 & ~Lmask;
        int src = bb | ((tcv - 1 + wwin) & Lmask);
        aoff = (size_t)src * 512 + (kc + skoff);
      } else {
        aoff = (size_t)(row0 + rr) * K + (k0 + skoff);
      }
      size_t woff = (size_t)(col0 + rr) * K + (k0 + skoff);
      GLD16(Ah + aoff, AsH + R0 * 32);
      GLD16(Al + aoff, AsL + R0 * 32);
      GLD16(Wh + woff, WsH + R0 * 32);
      GLD16(Wl + woff, WsL + R0 * 32);
    }
    __syncthreads();
    half8 fah[4], fal[4];
#pragma unroll
    for (int t = 0; t < 4; ++t) {
      fah[t] = *(const half8*)((const char*)AsH + oa[t]);
      fal[t] = *(const half8*)((const char*)AsL + oa[t]);
    }
#pragma unroll
    for (int ni = 0; ni < 4; ++ni) {
      half8 bh = *(const half8*)((const char*)WsH + ow[ni]);
      half8 bl = *(const half8*)((const char*)WsL + ow[ni]);
#pragma unroll
      for (int mi = 0; mi < 4; ++mi) {
        acc[mi][ni] = __builtin_amdgcn_mfma_f32_16x16x32_f16(
            fah[mi], bh, acc[mi][ni], 0, 0, 0);
        acc[mi][ni] = __builtin_amdgcn_mfma_f32_16x16x32_f16(
            fah[mi], bl, acc[mi][ni], 0, 0, 0);
        acc[mi][ni] = __builtin_amdgcn_mfma_f32_16x16x32_f16(
            fal[mi], bh, acc[mi][ni], 0, 0, 0);
      }
    }
    __syncthreads();
  }
  // epilogue: D lane mapping col=l15, row=lg*4+q
  if (PART) {
    float* Cp = C + (size_t)kb * ((size_t)(nty << 7)) * N;
#pragma unroll
    for (int mi = 0; mi < 4; ++mi)
#pragma unroll
      for (int q = 0; q < 4; ++q) {
        const int m = row0 + (wr << 6) + (mi << 4) + (lg << 2) + q;
#pragma unroll
        for (int ni = 0; ni < 4; ++ni) {
          const int col = col0 + (wc << 6) + (ni << 4) + l15;
          Cp[(size_t)m * N + col] = acc[mi][ni][q];
        }
      }
    return;
  }
  int cbase = col0;
  float* Cb = C;
  const float* bb = bias;
  if (QKV) {
    const int cb = col0 >> 9;
    cbase = col0 & 511;
    Cb = (cb == 0) ? C : ((cb == 1) ? C2 : C3);
    bb = (cb == 0) ? bias : ((cb == 1) ? bias2 : bias3);
  }
  const int OSTR = QKV ? 512 : N;
  float bsv[4];
#pragma unroll
  for (int ni = 0; ni < 4; ++ni)
    bsv[ni] = bb[cbase + (wc << 6) + (ni << 4) + l15];
#pragma unroll
  for (int mi = 0; mi < 4; ++mi) {
#pragma unroll
    for (int q = 0; q < 4; ++q) {
      const int m = row0 + (wr << 6) + (mi << 4) + (lg << 2) + q;
#pragma unroll
      for (int ni = 0; ni < 4; ++ni) {
        const int col = cbase + (wc << 6) + (ni << 4) + l15;
        float v = acc[mi][ni][q] + bsv[ni];
        if (HASR) v += Rres[(size_t)m * OSTR + col];
        if (ACT == 1) v = gelu_f(v);
        if (F16OUT) {
          unsigned short h, lo;
          f2hsplit(v, h, lo);
          Ch[(size_t)m * OSTR + col] = h;
          Cl[(size_t)m * OSTR + col] = lo;
        } else {
          Cb[(size_t)m * OSTR + col] = v;
        }
      }
    }
  }
}

// ---------------------------------------------------------------- fp32 GEMM (fallback path only)
template <int ACT, int HASR, int CONV, int PART>
__global__ __launch_bounds__(256, 2) void gemm128(
    const float* __restrict__ A, const float* __restrict__ W,
    const float* __restrict__ bias, const float* Rres, float* C,
    int N, int K, int Lmask, int ntx, int nty, int kloop, int ks) {
  __shared__ float As[16][140];
  __shared__ float Ws[16][140];
  const int tid = threadIdx.x;
  int blk = blockIdx.x;
  const int tiles = ntx * nty;
  int kb = 0;
  if (PART) { kb = blk / tiles; blk -= kb * tiles; }
  const int koff = kb * kloop;
  const int xcd = blk & 7;
  const int j = blk >> 3;
  const int jr = j / ntx;
  const int row_t = xcd * (nty >> 3) + jr;
  const int col_t = j - jr * ntx;
  const int row0 = row_t * 128, col0 = col_t * 128;

  const int ar = tid >> 1;
  const int ac = (tid & 1) << 3;
  const int arp = ar + ((ar >> 5) << 2);
  const int tx = tid & 15, ty = tid >> 4;
  const int wcol = tx * 8 + ((tx >> 2) << 2);
  const int acol = ty * 8 + ((ty >> 2) << 2);
  const int arow = row0 + ar;
  const float* Wp = W + (size_t)(col0 + ar) * K + koff + ac;
  const float* Ap = A + (size_t)arow * K + koff + ac;
  int tcv = 0, bbase = 0;
  if (CONV) { tcv = arow & Lmask; bbase = arow & ~Lmask; }
  float4 ra0, ra1, rw0, rw1;
  float acc[8][8] = {};
  const int T = kloop >> 4;

  {
    const float* ap;
    if (CONV) {
      int kabs = koff;
      int w = kabs >> 9;
      int src = bbase | ((tcv - 1 + w) & Lmask);
      ap = A + (size_t)src * 512 + (kabs & 511) + ac;
    } else {
      ap = Ap;
    }
    ra0 = *(const float4*)(ap);
    ra1 = *(const float4*)(ap + 4);
    rw0 = *(const float4*)(Wp);
    rw1 = *(const float4*)(Wp + 4);
  }

  for (int it = 0; it < T; ++it) {
#pragma unroll
    for (int q = 0; q < 4; q++) {
      As[ac + q][arp] = ((float*)&ra0)[q];
      As[ac + 4 + q][arp] = ((float*)&ra1)[q];
      Ws[ac + q][arp] = ((float*)&rw0)[q];
      Ws[ac + 4 + q][arp] = ((float*)&rw1)[q];
    }
    __syncthreads();
    if (it + 1 < T) {
      const int k0 = (it + 1) << 4;
      const float* ap;
      if (CONV) {
        int kabs = koff + k0;
        int w = kabs >> 9;
        int src = bbase | ((tcv - 1 + w) & Lmask);
        ap = A + (size_t)src * 512 + (kabs & 511) + ac;
      } else {
        ap = Ap + k0;
      }
      ra0 = *(const float4*)(ap);
      ra1 = *(const float4*)(ap + 4);
      rw0 = *(const float4*)(Wp + k0);
      rw1 = *(const float4*)(Wp + k0 + 4);
    }
#pragma unroll
    for (int k = 0; k < 16; k++) {
      float av[8], wvv[8];
      *(float4*)(av) = *(const float4*)&As[k][acol];
      *(float4*)(av + 4) = *(const float4*)&As[k][acol + 4];
      *(float4*)(wvv) = *(const float4*)&Ws[k][wcol];
      *(float4*)(wvv + 4) = *(const float4*)&Ws[k][wcol + 4];
#pragma unroll
      for (int i = 0; i < 8; i++)
#pragma unroll
        for (int q = 0; q < 8; q++) acc[i][q] += av[i] * wvv[q];
    }
    __syncthreads();
  }

  if (PART) {
    float* Cp = C + (size_t)kb * (nty << 7) * N;
#pragma unroll
    for (int i = 0; i < 8; i++) {
      const int m = row0 + ty * 8 + i;
      const int c0 = col0 + tx * 8;
      *(float4*)(Cp + (size_t)m * N + c0) = *(float4*)(&acc[i][0]);
      *(float4*)(Cp + (size_t)m * N + c0 + 4) = *(float4*)(&acc[i][4]);
    }
  } else {
#pragma unroll
    for (int i = 0; i < 8; i++) {
      const int m = row0 + ty * 8 + i;
      const int c0 = col0 + tx * 8;
      float vout[8];
#pragma unroll
      for (int q = 0; q < 8; q++) {
        float v = acc[i][q] + bias[c0 + q];
        if (HASR) v += Rres[(size_t)m * N + c0 + q];
        if (ACT == 1) v = gelu_f(v);
        vout[q] = v;
      }
      *(float4*)(C + (size_t)m * N + c0) = *(float4*)(vout);
      *(float4*)(C + (size_t)m * N + c0 + 4) = *(float4*)(vout + 4);
    }
  }
}

template <int HASR>
__global__ __launch_bounds__(256) void combine_kernel(
    const float* __restrict__ part, const float* __restrict__ bias,
    const float* Rres, float* __restrict__ Cout, size_t MN, int ks) {
  size_t gid = (size_t)blockIdx.x * 256 + threadIdx.x;
  int c = (int)(gid & 511);
  float v = 0.f;
  for (int kb = 0; kb < ks; kb++) v += part[kb * MN + gid];
  v += bias[c];
  if (HASR) v += Rres[gid];
  Cout[gid] = v;
}

// ---------------------------------------------------------------- token conv + pos embed (+hi/lo)
template <int EMIT>
__global__ void tokpe_kernel(const float* __restrict__ xe,
                             const float* __restrict__ w,
                             float* __restrict__ out,
                             unsigned short* __restrict__ Hh,
                             unsigned short* __restrict__ Hl, int S) {
  int gid = blockIdx.x * 256 + threadIdx.x;  // B*S*512
  int o = gid & 511;
  int bt = gid >> 9;
  int t = bt % S, b = bt / S;
  float acc = 0.f;
#pragma unroll
  for (int ww = 0; ww < 3; ww++) {
    int tt = t - 1 + ww;
    tt = (tt < 0) ? tt + S : (tt >= S ? tt - S : tt);
    const float* xr = xe + ((size_t)(b * S + tt)) * 7;
#pragma unroll
    for (int i = 0; i < 7; i++) acc += xr[i] * w[o * 21 + i * 3 + ww];
  }
  int i2 = o >> 1;
  float dv = expf((float)(2 * i2) * (-9.210340371976184f / 512.0f));
  float ang = (float)t * dv;
  acc += (o & 1) ? cosf(ang) : sinf(ang);
  out[gid] = acc;
  if (EMIT) {
    unsigned short h, l;
    f2hsplit(acc, h, l);
    Hh[gid] = h;
    Hl[gid] = l;
  }
}

// ---------------------------------------------------------------- conv weight pack (fallback fp32)
__global__ void packw_kernel(const float* __restrict__ dw, float* __restrict__ wp) {
  int gid = blockIdx.x * 256 + threadIdx.x;  // 512*1536
  int o = gid / 1536;
  int kk = gid - o * 1536;
  int ww = kk / 512;
  int c = kk - ww * 512;
  wp[gid] = dw[((size_t)o * 512 + c) * 3 + ww];
}

// ---------------------------------------------------------------- M score, 4 lanes per query
__global__ __launch_bounds__(256) void mscore4_kernel(
    const float* __restrict__ Q, const float* __restrict__ Kb,
    const int* __restrict__ idxb, float* __restrict__ Mout, int L, int U) {
  __shared__ int sidx[64 * 24];
  int i = blockIdx.x;  // b + 8*(h*chunks + c), 64 queries per block
  int b = i & 7;
  int j = i >> 3;
  int chunks = L >> 6;
  int h = j / chunks;
  int c = j - h * chunks;
  int t0 = c << 6;
  int tid = threadIdx.x;
  const int nidx = 64 * U;
  for (int k = tid; k < nidx; k += 256) sidx[k] = idxb[t0 * U + k];
  __syncthreads();
  int tsub = tid >> 2, sub = tid & 3;
  int t = t0 + tsub;
  const float4* qr =
      (const float4*)(Q + ((size_t)(b * L + t)) * DMODEL + h * HD + sub * 16);
  float4 q0 = qr[0], q1 = qr[1], q2 = qr[2], q3 = qr[3];
  const float* Kh = Kb + (size_t)b * L * DMODEL + h * HD + sub * 16;
  float mx = -3.4e38f, sm = 0.f;
  int krn = sidx[tsub * U];
  for (int jj = 0; jj < U; ++jj) {
    const float4* kp = (const float4*)(Kh + (size_t)krn * DMODEL);
    krn = sidx[tsub * U + ((jj + 1 < U) ? jj + 1 : jj)];
    float4 k0 = kp[0], k1 = kp[1], k2 = kp[2], k3 = kp[3];
    float dot = q0.x * k0.x + q0.y * k0.y + q0.z * k0.z + q0.w * k0.w +
                q1.x * k1.x + q1.y * k1.y + q1.z * k1.z + q1.w * k1.w +
                q2.x * k2.x + q2.y * k2.y + q2.z * k2.z + q2.w * k2.w +
                q3.x * k3.x + q3.y * k3.y + q3.z * k3.z + q3.w * k3.w;
    dot += __shfl_xor(dot, 1);
    dot += __shfl_xor(dot, 2);
    mx = fmaxf(mx, dot);
    sm += dot;
  }
  if (sub == 0) Mout[(size_t)(b * 8 + h) * L + t] = mx - sm / (float)L;
}

// ---------------------------------------------------------------- M score (fallback)
__global__ __launch_bounds__(256) void mscore_kernel(
    const float* __restrict__ Q, const float* __restrict__ Kb,
    const int* __restrict__ idxb, float* __restrict__ Mout, int L, int U) {
  int i = blockIdx.x;
  int b = i & 7;
  int j = i >> 3;
  int chunks = L >> 8;
  int h = j / chunks;
  int c = j - h * chunks;
  int t = c * 256 + threadIdx.x;
  const float4* qr = (const float4*)(Q + ((size_t)(b * L + t)) * DMODEL + h * HD);
  float4 qv[16];
#pragma unroll
  for (int ii = 0; ii < 16; ii++) qv[ii] = qr[ii];
  float mx = -3.4e38f, sm = 0.f;
  for (int jj = 0; jj < U; jj++) {
    int kr = idxb[t * U + jj];
    const float4* kp =
        (const float4*)(Kb + ((size_t)(b * L + kr)) * DMODEL + h * HD);
    float dot = 0.f;
#pragma unroll
    for (int ii = 0; ii < 16; ii++) {
      float4 kv = kp[ii];
      dot += qv[ii].x * kv.x + qv[ii].y * kv.y + qv[ii].z * kv.z + qv[ii].w * kv.w;
    }
    mx = fmaxf(mx, dot);
    sm += dot;
  }
  Mout[(size_t)(b * 8 + h) * L + t] = mx - sm / (float)L;
}

// ---------------------------------------------------------------- top-k
__global__ __launch_bounds__(256) void topk_kernel(const float* __restrict__ Mv,
                                                   int* __restrict__ topb, int L,
                                                   int u) {
  __shared__ float wv_s[4];
  __shared__ int wi_s[4];
  __shared__ int best_s;
  int bh = blockIdx.x, tid = threadIdx.x;
  int lane = tid & 63, w = tid >> 6;
  int cnt = L >> 8;
  float lv[8];
  for (int i = 0; i < cnt; i++) lv[i] = Mv[(size_t)bh * L + i * 256 + tid];
  for (int r = 0; r < u; r++) {
    float bv = -3.4e38f;
    int bi = 0x7fffffff;
    for (int i = 0; i < cnt; i++) {
      if (lv[i] > bv) { bv = lv[i]; bi = i * 256 + tid; }
    }
    for (int s = 32; s > 0; s >>= 1) {
      float ov = __shfl_down(bv, s);
      int oi = __shfl_down(bi, s);
      if (ov > bv || (ov == bv && oi < bi)) { bv = ov; bi = oi; }
    }
    if (lane == 0) { wv_s[w] = bv; wi_s[w] = bi; }
    __syncthreads();
    if (tid == 0) {
      float fv = wv_s[0];
      int fi = wi_s[0];
      for (int q = 1; q < 4; q++) {
        if (wv_s[q] > fv || (wv_s[q] == fv && wi_s[q] < fi)) {
          fv = wv_s[q];
          fi = wi_s[q];
        }
      }
      best_s = fi;
      topb[bh * u + r] = fi;
    }
    __syncthreads();
    int win = best_s;
    if ((win & 255) == tid) lv[win >> 8] = -3.4e38f;
  }
}

// ---------------------------------------------------------------- gather selected q rows
__global__ void gatherq_kernel(const float* __restrict__ Q,
                               const int* __restrict__ topb,
                               float* __restrict__ qsel, int L, int u) {
  int i = blockIdx.x;
  int bh = i / u;
  int b = bh >> 3, h = bh & 7;
  int t = topb[i];
  qsel[i * HD + threadIdx.x] =
      Q[((size_t)(b * L + t)) * DMODEL + h * HD + threadIdx.x];
}

// ---------------------------------------------------------------- mean of x rows per batch
__global__ __launch_bounds__(256) void xmean_kernel(const float* __restrict__ x,
                                                    float* __restrict__ psumx,
                                                    int L) {
  int i = blockIdx.x;
  int b = i >> 3, g = i & 7;
  int rows = L >> 3;
  int tid = threadIdx.x;
  const float* base = x + ((size_t)b * L + (size_t)g * rows) * DMODEL;
  float s0 = 0.f, s1 = 0.f;
  for (int t = 0; t < rows; t++) {
    s0 += base[(size_t)t * DMODEL + tid];
    s1 += base[(size_t)t * DMODEL + tid + 256];
  }
  psumx[i * DMODEL + tid] = s0;
  psumx[i * DMODEL + tid + 256] = s1;
}

__global__ __launch_bounds__(256) void mvmake_kernel(
    const float* __restrict__ psumx, const float* __restrict__ Wv,
    const float* __restrict__ bv, const float* __restrict__ Wo,
    const float* __restrict__ bo, float* __restrict__ mvg,
    float* __restrict__ mvWog, int L) {
  __shared__ float xm[512];
  __shared__ float mvs[512];
  int b = blockIdx.x, tid = threadIdx.x;
  float inv = 1.0f / (float)L;
  for (int nn = 0; nn < 2; nn++) {
    int c = tid + nn * 256;
    float s = 0.f;
    for (int g = 0; g < 8; g++) s += psumx[(b * 8 + g) * DMODEL + c];
    xm[c] = s * inv;
  }
  __syncthreads();
  for (int nn = 0; nn < 2; nn++) {
    int n = tid + nn * 256;
    const float* wr = Wv + (size_t)n * 512;
    float s = bv[n];
    for (int k = 0; k < 512; k += 4) {
      float4 w4 = *(const float4*)(wr + k);
      s += xm[k] * w4.x + xm[k + 1] * w4.y + xm[k + 2] * w4.z + xm[k + 3] * w4.w;
    }
    mvs[n] = s;
    mvg[b * DMODEL + n] = s;
  }
  __syncthreads();
  for (int nn = 0; nn < 2; nn++) {
    int n = tid + nn * 256;
    const float* wr = Wo + (size_t)n * 512;
    float s = bo[n];
    for (int k = 0; k < 512; k += 4) {
      float4 w4 = *(const float4*)(wr + k);
      s += mvs[k] * w4.x + mvs[k + 1] * w4.y + mvs[k + 2] * w4.z +
           mvs[k + 3] * w4.w;
    }
    mvWog[b * DMODEL + n] = s;
  }
}

__global__ void x1bcast_kernel(const float* __restrict__ x,
                               const float* __restrict__ mvWog,
                               float* __restrict__ x1, int L) {
  int gid = blockIdx.x * 256 + threadIdx.x;
  int c = gid & 511;
  int r = gid >> 9;
  int b = r / L;
  x1[gid] = x[gid] + mvWog[b * DMODEL + c];
}

// ---------------------------------------------------------------- chunked flash attention for selected rows
__global__ __launch_bounds__(256) void attnflash_kernel(
    const float* __restrict__ qsel, const float* __restrict__ Kb,
    const float* __restrict__ Vb, float* __restrict__ pm,
    float* __restrict__ pl, float* __restrict__ pO, int L, int u, int nchunk) {
  __shared__ float qs[24][64];
  __shared__ float Kt[64][68];
  __shared__ float Ps[24][68];
  int blk = blockIdx.x;
  int bh = blk / nchunk;
  int c = blk - bh * nchunk;
  int b = bh >> 3, h = bh & 7;
  int cs = L / nchunk;
  int tid = threadIdx.x;
  int lane = tid & 63;
  int w = tid >> 6;
  for (int i = tid; i < u * 64; i += 256)
    qs[i >> 6][i & 63] = qsel[(size_t)bh * u * 64 + i];
  float m[6], l[6], O[6];
#pragma unroll
  for (int k = 0; k < 6; k++) { m[k] = -3.4e38f; l[k] = 0.f; O[k] = 0.f; }
  const float* Kbase = Kb + (size_t)b * L * DMODEL + h * HD;
  const float* Vbase = Vb + (size_t)b * L * DMODEL + h * HD;
  const int jrow = tid & 63;
  const int dch = (tid >> 6) << 4;
  for (int j0 = c * cs; j0 < (c + 1) * cs; j0 += 64) {
    __syncthreads();
    const float* kr = Kbase + (size_t)(j0 + jrow) * DMODEL + dch;
    float4 k0 = *(const float4*)(kr);
    float4 k1 = *(const float4*)(kr + 4);
    float4 k2 = *(const float4*)(kr + 8);
    float4 k3 = *(const float4*)(kr + 12);
#pragma unroll
    for (int q = 0; q < 4; q++) {
      Kt[dch + q][jrow] = ((float*)&k0)[q];
      Kt[dch + 4 + q][jrow] = ((float*)&k1)[q];
      Kt[dch + 8 + q][jrow] = ((float*)&k2)[q];
      Kt[dch + 12 + q][jrow] = ((float*)&k3)[q];
    }
    __syncthreads();
#pragma unroll
    for (int k = 0; k < 6; k++) {
      int qi = 4 * k + w;
      if (qi >= u) break;
      float s = 0.f;
#pragma unroll
      for (int d = 0; d < 64; d++) s += qs[qi][d] * Kt[d][lane];
      s *= 0.125f;
      float mx = s;
#pragma unroll
      for (int off = 32; off > 0; off >>= 1)
        mx = fmaxf(mx, __shfl_down(mx, off));
      mx = __shfl(mx, 0);
      float mnew = fmaxf(m[k], mx);
      float p = expf(s - mnew);
      float ps = p;
#pragma unroll
      for (int off = 32; off > 0; off >>= 1) ps += __shfl_down(ps, off);
      ps = __shfl(ps, 0);
      float alpha = expf(m[k] - mnew);
      l[k] = l[k] * alpha + ps;
      m[k] = mnew;
      O[k] *= alpha;
      Ps[qi][lane] = p;
    }
    for (int jj = 0; jj < 64; jj += 4) {
      float v0 = Vbase[(size_t)(j0 + jj) * DMODEL + lane];
      float v1 = Vbase[(size_t)(j0 + jj + 1) * DMODEL + lane];
      float v2 = Vbase[(size_t)(j0 + jj + 2) * DMODEL + lane];
      float v3 = Vbase[(size_t)(j0 + jj + 3) * DMODEL + lane];
#pragma unroll
      for (int k = 0; k < 6; k++) {
        int qi = 4 * k + w;
        if (qi >= u) break;
        O[k] += Ps[qi][jj] * v0 + Ps[qi][jj + 1] * v1 + Ps[qi][jj + 2] * v2 +
                Ps[qi][jj + 3] * v3;
      }
    }
  }
#pragma unroll
  for (int k = 0; k < 6; k++) {
    int qi = 4 * k + w;
    if (qi < u) {
      int p = (bh * nchunk + c) * u + qi;
      if (lane == 0) { pm[p] = m[k]; pl[p] = l[k]; }
      pO[(size_t)p * 64 + lane] = O[k];
    }
  }
}

__global__ __launch_bounds__(256) void deltaWo_kernel(
    const float* __restrict__ pm, const float* __restrict__ pl,
    const float* __restrict__ pO, const float* __restrict__ mvg,
    const int* __restrict__ topb, const float* __restrict__ Wo, float* x1,
    int L, int u, int nchunk) {
  __shared__ float ds[64];
  int sel = blockIdx.x;
  int bh = sel / u;
  int qi = sel - bh * u;
  int b = bh >> 3, h = bh & 7;
  int t = topb[sel];
  int tid = threadIdx.x;
  if (tid < 64) {
    float mstar = -3.4e38f;
    for (int c = 0; c < nchunk; c++)
      mstar = fmaxf(mstar, pm[(bh * nchunk + c) * u + qi]);
    float lstar = 0.f, O = 0.f;
    for (int c = 0; c < nchunk; c++) {
      int p = (bh * nchunk + c) * u + qi;
      float wgt = expf(pm[p] - mstar);
      lstar += wgt * pl[p];
      O += wgt * pO[(size_t)p * 64 + tid];
    }
    ds[tid] = O / lstar - mvg[b * DMODEL + h * HD + tid];
  }
  __syncthreads();
  float* row = x1 + ((size_t)(b * L + t)) * DMODEL;
  for (int nn = 0; nn < 2; nn++) {
    int n = tid + nn * 256;
    const float* wr = Wo + (size_t)n * 512 + h * HD;
    float a = 0.f;
#pragma unroll
    for (int k = 0; k < 64; k += 4) {
      float4 w4 = *(const float4*)(wr + k);
      a += ds[k] * w4.x + ds[k + 1] * w4.y + ds[k + 2] * w4.z + ds[k + 3] * w4.w;
    }
    atomicAdd(row + n, a);
  }
}

// ---------------------------------------------------------------- layernorm (512 cols; wave-shuffle reduce; optional hi/lo emit; optional bcast add)
template <int EMIT, int ADDB>
__global__ __launch_bounds__(256) void ln_kernel(const float* __restrict__ X,
                                                 const float* __restrict__ g,
                                                 const float* __restrict__ bta,
                                                 float* __restrict__ Y,
                                                 unsigned short* __restrict__ Hh,
                                                 unsigned short* __restrict__ Hl,
                                                 const float* __restrict__ mvW,
                                                 int Lr) {
  __shared__ float ws[4];
  __shared__ float ws2[4];
  int row = blockIdx.x, tid = threadIdx.x;
  int lane = tid & 63, w = tid >> 6;
  size_t base = (size_t)row * DMODEL;
  float x0 = X[base + tid], x1 = X[base + tid + 256];
  if (ADDB) {
    int b = row / Lr;
    x0 += mvW[b * DMODEL + tid];
    x1 += mvW[b * DMODEL + tid + 256];
  }
  float s = x0 + x1;
#pragma unroll
  for (int off = 32; off > 0; off >>= 1) s += __shfl_xor(s, off);
  if (lane == 0) ws[w] = s;
  __syncthreads();
  float mean = (ws[0] + ws[1] + ws[2] + ws[3]) * (1.0f / 512.0f);
  float d0 = x0 - mean, d1 = x1 - mean;
  float q = d0 * d0 + d1 * d1;
#pragma unroll
  for (int off = 32; off > 0; off >>= 1) q += __shfl_xor(q, off);
  if (lane == 0) ws2[w] = q;
  __syncthreads();
  float inv =
      1.0f / sqrtf((ws2[0] + ws2[1] + ws2[2] + ws2[3]) * (1.0f / 512.0f) + 1e-5f);
  float y0 = d0 * inv * g[tid] + bta[tid];
  float y1 = d1 * inv * g[tid + 256] + bta[tid + 256];
  Y[base + tid] = y0;
  Y[base + tid + 256] = y1;
  if (EMIT) {
    unsigned short h, l;
    f2hsplit(y0, h, l);
    Hh[base + tid] = h;
    Hl[base + tid] = l;
    f2hsplit(y1, h, l);
    Hh[base + tid + 256] = h;
    Hl[base + tid + 256] = l;
  }
}

// ---------------------------------------------------------------- combine K-split partials + residual + LN2, fused (per 4096-row chunk)
// z = sum_kb part + bias + resid (exact combine order); y = LN(z; g, bta).
// EMIT=1: write hi/lo only (P1, conv input — LN2's fp32 out is dead for l<2).
// EMIT=0: write fp32 Y only (l=2 path; lnf reads it).
template <int EMIT>
__global__ __launch_bounds__(256) void lncomb_kernel(
    const float* __restrict__ part, const float* __restrict__ bias,
    const float* __restrict__ resid, const float* __restrict__ g,
    const float* __restrict__ bta, float* __restrict__ Y,
    unsigned short* __restrict__ Hh, unsigned short* __restrict__ Hl, int r0,
    size_t MNc) {
  __shared__ float ws[4];
  __shared__ float ws2[4];
  int lrow = blockIdx.x, tid = threadIdx.x;
  int lane = tid & 63, w = tid >> 6;
  size_t lbase = (size_t)lrow * DMODEL;
  size_t gbase = (size_t)(r0 + lrow) * DMODEL;
  float x0 = 0.f, x1 = 0.f;
  for (int kb = 0; kb < 4; kb++) {
    x0 += part[kb * MNc + lbase + tid];
    x1 += part[kb * MNc + lbase + tid + 256];
  }
  x0 += bias[tid];
  x1 += bias[tid + 256];
  x0 += resid[gbase + tid];
  x1 += resid[gbase + tid + 256];
  float s = x0 + x1;
#pragma unroll
  for (int off = 32; off > 0; off >>= 1) s += __shfl_xor(s, off);
  if (lane == 0) ws[w] = s;
  __syncthreads();
  float mean = (ws[0] + ws[1] + ws[2] + ws[3]) * (1.0f / 512.0f);
  float d0 = x0 - mean, d1 = x1 - mean;
  float q = d0 * d0 + d1 * d1;
#pragma unroll
  for (int off = 32; off > 0; off >>= 1) q += __shfl_xor(q, off);
  if (lane == 0) ws2[w] = q;
  __syncthreads();
  float inv =
      1.0f / sqrtf((ws2[0] + ws2[1] + ws2[2] + ws2[3]) * (1.0f / 512.0f) + 1e-5f);
  float y0 = d0 * inv * g[tid] + bta[tid];
  float y1 = d1 * inv * g[tid + 256] + bta[tid + 256];
  if (EMIT) {
    unsigned short h, l;
    f2hsplit(y0, h, l);
    Hh[gbase + tid] = h;
    Hl[gbase + tid] = l;
    f2hsplit(y1, h, l);
    Hh[gbase + tid + 256] = h;
    Hl[gbase + tid + 256] = l;
  } else {
    Y[gbase + tid] = y0;
    Y[gbase + tid + 256] = y1;
  }
}

// ---------------------------------------------------------------- BN stats + pool
__global__ __launch_bounds__(256) void bnpart_kernel(const float* __restrict__ z,
                                                     float* __restrict__ psum,
                                                     float* __restrict__ psq,
                                                     int rowsPer) {
  int blk = blockIdx.x, tid = threadIdx.x;
  size_t r0 = (size_t)blk * rowsPer;
  float s0 = 0, q0 = 0, s1 = 0, q1 = 0;
  for (int r = 0; r < rowsPer; r++) {
    const float* zp = z + (r0 + r) * DMODEL;
    float a = zp[tid];
    s0 += a; q0 += a * a;
    float c = zp[tid + 256];
    s1 += c; q1 += c * c;
  }
  psum[blk * DMODEL + tid] = s0;
  psum[blk * DMODEL + tid + 256] = s1;
  psq[blk * DMODEL + tid] = q0;
  psq[blk * DMODEL + tid + 256] = q1;
}

__global__ void bnfin_kernel(const float* __restrict__ psum,
                             const float* __restrict__ psq, float* __restrict__ mu,
                             float* __restrict__ var, int nb, int Rtot) {
  int c = blockIdx.x * 256 + threadIdx.x;
  float s = 0, q = 0;
  for (int b = 0; b < nb; b++) {
    s += psum[b * DMODEL + c];
    q += psq[b * DMODEL + c];
  }
  float m = s / (float)Rtot;
  mu[c] = m;
  var[c] = fmaxf(q / (float)Rtot - m * m, 0.f);
}

template <int EMIT>
__global__ void bnpool_kernel(const float* __restrict__ z,
                              const float* __restrict__ mu,
                              const float* __restrict__ var,
                              const float* __restrict__ g,
                              const float* __restrict__ bta,
                              float* __restrict__ out,
                              unsigned short* __restrict__ Hh,
                              unsigned short* __restrict__ Hl, int L) {
  int gid = blockIdx.x * 256 + threadIdx.x;
  int c = gid & 511;
  int bt = gid >> 9;
  int L2 = L >> 1;
  int t2 = bt % L2, b = bt / L2;
  float m = mu[c];
  float inv = 1.0f / sqrtf(var[c] + 1e-5f);
  float gg = g[c], bb = bta[c];
  float best = -3.4e38f;
#pragma unroll
  for (int ww = 0; ww < 3; ww++) {
    int t = 2 * t2 - 1 + ww;
    if (t < 0 || t >= L) continue;
    float yv = (z[((size_t)(b * L + t)) * DMODEL + c] - m) * inv * gg + bb;
    yv = (yv > 0.f) ? yv : expm1f(yv);
    best = fmaxf(best, yv);
  }
  out[gid] = best;
  if (EMIT) {
    unsigned short h, l;
    f2hsplit(best, h, l);
    Hh[gid] = h;
    Hl[gid] = l;
  }
}

// ---------------------------------------------------------------- final projection (512 -> 7)
__global__ __launch_bounds__(64) void end_kernel(const float* __restrict__ xn,
                                                 const float* __restrict__ ew,
                                                 const float* __restrict__ eb,
                                                 float* __restrict__ out) {
  __shared__ float xs[512];
  __shared__ float red[64];
  int row = blockIdx.x, tid = threadIdx.x;
#pragma unroll
  for (int i = 0; i < 8; i++) xs[tid + 64 * i] = xn[(size_t)row * DMODEL + tid + 64 * i];
  __syncthreads();
  for (int c = 0; c < 7; c++) {
    float p = 0.f;
    for (int d = tid; d < 512; d += 64) p += xs[d] * ew[c * DMODEL + d];
    red[tid] = p;
    __syncthreads();
    for (int s = 32; s > 0; s >>= 1) {
      if (tid < s) red[tid] += red[tid + s];
      __syncthreads();
    }
    if (tid == 0) out[row * 7 + c] = red[0] + eb[c];
    __syncthreads();
  }
}

// ---------------------------------------------------------------- host
extern "C" void kernel_launch(void* const* d_in, const int* in_sizes, int n_in,
                              void* d_out, int out_size, void* d_ws,
                              size_t ws_size, hipStream_t stream) {
  (void)in_sizes; (void)n_in; (void)out_size;
  const float* x_enc = (const float*)d_in[0];
  const float* tok_w = (const float*)d_in[1];
  const float* Wq = (const float*)d_in[2];
  const float* bq = (const float*)d_in[3];
  const float* Wk = (const float*)d_in[4];
  const float* bk = (const float*)d_in[5];
  const float* Wv = (const float*)d_in[6];
  const float* bv = (const float*)d_in[7];
  const float* Wo = (const float*)d_in[8];
  const float* bo = (const float*)d_in[9];
  const float* w1 = (const float*)d_in[10];
  const float* b1 = (const float*)d_in[11];
  const float* w2 = (const float*)d_in[12];
  const float* b2 = (const float*)d_in[13];
  const float* g1 = (const float*)d_in[14];
  const float* be1 = (const float*)d_in[15];
  const float* g2 = (const float*)d_in[16];
  const float* be2 = (const float*)d_in[17];
  const float* dw = (const float*)d_in[18];
  const float* db = (const float*)d_in[19];
  const float* bng = (const float*)d_in[20];
  const float* bnb = (const float*)d_in[21];
  const float* lnfg = (const float*)d_in[22];
  const float* lnfb = (const float*)d_in[23];
  const float* endw = (const float*)d_in[24];
  const float* endb = (const float*)d_in[25];
  float* out = (float*)d_out;
  char* ws = (char*)d_ws;

  const int B = 8;
  const int S = 2048;
  const int Uarr[3] = {24, 21, 21};
  const int NCHMAX = 32;

  // ---- MFMA-path arena ----
  size_t o = 0;
  float* buf0 = (float*)(ws + o); o += (size_t)16384 * 512 * 4;
  float* qbuf = (float*)(ws + o); o += (size_t)16384 * 512 * 4;
  float* kbuf = (float*)(ws + o); o += (size_t)16384 * 512 * 4;
  float* Mb    = (float*)(ws + o); o += (size_t)64 * 2048 * 4;
  int*   idxb  = (int*)(ws + o);   o += (size_t)2048 * 24 * 4;
  int*   topb  = (int*)(ws + o);   o += 8192;
  float* qsel  = (float*)(ws + o); o += (size_t)64 * 24 * 64 * 4;
  float* mvg   = (float*)(ws + o); o += (size_t)8 * 512 * 4;
  float* mvWog = (float*)(ws + o); o += (size_t)8 * 512 * 4;
  float* psumx = (float*)(ws + o); o += (size_t)64 * 512 * 4;
  float* psum  = (float*)(ws + o); o += (size_t)128 * 512 * 4;
  float* psq   = (float*)(ws + o); o += (size_t)128 * 512 * 4;
  float* muv   = (float*)(ws + o); o += 2048;
  float* varv  = (float*)(ws + o); o += 2048;
  float* pmb   = (float*)(ws + o); o += (size_t)64 * NCHMAX * 24 * 4;
  float* plb   = (float*)(ws + o); o += (size_t)64 * NCHMAX * 24 * 4;
  float* pOb   = (float*)(ws + o); o += (size_t)64 * NCHMAX * 24 * 64 * 4;
  unsigned short* P1h = (unsigned short*)(ws + o); o += (size_t)16384 * 512 * 2;
  unsigned short* P1l = (unsigned short*)(ws + o); o += (size_t)16384 * 512 * 2;
  unsigned short* P2h = (unsigned short*)(ws + o); o += (size_t)16384 * 512 * 2;
  unsigned short* P2l = (unsigned short*)(ws + o); o += (size_t)16384 * 512 * 2;
  unsigned short* Wqkvh = (unsigned short*)(ws + o); o += (size_t)1536 * 512 * 2;
  unsigned short* Wqkvl = (unsigned short*)(ws + o); o += (size_t)1536 * 512 * 2;
  unsigned short* w1h = (unsigned short*)(ws + o); o += (size_t)2048 * 512 * 2;
  unsigned short* w1l = (unsigned short*)(ws + o); o += (size_t)2048 * 512 * 2;
  unsigned short* w2h = (unsigned short*)(ws + o); o += (size_t)512 * 2048 * 2;
  unsigned short* w2l = (unsigned short*)(ws + o); o += (size_t)512 * 2048 * 2;
  unsigned short* wph = (unsigned short*)(ws + o); o += (size_t)512 * 1536 * 2;
  unsigned short* wpl = (unsigned short*)(ws + o); o += (size_t)512 * 1536 * 2;
  const bool use_mfma = (ws_size >= o);
  float* vbuf = (float*)(ws + o); o += (size_t)16384 * 512 * 4;
  const bool fuseqkv = (ws_size >= o);
  unsigned short* CHh = (unsigned short*)(ws + o); o += (size_t)16384 * 2048 * 2;
  unsigned short* CHl = (unsigned short*)(ws + o); o += (size_t)16384 * 2048 * 2;
  const bool fullffn = (ws_size >= o);
  // chunked-FFN scratch (aliased over dead buffers):
  //  fuseqkv: CH chunk (33.5 MB) -> vbuf (V dead after attnflash);
  //           FFN2 K-split partials (33.5 MB) -> kbuf (K dead; z never built)
  //  !fuseqkv fallback: CH chunk -> buf0, partials -> P1 region (round-3 layout)
  unsigned short* CHb0 = (unsigned short*)buf0;
  float* partmP1 = (float*)P1h;
  unsigned short* CHv = (unsigned short*)vbuf;
  float* partk = kbuf;

  if (use_mfma) {
    tokpe_kernel<1><<<B * S * DMODEL / 256, 256, 0, stream>>>(x_enc, tok_w,
                                                              buf0, P1h, P1l, S);
    int L = S;
    for (int l = 0; l < 3; l++) {
      int U = Uarr[l];
      int u = Uarr[l];
      int BL = B * L;
      int nty = BL >> 7;
      int nch = L >> 6;
      if (nch > NCHMAX) nch = NCHMAX;
      idx_kernel<<<(L * U + 255) / 256, 256, 0, stream>>>(idxb, L * U, l, L - 1);
      // weights -> packed fp16 hi/lo
      cvt_kernel<<<128, 256, 0, stream>>>(Wq + (size_t)l * 262144, Wqkvh, Wqkvl, 32768);
      cvt_kernel<<<128, 256, 0, stream>>>(Wk + (size_t)l * 262144, Wqkvh + 262144,
                                          Wqkvl + 262144, 32768);
      cvt_kernel<<<128, 256, 0, stream>>>(Wv + (size_t)l * 262144, Wqkvh + 524288,
                                          Wqkvl + 524288, 32768);
      if (fuseqkv) {
        gemm_mfma<0, 0, 0, 0, 1, 0><<<12 * nty, 256, 0, stream>>>(
            P1h, P1l, Wqkvh, Wqkvl, bq + l * 512, bk + l * 512, bv + l * 512,
            nullptr, qbuf, kbuf, vbuf, nullptr, nullptr, 1536, 512, 0, 12, nty,
            512);
      } else {
        gemm_mfma<0, 0, 0, 0, 0, 0><<<4 * nty, 256, 0, stream>>>(
            P1h, P1l, Wqkvh, Wqkvl, bq + l * 512, nullptr, nullptr, nullptr,
            qbuf, nullptr, nullptr, nullptr, nullptr, 512, 512, 0, 4, nty, 512);
        gemm_mfma<0, 0, 0, 0, 0, 0><<<4 * nty, 256, 0, stream>>>(
            P1h, P1l, Wqkvh + 262144, Wqkvl + 262144, bk + l * 512, nullptr,
            nullptr, nullptr, kbuf, nullptr, nullptr, nullptr, nullptr, 512,
            512, 0, 4, nty, 512);
      }
      mscore4_kernel<<<64 * (L >> 6), 256, 0, stream>>>(qbuf, kbuf, idxb, Mb, L, U);
      topk_kernel<<<64, 256, 0, stream>>>(Mb, topb, L, u);
      gatherq_kernel<<<64 * u, 64, 0, stream>>>(qbuf, topb, qsel, L, u);
      xmean_kernel<<<64, 256, 0, stream>>>(buf0, psumx, L);
      mvmake_kernel<<<8, 256, 0, stream>>>(psumx, Wv + (size_t)l * 262144,
                                           bv + l * 512, Wo + (size_t)l * 262144,
                                           bo + l * 512, mvg, mvWog, L);
      const float* Vb;
      if (fuseqkv) {
        Vb = vbuf;
      } else {
        gemm_mfma<0, 0, 0, 0, 0, 0><<<4 * nty, 256, 0, stream>>>(
            P1h, P1l, Wqkvh + 524288, Wqkvl + 524288, bv + l * 512, nullptr,
            nullptr, nullptr, qbuf, nullptr, nullptr, nullptr, nullptr, 512,
            512, 0, 4, nty, 512);
        Vb = qbuf;
      }
      attnflash_kernel<<<64 * nch, 256, 0, stream>>>(qsel, kbuf, Vb, pmb, plb,
                                                     pOb, L, u, nch);
      // delta accumulates straight into x (buf0); mvWo broadcast folded into LN1
      deltaWo_kernel<<<64 * u, 256, 0, stream>>>(pmb, plb, pOb, mvg, topb,
                                                 Wo + (size_t)l * 262144, buf0, L,
                                                 u, nch);
      // xa = LN1(x + delta + mvWo) -> qbuf (+hi/lo -> P2); buf0 x now dead
      ln_kernel<1, 1><<<BL, 256, 0, stream>>>(buf0, g1 + l * 512, be1 + l * 512,
                                              qbuf, P2h, P2l, mvWog, L);
      cvt_kernel<<<512, 256, 0, stream>>>(w1 + (size_t)l * 1048576, w1h, w1l, 131072);
      cvt_kernel<<<512, 256, 0, stream>>>(w2 + (size_t)l * 1048576, w2h, w2l, 131072);
      if (fullffn) {
        gemm_mfma<1, 0, 0, 1, 0, 0><<<16 * nty, 256, 0, stream>>>(
            P2h, P2l, w1h, w1l, b1 + l * 2048, nullptr, nullptr, nullptr,
            nullptr, nullptr, nullptr, CHh, CHl, 2048, 512, 0, 16, nty, 512);
        gemm_mfma<0, 1, 0, 0, 0, 0><<<4 * nty, 256, 0, stream>>>(
            CHh, CHl, w2h, w2l, b2 + l * 512, nullptr, nullptr, qbuf, kbuf,
            nullptr, nullptr, nullptr, nullptr, 512, 2048, 0, 4, nty, 2048);
        if (l < 2) {
          ln_kernel<1, 0><<<BL, 256, 0, stream>>>(kbuf, g2 + l * 512,
                                                  be2 + l * 512, buf0, P1h, P1l,
                                                  nullptr, 1);
        } else {
          ln_kernel<0, 0><<<BL, 256, 0, stream>>>(kbuf, g2 + l * 512,
                                                  be2 + l * 512, buf0, nullptr,
                                                  nullptr, nullptr, 1);
        }
      } else if (fuseqkv) {
        // chunked FFN + fused combine/LN2: CH -> vbuf, partials -> kbuf.
        unsigned short* CHvl = CHv + (size_t)4096 * 2048;
        for (int r0 = 0; r0 < BL; r0 += 4096) {
          gemm_mfma<1, 0, 0, 1, 0, 0><<<16 * 32, 256, 0, stream>>>(
              P2h + (size_t)r0 * 512, P2l + (size_t)r0 * 512, w1h, w1l,
              b1 + l * 2048, nullptr, nullptr, nullptr, nullptr, nullptr,
              nullptr, CHv, CHvl, 2048, 512, 0, 16, 32, 512);
          gemm_mfma<0, 0, 0, 0, 0, 1><<<4 * 32 * 4, 256, 0, stream>>>(
              CHv, CHvl, w2h, w2l, nullptr, nullptr, nullptr, nullptr, partk,
              nullptr, nullptr, nullptr, nullptr, 512, 2048, 0, 4, 32, 512);
          if (l < 2) {
            lncomb_kernel<1><<<4096, 256, 0, stream>>>(
                partk, b2 + l * 512, qbuf, g2 + l * 512, be2 + l * 512, nullptr,
                P1h, P1l, r0, (size_t)4096 * 512);
          } else {
            lncomb_kernel<0><<<4096, 256, 0, stream>>>(
                partk, b2 + l * 512, qbuf, g2 + l * 512, be2 + l * 512, buf0,
                nullptr, nullptr, r0, (size_t)4096 * 512);
          }
        }
      } else {
        // fallback chunked path (round-3 layout): CH -> buf0, partials -> P1
        unsigned short* CHlch = CHb0 + (size_t)4096 * 2048;
        for (int r0 = 0; r0 < BL; r0 += 4096) {
          gemm_mfma<1, 0, 0, 1, 0, 0><<<16 * 32, 256, 0, stream>>>(
              P2h + (size_t)r0 * 512, P2l + (size_t)r0 * 512, w1h, w1l,
              b1 + l * 2048, nullptr, nullptr, nullptr, nullptr, nullptr,
              nullptr, CHb0, CHlch, 2048, 512, 0, 16, 32, 512);
          gemm_mfma<0, 0, 0, 0, 0, 1><<<4 * 32 * 4, 256, 0, stream>>>(
              CHb0, CHlch, w2h, w2l, nullptr, nullptr, nullptr, nullptr,
              partmP1, nullptr, nullptr, nullptr, nullptr, 512, 2048, 0, 4, 32,
              512);
          combine_kernel<1><<<4096 * 512 / 256, 256, 0, stream>>>(
              partmP1, b2 + l * 512, qbuf + (size_t)r0 * 512,
              kbuf + (size_t)r0 * 512, (size_t)4096 * 512, 4);
        }
        if (l < 2) {
          ln_kernel<1, 0><<<BL, 256, 0, stream>>>(kbuf, g2 + l * 512,
                                                  be2 + l * 512, buf0, P1h, P1l,
                                                  nullptr, 1);
        } else {
          ln_kernel<0, 0><<<BL, 256, 0, stream>>>(kbuf, g2 + l * 512,
                                                  be2 + l * 512, buf0, nullptr,
                                                  nullptr, nullptr, 1);
        }
      }
      if (l < 2) {
        packw2_kernel<<<512 * 1536 / 256, 256, 0, stream>>>(
            dw + (size_t)l * 512 * 512 * 3, wph, wpl);
        gemm_mfma<0, 0, 1, 0, 0, 0><<<4 * nty, 256, 0, stream>>>(
            P1h, P1l, wph, wpl, db + l * 512, nullptr, nullptr, nullptr, kbuf,
            nullptr, nullptr, nullptr, nullptr, 512, 1536, L - 1, 4, nty, 1536);
        int nb = BL / 128;
        bnpart_kernel<<<nb, 256, 0, stream>>>(kbuf, psum, psq, 128);
        bnfin_kernel<<<2, 256, 0, stream>>>(psum, psq, muv, varv, nb, BL);
        bnpool_kernel<1><<<(BL / 2) * 512 / 256, 256, 0, stream>>>(
            kbuf, muv, varv, bng + l * 512, bnb + l * 512, buf0, P1h, P1l, L);
        L >>= 1;
      }
    }
    int BL = B * L;  // 4096
    ln_kernel<0, 0><<<BL, 256, 0, stream>>>(buf0, lnfg, lnfb, qbuf, nullptr,
                                            nullptr, nullptr, 1);
    end_kernel<<<BL, 64, 0, stream>>>(qbuf, endw, endb, out);
    return;
  }

  // ================= fallback: verified fp32 path =================
  {
    const int NCH = 8;
    size_t o2 = 0;
    float* buf0f = (float*)(ws + o2); o2 += (size_t)16384 * 512 * 4;
    float* qbuff = (float*)(ws + o2); o2 += (size_t)16384 * 512 * 4;
    float* kbuff = (float*)(ws + o2); o2 += (size_t)16384 * 512 * 4;
    float* wpack = (float*)(ws + o2); o2 += (size_t)512 * 1536 * 4;
    float* Mbf    = (float*)(ws + o2); o2 += (size_t)64 * 2048 * 4;
    int*   idxbf  = (int*)(ws + o2);   o2 += (size_t)2048 * 24 * 4;
    int*   topbf  = (int*)(ws + o2);   o2 += 8192;
    float* qself  = (float*)(ws + o2); o2 += (size_t)64 * 24 * 64 * 4;
    float* mvgf   = (float*)(ws + o2); o2 += (size_t)8 * 512 * 4;
    float* mvWogf = (float*)(ws + o2); o2 += (size_t)8 * 512 * 4;
    float* psumxf = (float*)(ws + o2); o2 += (size_t)64 * 512 * 4;
    float* psumf  = (float*)(ws + o2); o2 += (size_t)128 * 512 * 4;
    float* psqf   = (float*)(ws + o2); o2 += (size_t)128 * 512 * 4;
    float* muvf   = (float*)(ws + o2); o2 += 2048;
    float* varvf  = (float*)(ws + o2); o2 += 2048;
    float* pmbf   = (float*)(ws + o2); o2 += (size_t)64 * NCH * 24 * 4;
    float* plbf   = (float*)(ws + o2); o2 += (size_t)64 * NCH * 24 * 4;
    float* pObf   = (float*)(ws + o2); o2 += (size_t)64 * NCH * 24 * 64 * 4;
    float* partb  = (float*)(ws + o2); o2 += (size_t)4 * 4096 * 2048;
    const bool uks = (ws_size >= o2);

    tokpe_kernel<0><<<B * S * DMODEL / 256, 256, 0, stream>>>(
        x_enc, tok_w, buf0f, nullptr, nullptr, S);
    int L = S;
    for (int l = 0; l < 3; l++) {
      int U = Uarr[l];
      int u = U;
      int BL = B * L;
      int nty = BL / 128;
      size_t MN = (size_t)BL * 512;
      int gq = 4 * nty;
      int ksq = (gq >= 512 || !uks) ? 1 : (512 / gq);
      idx_kernel<<<(L * U + 255) / 256, 256, 0, stream>>>(idxbf, L * U, l, L - 1);
      if (ksq == 1) {
        gemm128<0, 0, 0, 0><<<gq, 256, 0, stream>>>(
            buf0f, Wq + (size_t)l * 262144, bq + l * 512, nullptr, qbuff, 512,
            512, 0, 4, nty, 512, 1);
        gemm128<0, 0, 0, 0><<<gq, 256, 0, stream>>>(
            buf0f, Wk + (size_t)l * 262144, bk + l * 512, nullptr, kbuff, 512,
            512, 0, 4, nty, 512, 1);
      } else {
        gemm128<0, 0, 0, 1><<<gq * ksq, 256, 0, stream>>>(
            buf0f, Wq + (size_t)l * 262144, nullptr, nullptr, partb, 512, 512, 0,
            4, nty, 512 / ksq, ksq);
        combine_kernel<0><<<(unsigned)(MN / 256), 256, 0, stream>>>(
            partb, bq + l * 512, nullptr, qbuff, MN, ksq);
        gemm128<0, 0, 0, 1><<<gq * ksq, 256, 0, stream>>>(
            buf0f, Wk + (size_t)l * 262144, nullptr, nullptr, partb, 512, 512, 0,
            4, nty, 512 / ksq, ksq);
        combine_kernel<0><<<(unsigned)(MN / 256), 256, 0, stream>>>(
            partb, bk + l * 512, nullptr, kbuff, MN, ksq);
      }
      mscore_kernel<<<8 * 8 * L / 256, 256, 0, stream>>>(qbuff, kbuff, idxbf, Mbf, L, U);
      topk_kernel<<<64, 256, 0, stream>>>(Mbf, topbf, L, u);
      gatherq_kernel<<<64 * u, 64, 0, stream>>>(qbuff, topbf, qself, L, u);
      xmean_kernel<<<64, 256, 0, stream>>>(buf0f, psumxf, L);
      mvmake_kernel<<<8, 256, 0, stream>>>(psumxf, Wv + (size_t)l * 262144,
                                           bv + l * 512, Wo + (size_t)l * 262144,
                                           bo + l * 512, mvgf, mvWogf, L);
      if (ksq == 1) {
        gemm128<0, 0, 0, 0><<<gq, 256, 0, stream>>>(
            buf0f, Wv + (size_t)l * 262144, bv + l * 512, nullptr, qbuff, 512,
            512, 0, 4, nty, 512, 1);
      } else {
        gemm128<0, 0, 0, 1><<<gq * ksq, 256, 0, stream>>>(
            buf0f, Wv + (size_t)l * 262144, nullptr, nullptr, partb, 512, 512, 0,
            4, nty, 512 / ksq, ksq);
        combine_kernel<0><<<(unsigned)(MN / 256), 256, 0, stream>>>(
            partb, bv + l * 512, nullptr, qbuff, MN, ksq);
      }
      attnflash_kernel<<<64 * NCH, 256, 0, stream>>>(qself, kbuff, qbuff, pmbf,
                                                     plbf, pObf, L, u, NCH);
      x1bcast_kernel<<<(unsigned)(MN / 256), 256, 0, stream>>>(buf0f, mvWogf, kbuff, L);
      deltaWo_kernel<<<64 * u, 256, 0, stream>>>(pmbf, plbf, pObf, mvgf, topbf,
                                                 Wo + (size_t)l * 262144, kbuff,
                                                 L, u, NCH);
      ln_kernel<0, 0><<<BL, 256, 0, stream>>>(kbuff, g1 + l * 512, be1 + l * 512,
                                              qbuff, nullptr, nullptr, nullptr, 1);
      for (int r0 = 0; r0 < BL; r0 += 4096) {
        gemm128<1, 0, 0, 0><<<16 * 32, 256, 0, stream>>>(
            qbuff + (size_t)r0 * 512, w1 + (size_t)l * 2048 * 512, b1 + l * 2048,
            nullptr, buf0f, 2048, 512, 0, 16, 32, 512, 1);
        if (uks) {
          gemm128<0, 0, 0, 1><<<4 * 32 * 4, 256, 0, stream>>>(
              buf0f, w2 + (size_t)l * 512 * 2048, nullptr, nullptr, partb, 512,
              2048, 0, 4, 32, 512, 4);
          combine_kernel<1><<<4096 * 512 / 256, 256, 0, stream>>>(
              partb, b2 + l * 512, qbuff + (size_t)r0 * 512,
              kbuff + (size_t)r0 * 512, (size_t)4096 * 512, 4);
        } else {
          gemm128<0, 1, 0, 0><<<4 * 32, 256, 0, stream>>>(
              buf0f, w2 + (size_t)l * 512 * 2048, b2 + l * 512,
              qbuff + (size_t)r0 * 512, kbuff + (size_t)r0 * 512, 512, 2048, 0,
              4, 32, 2048, 1);
        }
      }
      ln_kernel<0, 0><<<BL, 256, 0, stream>>>(kbuff, g2 + l * 512, be2 + l * 512,
                                              buf0f, nullptr, nullptr, nullptr, 1);

      if (l < 2) {
        packw_kernel<<<512 * 1536 / 256, 256, 0, stream>>>(
            dw + (size_t)l * 512 * 512 * 3, wpack);
        int ksc = (gq >= 512 || !uks) ? 1 : 2;
        if (ksc == 1) {
          gemm128<0, 0, 1, 0><<<gq, 256, 0, stream>>>(
              buf0f, wpack, db + l * 512, nullptr, kbuff, 512, 1536, L - 1, 4,
              nty, 1536, 1);
        } else {
          gemm128<0, 0, 1, 1><<<gq * 2, 256, 0, stream>>>(
              buf0f, wpack, nullptr, nullptr, partb, 512, 1536, L - 1, 4, nty,
              768, 2);
          combine_kernel<0><<<(unsigned)(MN / 256), 256, 0, stream>>>(
              partb, db + l * 512, nullptr, kbuff, MN, 2);
        }
        int nb = BL / 128;
        bnpart_kernel<<<nb, 256, 0, stream>>>(kbuff, psumf, psqf, 128);
        bnfin_kernel<<<2, 256, 0, stream>>>(psumf, psqf, muvf, varvf, nb, BL);
        bnpool_kernel<0><<<(BL / 2) * 512 / 256, 256, 0, stream>>>(
            kbuff, muvf, varvf, bng + l * 512, bnb + l * 512, buf0f, nullptr,
            nullptr, L);
        L >>= 1;
      }
    }
    int BL = B * L;
    ln_kernel<0, 0><<<BL, 256, 0, stream>>>(buf0f, lnfg, lnfb, qbuff, nullptr,
                                            nullptr, nullptr, 1);
    end_kernel<<<BL, 64, 0, stream>>>(qbuff, endw, endb, out);
  }
}

// Round 7
// 2094.401 us; speedup vs baseline: 1.8445x; 1.8445x over previous
//
#include <hip/hip_runtime.h>
#include <cstdint>
#include <cstddef>

#define DMODEL 512
#define NHEAD 8
#define HD 64

typedef _Float16 half8 __attribute__((ext_vector_type(8)));
typedef float f32x4 __attribute__((ext_vector_type(4)));

// ---------------------------------------------------------------- threefry
__device__ __forceinline__ uint32_t rotl32(uint32_t x, int r) {
  return (x << r) | (x >> (32 - r));
}

__device__ __forceinline__ void tf_block(uint32_t k0, uint32_t k1,
                                         uint32_t& x0, uint32_t& x1) {
  uint32_t ks0 = k0, ks1 = k1, ks2 = k0 ^ k1 ^ 0x1BD11BDAu;
  x0 += ks0; x1 += ks1;
  x0 += x1; x1 = rotl32(x1, 13); x1 ^= x0;
  x0 += x1; x1 = rotl32(x1, 15); x1 ^= x0;
  x0 += x1; x1 = rotl32(x1, 26); x1 ^= x0;
  x0 += x1; x1 = rotl32(x1, 6);  x1 ^= x0;
  x0 += ks1; x1 += ks2 + 1u;
  x0 += x1; x1 = rotl32(x1, 17); x1 ^= x0;
  x0 += x1; x1 = rotl32(x1, 29); x1 ^= x0;
  x0 += x1; x1 = rotl32(x1, 16); x1 ^= x0;
  x0 += x1; x1 = rotl32(x1, 24); x1 ^= x0;
  x0 += ks2; x1 += ks0 + 2u;
  x0 += x1; x1 = rotl32(x1, 13); x1 ^= x0;
  x0 += x1; x1 = rotl32(x1, 15); x1 ^= x0;
  x0 += x1; x1 = rotl32(x1, 26); x1 ^= x0;
  x0 += x1; x1 = rotl32(x1, 6);  x1 ^= x0;
  x0 += ks0; x1 += ks1 + 3u;
  x0 += x1; x1 = rotl32(x1, 17); x1 ^= x0;
  x0 += x1; x1 = rotl32(x1, 29); x1 ^= x0;
  x0 += x1; x1 = rotl32(x1, 16); x1 ^= x0;
  x0 += x1; x1 = rotl32(x1, 24); x1 ^= x0;
  x0 += ks1; x1 += ks2 + 4u;
  x0 += x1; x1 = rotl32(x1, 13); x1 ^= x0;
  x0 += x1; x1 = rotl32(x1, 15); x1 ^= x0;
  x0 += x1; x1 = rotl32(x1, 26); x1 ^= x0;
  x0 += x1; x1 = rotl32(x1, 6);  x1 ^= x0;
  x0 += ks2; x1 += ks0 + 5u;
}

__global__ void idx_kernel(int* __restrict__ idxb, int n, int layer, int mask) {
  int e = blockIdx.x * 256 + threadIdx.x;
  if (e >= n) return;
  uint32_t f0 = 0u, f1 = (uint32_t)layer;
  tf_block(0u, 42u, f0, f1);
  uint32_t s0 = 0u, s1 = 1u;
  tf_block(f0, f1, s0, s1);
  uint32_t x0 = 0u, x1 = (uint32_t)e;
  tf_block(s0, s1, x0, x1);
  uint32_t bits = x0 ^ x1;
  idxb[e] = (int)(bits & (uint32_t)mask);
}

// ---------------------------------------------------------------- fp16 hi/lo split helpers
__device__ __forceinline__ void f2hsplit(float v, unsigned short& h,
                                         unsigned short& l) {
  _Float16 hh = (_Float16)v;          // RNE
  float r = v - (float)hh;            // exact
  _Float16 ll = (_Float16)r;
  h = __builtin_bit_cast(unsigned short, hh);
  l = __builtin_bit_cast(unsigned short, ll);
}

__device__ __forceinline__ float gelu_f(float v) {
  return 0.5f * v * (1.0f + erff(v * 0.7071067811865476f));
}

// address-space cast helpers for global_load_lds
#define AS1G(p) ((const __attribute__((address_space(1))) void*)(size_t)(p))
#define AS3L(p) ((__attribute__((address_space(3))) void*)(unsigned)(size_t)(p))
#define GLD16(g, l) __builtin_amdgcn_global_load_lds(AS1G(g), AS3L(l), 16, 0, 0)

// ---------------------------------------------------------------- fp32 -> fp16 hi/lo conversion (weights)
__global__ __launch_bounds__(256) void cvt_kernel(const float* __restrict__ X,
                                                  unsigned short* __restrict__ H,
                                                  unsigned short* __restrict__ Lo,
                                                  int n8) {
  int i = blockIdx.x * 256 + threadIdx.x;
  if (i >= n8) return;
  const float4* xp = (const float4*)X + 2 * (size_t)i;
  float4 a = xp[0], b = xp[1];
  float v[8] = {a.x, a.y, a.z, a.w, b.x, b.y, b.z, b.w};
  unsigned hu[4], lu[4];
#pragma unroll
  for (int q = 0; q < 4; ++q) {
    unsigned short h0, l0, h1, l1;
    f2hsplit(v[2 * q], h0, l0);
    f2hsplit(v[2 * q + 1], h1, l1);
    hu[q] = (unsigned)h0 | ((unsigned)h1 << 16);
    lu[q] = (unsigned)l0 | ((unsigned)l1 << 16);
  }
  uint4 hv; hv.x = hu[0]; hv.y = hu[1]; hv.z = hu[2]; hv.w = hu[3];
  uint4 lv; lv.x = lu[0]; lv.y = lu[1]; lv.z = lu[2]; lv.w = lu[3];
  *(uint4*)(H + 8 * (size_t)i) = hv;
  *(uint4*)(Lo + 8 * (size_t)i) = lv;
}

// conv weight pack + split: wp[o][w*512+c] = dw[o][c][w]
__global__ void packw2_kernel(const float* __restrict__ dw,
                              unsigned short* __restrict__ Hh,
                              unsigned short* __restrict__ Hl) {
  int gid = blockIdx.x * 256 + threadIdx.x;  // 512*1536
  int o = gid / 1536;
  int kk = gid - o * 1536;
  int ww = kk / 512;
  int c = kk - ww * 512;
  float v = dw[((size_t)o * 512 + c) * 3 + ww];
  unsigned short h, l;
  f2hsplit(v, h, l);
  Hh[gid] = h;
  Hl[gid] = l;
}

// ---------------------------------------------------------------- MFMA GEMM 128x128, split-fp16 3-product, BK=32
// __launch_bounds__(256,4): acc alone is 64 VGPRs; (256,5) squeezed the
// allocator to 48 VGPRs -> accumulator SPILLED to scratch (r5: 1.78 GB
// HBM traffic/dispatch, 4x slowdown). 4 waves/EU keeps VGPR=64, no spill.
// LDS 32 KB. Swizzle: slot ^= (row>>1)&3 (conflict-free, r4 verified: 6.3M -> 0).
// Source pre-swizzled for linear global_load_lds dest (rule #21).
// PART: K-split partials (raw fp32, no bias/act) -> C + kb*M*N.
template <int ACT, int HASR, int CONV, int F16OUT, int QKV, int PART>
__global__ __launch_bounds__(256, 4) void gemm_mfma(
    const unsigned short* __restrict__ Ah, const unsigned short* __restrict__ Al,
    const unsigned short* __restrict__ Wh, const unsigned short* __restrict__ Wl,
    const float* __restrict__ bias, const float* __restrict__ bias2,
    const float* __restrict__ bias3, const float* __restrict__ Rres,
    float* __restrict__ C, float* __restrict__ C2, float* __restrict__ C3,
    unsigned short* __restrict__ Ch, unsigned short* __restrict__ Cl,
    int N, int K, int Lmask, int ntx, int nty, int kloop) {
  __shared__ __attribute__((aligned(16))) unsigned short AsH[4096];
  __shared__ __attribute__((aligned(16))) unsigned short AsL[4096];
  __shared__ __attribute__((aligned(16))) unsigned short WsH[4096];
  __shared__ __attribute__((aligned(16))) unsigned short WsL[4096];
  const int tid = threadIdx.x;
  int blk = blockIdx.x;
  int kb = 0;
  if (PART) {
    const int tiles = ntx * nty;
    kb = blk / tiles;
    blk -= kb * tiles;
  }
  const int koff = PART ? kb * kloop : 0;
  const int xcd = blk & 7;
  const int j = blk >> 3;
  const int jr = j / ntx;
  const int row_t = xcd * (nty >> 3) + jr;
  const int col_t = j - jr * ntx;
  const int row0 = row_t << 7, col0 = col_t << 7;
  const int lane = tid & 63;
  const int wv = tid >> 6;
  const int wr = wv >> 1, wc = wv & 1;  // wave's 64x64 quadrant
  const int srow = lane >> 2;                          // 0..15
  const int skoff = (((lane & 3) ^ ((lane >> 3) & 3)) << 3);
  const int l15 = lane & 15, lg = lane >> 4;
  const int slotx = ((lg ^ ((l15 >> 1) & 3)) << 4);
  int oa[4], ow[4];
#pragma unroll
  for (int t = 0; t < 4; ++t) {
    oa[t] = (((wr << 6) + (t << 4) + l15) << 6) + slotx;
    ow[t] = (((wc << 6) + (t << 4) + l15) << 6) + slotx;
  }
  f32x4 acc[4][4] = {};
  const int T = (PART ? kloop : K) >> 5;
  for (int it = 0; it < T; ++it) {
    const int k0 = koff + (it << 5);
    int wwin = 0, kc = k0;
    if (CONV) { wwin = k0 >> 9; kc = k0 & 511; }
#pragma unroll
    for (int g = 0; g < 2; ++g) {
      const int R0 = (wv << 5) + (g << 4);
      const int rr = R0 + srow;
      size_t aoff;
      if (CONV) {
        int t0 = row0 + rr;
        int tcv = t0 & Lmask, bb = t0 & ~Lmask;
        int src = bb | ((tcv - 1 + wwin) & Lmask);
        aoff = (size_t)src * 512 + (kc + skoff);
      } else {
        aoff = (size_t)(row0 + rr) * K + (k0 + skoff);
      }
      size_t woff = (size_t)(col0 + rr) * K + (k0 + skoff);
      GLD16(Ah + aoff, AsH + R0 * 32);
      GLD16(Al + aoff, AsL + R0 * 32);
      GLD16(Wh + woff, WsH + R0 * 32);
      GLD16(Wl + woff, WsL + R0 * 32);
    }
    __syncthreads();
    half8 fah[4], fal[4];
#pragma unroll
    for (int t = 0; t < 4; ++t) {
      fah[t] = *(const half8*)((const char*)AsH + oa[t]);
      fal[t] = *(const half8*)((const char*)AsL + oa[t]);
    }
#pragma unroll
    for (int ni = 0; ni < 4; ++ni) {
      half8 bh = *(const half8*)((const char*)WsH + ow[ni]);
      half8 bl = *(const half8*)((const char*)WsL + ow[ni]);
#pragma unroll
      for (int mi = 0; mi < 4; ++mi) {
        acc[mi][ni] = __builtin_amdgcn_mfma_f32_16x16x32_f16(
            fah[mi], bh, acc[mi][ni], 0, 0, 0);
        acc[mi][ni] = __builtin_amdgcn_mfma_f32_16x16x32_f16(
            fah[mi], bl, acc[mi][ni], 0, 0, 0);
        acc[mi][ni] = __builtin_amdgcn_mfma_f32_16x16x32_f16(
            fal[mi], bh, acc[mi][ni], 0, 0, 0);
      }
    }
    __syncthreads();
  }
  // epilogue: D lane mapping col=l15, row=lg*4+q
  if (PART) {
    float* Cp = C + (size_t)kb * ((size_t)(nty << 7)) * N;
#pragma unroll
    for (int mi = 0; mi < 4; ++mi)
#pragma unroll
      for (int q = 0; q < 4; ++q) {
        const int m = row0 + (wr << 6) + (mi << 4) + (lg << 2) + q;
#pragma unroll
        for (int ni = 0; ni < 4; ++ni) {
          const int col = col0 + (wc << 6) + (ni << 4) + l15;
          Cp[(size_t)m * N + col] = acc[mi][ni][q];
        }
      }
    return;
  }
  int cbase = col0;
  float* Cb = C;
  const float* bb = bias;
  if (QKV) {
    const int cb = col0 >> 9;
    cbase = col0 & 511;
    Cb = (cb == 0) ? C : ((cb == 1) ? C2 : C3);
    bb = (cb == 0) ? bias : ((cb == 1) ? bias2 : bias3);
  }
  const int OSTR = QKV ? 512 : N;
  float bsv[4];
#pragma unroll
  for (int ni = 0; ni < 4; ++ni)
    bsv[ni] = bb[cbase + (wc << 6) + (ni << 4) + l15];
#pragma unroll
  for (int mi = 0; mi < 4; ++mi) {
#pragma unroll
    for (int q = 0; q < 4; ++q) {
      const int m = row0 + (wr << 6) + (mi << 4) + (lg << 2) + q;
#pragma unroll
      for (int ni = 0; ni < 4; ++ni) {
        const int col = cbase + (wc << 6) + (ni << 4) + l15;
        float v = acc[mi][ni][q] + bsv[ni];
        if (HASR) v += Rres[(size_t)m * OSTR + col];
        if (ACT == 1) v = gelu_f(v);
        if (F16OUT) {
          unsigned short h, lo;
          f2hsplit(v, h, lo);
          Ch[(size_t)m * OSTR + col] = h;
          Cl[(size_t)m * OSTR + col] = lo;
        } else {
          Cb[(size_t)m * OSTR + col] = v;
        }
      }
    }
  }
}

// ---------------------------------------------------------------- fp32 GEMM (fallback path only)
template <int ACT, int HASR, int CONV, int PART>
__global__ __launch_bounds__(256, 2) void gemm128(
    const float* __restrict__ A, const float* __restrict__ W,
    const float* __restrict__ bias, const float* Rres, float* C,
    int N, int K, int Lmask, int ntx, int nty, int kloop, int ks) {
  __shared__ float As[16][140];
  __shared__ float Ws[16][140];
  const int tid = threadIdx.x;
  int blk = blockIdx.x;
  const int tiles = ntx * nty;
  int kb = 0;
  if (PART) { kb = blk / tiles; blk -= kb * tiles; }
  const int koff = kb * kloop;
  const int xcd = blk & 7;
  const int j = blk >> 3;
  const int jr = j / ntx;
  const int row_t = xcd * (nty >> 3) + jr;
  const int col_t = j - jr * ntx;
  const int row0 = row_t * 128, col0 = col_t * 128;

  const int ar = tid >> 1;
  const int ac = (tid & 1) << 3;
  const int arp = ar + ((ar >> 5) << 2);
  const int tx = tid & 15, ty = tid >> 4;
  const int wcol = tx * 8 + ((tx >> 2) << 2);
  const int acol = ty * 8 + ((ty >> 2) << 2);
  const int arow = row0 + ar;
  const float* Wp = W + (size_t)(col0 + ar) * K + koff + ac;
  const float* Ap = A + (size_t)arow * K + koff + ac;
  int tcv = 0, bbase = 0;
  if (CONV) { tcv = arow & Lmask; bbase = arow & ~Lmask; }
  float4 ra0, ra1, rw0, rw1;
  float acc[8][8] = {};
  const int T = kloop >> 4;

  {
    const float* ap;
    if (CONV) {
      int kabs = koff;
      int w = kabs >> 9;
      int src = bbase | ((tcv - 1 + w) & Lmask);
      ap = A + (size_t)src * 512 + (kabs & 511) + ac;
    } else {
      ap = Ap;
    }
    ra0 = *(const float4*)(ap);
    ra1 = *(const float4*)(ap + 4);
    rw0 = *(const float4*)(Wp);
    rw1 = *(const float4*)(Wp + 4);
  }

  for (int it = 0; it < T; ++it) {
#pragma unroll
    for (int q = 0; q < 4; q++) {
      As[ac + q][arp] = ((float*)&ra0)[q];
      As[ac + 4 + q][arp] = ((float*)&ra1)[q];
      Ws[ac + q][arp] = ((float*)&rw0)[q];
      Ws[ac + 4 + q][arp] = ((float*)&rw1)[q];
    }
    __syncthreads();
    if (it + 1 < T) {
      const int k0 = (it + 1) << 4;
      const float* ap;
      if (CONV) {
        int kabs = koff + k0;
        int w = kabs >> 9;
        int src = bbase | ((tcv - 1 + w) & Lmask);
        ap = A + (size_t)src * 512 + (kabs & 511) + ac;
      } else {
        ap = Ap + k0;
      }
      ra0 = *(const float4*)(ap);
      ra1 = *(const float4*)(ap + 4);
      rw0 = *(const float4*)(Wp + k0);
      rw1 = *(const float4*)(Wp + k0 + 4);
    }
#pragma unroll
    for (int k = 0; k < 16; k++) {
      float av[8], wvv[8];
      *(float4*)(av) = *(const float4*)&As[k][acol];
      *(float4*)(av + 4) = *(const float4*)&As[k][acol + 4];
      *(float4*)(wvv) = *(const float4*)&Ws[k][wcol];
      *(float4*)(wvv + 4) = *(const float4*)&Ws[k][wcol + 4];
#pragma unroll
      for (int i = 0; i < 8; i++)
#pragma unroll
        for (int q = 0; q < 8; q++) acc[i][q] += av[i] * wvv[q];
    }
    __syncthreads();
  }

  if (PART) {
    float* Cp = C + (size_t)kb * (nty << 7) * N;
#pragma unroll
    for (int i = 0; i < 8; i++) {
      const int m = row0 + ty * 8 + i;
      const int c0 = col0 + tx * 8;
      *(float4*)(Cp + (size_t)m * N + c0) = *(float4*)(&acc[i][0]);
      *(float4*)(Cp + (size_t)m * N + c0 + 4) = *(float4*)(&acc[i][4]);
    }
  } else {
#pragma unroll
    for (int i = 0; i < 8; i++) {
      const int m = row0 + ty * 8 + i;
      const int c0 = col0 + tx * 8;
      float vout[8];
#pragma unroll
      for (int q = 0; q < 8; q++) {
        float v = acc[i][q] + bias[c0 + q];
        if (HASR) v += Rres[(size_t)m * N + c0 + q];
        if (ACT == 1) v = gelu_f(v);
        vout[q] = v;
      }
      *(float4*)(C + (size_t)m * N + c0) = *(float4*)(vout);
      *(float4*)(C + (size_t)m * N + c0 + 4) = *(float4*)(vout + 4);
    }
  }
}

template <int HASR>
__global__ __launch_bounds__(256) void combine_kernel(
    const float* __restrict__ part, const float* __restrict__ bias,
    const float* Rres, float* __restrict__ Cout, size_t MN, int ks) {
  size_t gid = (size_t)blockIdx.x * 256 + threadIdx.x;
  int c = (int)(gid & 511);
  float v = 0.f;
  for (int kb = 0; kb < ks; kb++) v += part[kb * MN + gid];
  v += bias[c];
  if (HASR) v += Rres[gid];
  Cout[gid] = v;
}

// ---------------------------------------------------------------- token conv + pos embed (+hi/lo)
template <int EMIT>
__global__ void tokpe_kernel(const float* __restrict__ xe,
                             const float* __restrict__ w,
                             float* __restrict__ out,
                             unsigned short* __restrict__ Hh,
                             unsigned short* __restrict__ Hl, int S) {
  int gid = blockIdx.x * 256 + threadIdx.x;  // B*S*512
  int o = gid & 511;
  int bt = gid >> 9;
  int t = bt % S, b = bt / S;
  float acc = 0.f;
#pragma unroll
  for (int ww = 0; ww < 3; ww++) {
    int tt = t - 1 + ww;
    tt = (tt < 0) ? tt + S : (tt >= S ? tt - S : tt);
    const float* xr = xe + ((size_t)(b * S + tt)) * 7;
#pragma unroll
    for (int i = 0; i < 7; i++) acc += xr[i] * w[o * 21 + i * 3 + ww];
  }
  int i2 = o >> 1;
  float dv = expf((float)(2 * i2) * (-9.210340371976184f / 512.0f));
  float ang = (float)t * dv;
  acc += (o & 1) ? cosf(ang) : sinf(ang);
  out[gid] = acc;
  if (EMIT) {
    unsigned short h, l;
    f2hsplit(acc, h, l);
    Hh[gid] = h;
    Hl[gid] = l;
  }
}

// ---------------------------------------------------------------- conv weight pack (fallback fp32)
__global__ void packw_kernel(const float* __restrict__ dw, float* __restrict__ wp) {
  int gid = blockIdx.x * 256 + threadIdx.x;  // 512*1536
  int o = gid / 1536;
  int kk = gid - o * 1536;
  int ww = kk / 512;
  int c = kk - ww * 512;
  wp[gid] = dw[((size_t)o * 512 + c) * 3 + ww];
}

// ---------------------------------------------------------------- M score, 4 lanes per query
__global__ __launch_bounds__(256) void mscore4_kernel(
    const float* __restrict__ Q, const float* __restrict__ Kb,
    const int* __restrict__ idxb, float* __restrict__ Mout, int L, int U) {
  __shared__ int sidx[64 * 24];
  int i = blockIdx.x;  // b + 8*(h*chunks + c), 64 queries per block
  int b = i & 7;
  int j = i >> 3;
  int chunks = L >> 6;
  int h = j / chunks;
  int c = j - h * chunks;
  int t0 = c << 6;
  int tid = threadIdx.x;
  const int nidx = 64 * U;
  for (int k = tid; k < nidx; k += 256) sidx[k] = idxb[t0 * U + k];
  __syncthreads();
  int tsub = tid >> 2, sub = tid & 3;
  int t = t0 + tsub;
  const float4* qr =
      (const float4*)(Q + ((size_t)(b * L + t)) * DMODEL + h * HD + sub * 16);
  float4 q0 = qr[0], q1 = qr[1], q2 = qr[2], q3 = qr[3];
  const float* Kh = Kb + (size_t)b * L * DMODEL + h * HD + sub * 16;
  float mx = -3.4e38f, sm = 0.f;
  int krn = sidx[tsub * U];
  for (int jj = 0; jj < U; ++jj) {
    const float4* kp = (const float4*)(Kh + (size_t)krn * DMODEL);
    krn = sidx[tsub * U + ((jj + 1 < U) ? jj + 1 : jj)];
    float4 k0 = kp[0], k1 = kp[1], k2 = kp[2], k3 = kp[3];
    float dot = q0.x * k0.x + q0.y * k0.y + q0.z * k0.z + q0.w * k0.w +
                q1.x * k1.x + q1.y * k1.y + q1.z * k1.z + q1.w * k1.w +
                q2.x * k2.x + q2.y * k2.y + q2.z * k2.z + q2.w * k2.w +
                q3.x * k3.x + q3.y * k3.y + q3.z * k3.z + q3.w * k3.w;
    dot += __shfl_xor(dot, 1);
    dot += __shfl_xor(dot, 2);
    mx = fmaxf(mx, dot);
    sm += dot;
  }
  if (sub == 0) Mout[(size_t)(b * 8 + h) * L + t] = mx - sm / (float)L;
}

// ---------------------------------------------------------------- M score (fallback)
__global__ __launch_bounds__(256) void mscore_kernel(
    const float* __restrict__ Q, const float* __restrict__ Kb,
    const int* __restrict__ idxb, float* __restrict__ Mout, int L, int U) {
  int i = blockIdx.x;
  int b = i & 7;
  int j = i >> 3;
  int chunks = L >> 8;
  int h = j / chunks;
  int c = j - h * chunks;
  int t = c * 256 + threadIdx.x;
  const float4* qr = (const float4*)(Q + ((size_t)(b * L + t)) * DMODEL + h * HD);
  float4 qv[16];
#pragma unroll
  for (int ii = 0; ii < 16; ii++) qv[ii] = qr[ii];
  float mx = -3.4e38f, sm = 0.f;
  for (int jj = 0; jj < U; jj++) {
    int kr = idxb[t * U + jj];
    const float4* kp =
        (const float4*)(Kb + ((size_t)(b * L + kr)) * DMODEL + h * HD);
    float dot = 0.f;
#pragma unroll
    for (int ii = 0; ii < 16; ii++) {
      float4 kv = kp[ii];
      dot += qv[ii].x * kv.x + qv[ii].y * kv.y + qv[ii].z * kv.z + qv[ii].w * kv.w;
    }
    mx = fmaxf(mx, dot);
    sm += dot;
  }
  Mout[(size_t)(b * 8 + h) * L + t] = mx - sm / (float)L;
}

// ---------------------------------------------------------------- top-k
__global__ __launch_bounds__(256) void topk_kernel(const float* __restrict__ Mv,
                                                   int* __restrict__ topb, int L,
                                                   int u) {
  __shared__ float wv_s[4];
  __shared__ int wi_s[4];
  __shared__ int best_s;
  int bh = blockIdx.x, tid = threadIdx.x;
  int lane = tid & 63, w = tid >> 6;
  int cnt = L >> 8;
  float lv[8];
  for (int i = 0; i < cnt; i++) lv[i] = Mv[(size_t)bh * L + i * 256 + tid];
  for (int r = 0; r < u; r++) {
    float bv = -3.4e38f;
    int bi = 0x7fffffff;
    for (int i = 0; i < cnt; i++) {
      if (lv[i] > bv) { bv = lv[i]; bi = i * 256 + tid; }
    }
    for (int s = 32; s > 0; s >>= 1) {
      float ov = __shfl_down(bv, s);
      int oi = __shfl_down(bi, s);
      if (ov > bv || (ov == bv && oi < bi)) { bv = ov; bi = oi; }
    }
    if (lane == 0) { wv_s[w] = bv; wi_s[w] = bi; }
    __syncthreads();
    if (tid == 0) {
      float fv = wv_s[0];
      int fi = wi_s[0];
      for (int q = 1; q < 4; q++) {
        if (wv_s[q] > fv || (wv_s[q] == fv && wi_s[q] < fi)) {
          fv = wv_s[q];
          fi = wi_s[q];
        }
      }
      best_s = fi;
      topb[bh * u + r] = fi;
    }
    __syncthreads();
    int win = best_s;
    if ((win & 255) == tid) lv[win >> 8] = -3.4e38f;
  }
}

// ---------------------------------------------------------------- gather selected q rows
__global__ void gatherq_kernel(const float* __restrict__ Q,
                               const int* __restrict__ topb,
                               float* __restrict__ qsel, int L, int u) {
  int i = blockIdx.x;
  int bh = i / u;
  int b = bh >> 3, h = bh & 7;
  int t = topb[i];
  qsel[i * HD + threadIdx.x] =
      Q[((size_t)(b * L + t)) * DMODEL + h * HD + threadIdx.x];
}

// ---------------------------------------------------------------- mean of x rows per batch
__global__ __launch_bounds__(256) void xmean_kernel(const float* __restrict__ x,
                                                    float* __restrict__ psumx,
                                                    int L) {
  int i = blockIdx.x;
  int b = i >> 3, g = i & 7;
  int rows = L >> 3;
  int tid = threadIdx.x;
  const float* base = x + ((size_t)b * L + (size_t)g * rows) * DMODEL;
  float s0 = 0.f, s1 = 0.f;
  for (int t = 0; t < rows; t++) {
    s0 += base[(size_t)t * DMODEL + tid];
    s1 += base[(size_t)t * DMODEL + tid + 256];
  }
  psumx[i * DMODEL + tid] = s0;
  psumx[i * DMODEL + tid + 256] = s1;
}

__global__ __launch_bounds__(256) void mvmake_kernel(
    const float* __restrict__ psumx, const float* __restrict__ Wv,
    const float* __restrict__ bv, const float* __restrict__ Wo,
    const float* __restrict__ bo, float* __restrict__ mvg,
    float* __restrict__ mvWog, int L) {
  __shared__ float xm[512];
  __shared__ float mvs[512];
  int b = blockIdx.x, tid = threadIdx.x;
  float inv = 1.0f / (float)L;
  for (int nn = 0; nn < 2; nn++) {
    int c = tid + nn * 256;
    float s = 0.f;
    for (int g = 0; g < 8; g++) s += psumx[(b * 8 + g) * DMODEL + c];
    xm[c] = s * inv;
  }
  __syncthreads();
  for (int nn = 0; nn < 2; nn++) {
    int n = tid + nn * 256;
    const float* wr = Wv + (size_t)n * 512;
    float s = bv[n];
    for (int k = 0; k < 512; k += 4) {
      float4 w4 = *(const float4*)(wr + k);
      s += xm[k] * w4.x + xm[k + 1] * w4.y + xm[k + 2] * w4.z + xm[k + 3] * w4.w;
    }
    mvs[n] = s;
    mvg[b * DMODEL + n] = s;
  }
  __syncthreads();
  for (int nn = 0; nn < 2; nn++) {
    int n = tid + nn * 256;
    const float* wr = Wo + (size_t)n * 512;
    float s = bo[n];
    for (int k = 0; k < 512; k += 4) {
      float4 w4 = *(const float4*)(wr + k);
      s += mvs[k] * w4.x + mvs[k + 1] * w4.y + mvs[k + 2] * w4.z +
           mvs[k + 3] * w4.w;
    }
    mvWog[b * DMODEL + n] = s;
  }
}

__global__ void x1bcast_kernel(const float* __restrict__ x,
                               const float* __restrict__ mvWog,
                               float* __restrict__ x1, int L) {
  int gid = blockIdx.x * 256 + threadIdx.x;
  int c = gid & 511;
  int r = gid >> 9;
  int b = r / L;
  x1[gid] = x[gid] + mvWog[b * DMODEL + c];
}

// ---------------------------------------------------------------- chunked flash attention for selected rows
__global__ __launch_bounds__(256) void attnflash_kernel(
    const float* __restrict__ qsel, const float* __restrict__ Kb,
    const float* __restrict__ Vb, float* __restrict__ pm,
    float* __restrict__ pl, float* __restrict__ pO, int L, int u, int nchunk) {
  __shared__ float qs[24][64];
  __shared__ float Kt[64][68];
  __shared__ float Ps[24][68];
  int blk = blockIdx.x;
  int bh = blk / nchunk;
  int c = blk - bh * nchunk;
  int b = bh >> 3, h = bh & 7;
  int cs = L / nchunk;
  int tid = threadIdx.x;
  int lane = tid & 63;
  int w = tid >> 6;
  for (int i = tid; i < u * 64; i += 256)
    qs[i >> 6][i & 63] = qsel[(size_t)bh * u * 64 + i];
  float m[6], l[6], O[6];
#pragma unroll
  for (int k = 0; k < 6; k++) { m[k] = -3.4e38f; l[k] = 0.f; O[k] = 0.f; }
  const float* Kbase = Kb + (size_t)b * L * DMODEL + h * HD;
  const float* Vbase = Vb + (size_t)b * L * DMODEL + h * HD;
  const int jrow = tid & 63;
  const int dch = (tid >> 6) << 4;
  for (int j0 = c * cs; j0 < (c + 1) * cs; j0 += 64) {
    __syncthreads();
    const float* kr = Kbase + (size_t)(j0 + jrow) * DMODEL + dch;
    float4 k0 = *(const float4*)(kr);
    float4 k1 = *(const float4*)(kr + 4);
    float4 k2 = *(const float4*)(kr + 8);
    float4 k3 = *(const float4*)(kr + 12);
#pragma unroll
    for (int q = 0; q < 4; q++) {
      Kt[dch + q][jrow] = ((float*)&k0)[q];
      Kt[dch + 4 + q][jrow] = ((float*)&k1)[q];
      Kt[dch + 8 + q][jrow] = ((float*)&k2)[q];
      Kt[dch + 12 + q][jrow] = ((float*)&k3)[q];
    }
    __syncthreads();
#pragma unroll
    for (int k = 0; k < 6; k++) {
      int qi = 4 * k + w;
      if (qi >= u) break;
      float s = 0.f;
#pragma unroll
      for (int d = 0; d < 64; d++) s += qs[qi][d] * Kt[d][lane];
      s *= 0.125f;
      float mx = s;
#pragma unroll
      for (int off = 32; off > 0; off >>= 1)
        mx = fmaxf(mx, __shfl_down(mx, off));
      mx = __shfl(mx, 0);
      float mnew = fmaxf(m[k], mx);
      float p = expf(s - mnew);
      float ps = p;
#pragma unroll
      for (int off = 32; off > 0; off >>= 1) ps += __shfl_down(ps, off);
      ps = __shfl(ps, 0);
      float alpha = expf(m[k] - mnew);
      l[k] = l[k] * alpha + ps;
      m[k] = mnew;
      O[k] *= alpha;
      Ps[qi][lane] = p;
    }
    for (int jj = 0; jj < 64; jj += 4) {
      float v0 = Vbase[(size_t)(j0 + jj) * DMODEL + lane];
      float v1 = Vbase[(size_t)(j0 + jj + 1) * DMODEL + lane];
      float v2 = Vbase[(size_t)(j0 + jj + 2) * DMODEL + lane];
      float v3 = Vbase[(size_t)(j0 + jj + 3) * DMODEL + lane];
#pragma unroll
      for (int k = 0; k < 6; k++) {
        int qi = 4 * k + w;
        if (qi >= u) break;
        O[k] += Ps[qi][jj] * v0 + Ps[qi][jj + 1] * v1 + Ps[qi][jj + 2] * v2 +
                Ps[qi][jj + 3] * v3;
      }
    }
  }
#pragma unroll
  for (int k = 0; k < 6; k++) {
    int qi = 4 * k + w;
    if (qi < u) {
      int p = (bh * nchunk + c) * u + qi;
      if (lane == 0) { pm[p] = m[k]; pl[p] = l[k]; }
      pO[(size_t)p * 64 + lane] = O[k];
    }
  }
}

__global__ __launch_bounds__(256) void deltaWo_kernel(
    const float* __restrict__ pm, const float* __restrict__ pl,
    const float* __restrict__ pO, const float* __restrict__ mvg,
    const int* __restrict__ topb, const float* __restrict__ Wo, float* x1,
    int L, int u, int nchunk) {
  __shared__ float ds[64];
  int sel = blockIdx.x;
  int bh = sel / u;
  int qi = sel - bh * u;
  int b = bh >> 3, h = bh & 7;
  int t = topb[sel];
  int tid = threadIdx.x;
  if (tid < 64) {
    float mstar = -3.4e38f;
    for (int c = 0; c < nchunk; c++)
      mstar = fmaxf(mstar, pm[(bh * nchunk + c) * u + qi]);
    float lstar = 0.f, O = 0.f;
    for (int c = 0; c < nchunk; c++) {
      int p = (bh * nchunk + c) * u + qi;
      float wgt = expf(pm[p] - mstar);
      lstar += wgt * pl[p];
      O += wgt * pO[(size_t)p * 64 + tid];
    }
    ds[tid] = O / lstar - mvg[b * DMODEL + h * HD + tid];
  }
  __syncthreads();
  float* row = x1 + ((size_t)(b * L + t)) * DMODEL;
  for (int nn = 0; nn < 2; nn++) {
    int n = tid + nn * 256;
    const float* wr = Wo + (size_t)n * 512 + h * HD;
    float a = 0.f;
#pragma unroll
    for (int k = 0; k < 64; k += 4) {
      float4 w4 = *(const float4*)(wr + k);
      a += ds[k] * w4.x + ds[k + 1] * w4.y + ds[k + 2] * w4.z + ds[k + 3] * w4.w;
    }
    atomicAdd(row + n, a);
  }
}

// ---------------------------------------------------------------- layernorm (512 cols; wave-shuffle reduce; optional hi/lo emit; optional bcast add)
template <int EMIT, int ADDB>
__global__ __launch_bounds__(256) void ln_kernel(const float* __restrict__ X,
                                                 const float* __restrict__ g,
                                                 const float* __restrict__ bta,
                                                 float* __restrict__ Y,
                                                 unsigned short* __restrict__ Hh,
                                                 unsigned short* __restrict__ Hl,
                                                 const float* __restrict__ mvW,
                                                 int Lr) {
  __shared__ float ws[4];
  __shared__ float ws2[4];
  int row = blockIdx.x, tid = threadIdx.x;
  int lane = tid & 63, w = tid >> 6;
  size_t base = (size_t)row * DMODEL;
  float x0 = X[base + tid], x1 = X[base + tid + 256];
  if (ADDB) {
    int b = row / Lr;
    x0 += mvW[b * DMODEL + tid];
    x1 += mvW[b * DMODEL + tid + 256];
  }
  float s = x0 + x1;
#pragma unroll
  for (int off = 32; off > 0; off >>= 1) s += __shfl_xor(s, off);
  if (lane == 0) ws[w] = s;
  __syncthreads();
  float mean = (ws[0] + ws[1] + ws[2] + ws[3]) * (1.0f / 512.0f);
  float d0 = x0 - mean, d1 = x1 - mean;
  float q = d0 * d0 + d1 * d1;
#pragma unroll
  for (int off = 32; off > 0; off >>= 1) q += __shfl_xor(q, off);
  if (lane == 0) ws2[w] = q;
  __syncthreads();
  float inv =
      1.0f / sqrtf((ws2[0] + ws2[1] + ws2[2] + ws2[3]) * (1.0f / 512.0f) + 1e-5f);
  float y0 = d0 * inv * g[tid] + bta[tid];
  float y1 = d1 * inv * g[tid + 256] + bta[tid + 256];
  Y[base + tid] = y0;
  Y[base + tid + 256] = y1;
  if (EMIT) {
    unsigned short h, l;
    f2hsplit(y0, h, l);
    Hh[base + tid] = h;
    Hl[base + tid] = l;
    f2hsplit(y1, h, l);
    Hh[base + tid + 256] = h;
    Hl[base + tid + 256] = l;
  }
}

// ---------------------------------------------------------------- combine K-split partials + residual + LN2, fused (per 4096-row chunk)
// z = sum_kb part + bias + resid (exact combine order); y = LN(z; g, bta).
// EMIT=1: write hi/lo only (P1, conv input — LN2's fp32 out is dead for l<2).
// EMIT=0: write fp32 Y only (l=2 path; lnf reads it).
template <int EMIT>
__global__ __launch_bounds__(256) void lncomb_kernel(
    const float* __restrict__ part, const float* __restrict__ bias,
    const float* __restrict__ resid, const float* __restrict__ g,
    const float* __restrict__ bta, float* __restrict__ Y,
    unsigned short* __restrict__ Hh, unsigned short* __restrict__ Hl, int r0,
    size_t MNc) {
  __shared__ float ws[4];
  __shared__ float ws2[4];
  int lrow = blockIdx.x, tid = threadIdx.x;
  int lane = tid & 63, w = tid >> 6;
  size_t lbase = (size_t)lrow * DMODEL;
  size_t gbase = (size_t)(r0 + lrow) * DMODEL;
  float x0 = 0.f, x1 = 0.f;
  for (int kb = 0; kb < 4; kb++) {
    x0 += part[kb * MNc + lbase + tid];
    x1 += part[kb * MNc + lbase + tid + 256];
  }
  x0 += bias[tid];
  x1 += bias[tid + 256];
  x0 += resid[gbase + tid];
  x1 += resid[gbase + tid + 256];
  float s = x0 + x1;
#pragma unroll
  for (int off = 32; off > 0; off >>= 1) s += __shfl_xor(s, off);
  if (lane == 0) ws[w] = s;
  __syncthreads();
  float mean = (ws[0] + ws[1] + ws[2] + ws[3]) * (1.0f / 512.0f);
  float d0 = x0 - mean, d1 = x1 - mean;
  float q = d0 * d0 + d1 * d1;
#pragma unroll
  for (int off = 32; off > 0; off >>= 1) q += __shfl_xor(q, off);
  if (lane == 0) ws2[w] = q;
  __syncthreads();
  float inv =
      1.0f / sqrtf((ws2[0] + ws2[1] + ws2[2] + ws2[3]) * (1.0f / 512.0f) + 1e-5f);
  float y0 = d0 * inv * g[tid] + bta[tid];
  float y1 = d1 * inv * g[tid + 256] + bta[tid + 256];
  if (EMIT) {
    unsigned short h, l;
    f2hsplit(y0, h, l);
    Hh[gbase + tid] = h;
    Hl[gbase + tid] = l;
    f2hsplit(y1, h, l);
    Hh[gbase + tid + 256] = h;
    Hl[gbase + tid + 256] = l;
  } else {
    Y[gbase + tid] = y0;
    Y[gbase + tid + 256] = y1;
  }
}

// ---------------------------------------------------------------- BN stats + pool
__global__ __launch_bounds__(256) void bnpart_kernel(const float* __restrict__ z,
                                                     float* __restrict__ psum,
                                                     float* __restrict__ psq,
                                                     int rowsPer) {
  int blk = blockIdx.x, tid = threadIdx.x;
  size_t r0 = (size_t)blk * rowsPer;
  float s0 = 0, q0 = 0, s1 = 0, q1 = 0;
  for (int r = 0; r < rowsPer; r++) {
    const float* zp = z + (r0 + r) * DMODEL;
    float a = zp[tid];
    s0 += a; q0 += a * a;
    float c = zp[tid + 256];
    s1 += c; q1 += c * c;
  }
  psum[blk * DMODEL + tid] = s0;
  psum[blk * DMODEL + tid + 256] = s1;
  psq[blk * DMODEL + tid] = q0;
  psq[blk * DMODEL + tid + 256] = q1;
}

__global__ void bnfin_kernel(const float* __restrict__ psum,
                             const float* __restrict__ psq, float* __restrict__ mu,
                             float* __restrict__ var, int nb, int Rtot) {
  int c = blockIdx.x * 256 + threadIdx.x;
  float s = 0, q = 0;
  for (int b = 0; b < nb; b++) {
    s += psum[b * DMODEL + c];
    q += psq[b * DMODEL + c];
  }
  float m = s / (float)Rtot;
  mu[c] = m;
  var[c] = fmaxf(q / (float)Rtot - m * m, 0.f);
}

template <int EMIT>
__global__ void bnpool_kernel(const float* __restrict__ z,
                              const float* __restrict__ mu,
                              const float* __restrict__ var,
                              const float* __restrict__ g,
                              const float* __restrict__ bta,
                              float* __restrict__ out,
                              unsigned short* __restrict__ Hh,
                              unsigned short* __restrict__ Hl, int L) {
  int gid = blockIdx.x * 256 + threadIdx.x;
  int c = gid & 511;
  int bt = gid >> 9;
  int L2 = L >> 1;
  int t2 = bt % L2, b = bt / L2;
  float m = mu[c];
  float inv = 1.0f / sqrtf(var[c] + 1e-5f);
  float gg = g[c], bb = bta[c];
  float best = -3.4e38f;
#pragma unroll
  for (int ww = 0; ww < 3; ww++) {
    int t = 2 * t2 - 1 + ww;
    if (t < 0 || t >= L) continue;
    float yv = (z[((size_t)(b * L + t)) * DMODEL + c] - m) * inv * gg + bb;
    yv = (yv > 0.f) ? yv : expm1f(yv);
    best = fmaxf(best, yv);
  }
  out[gid] = best;
  if (EMIT) {
    unsigned short h, l;
    f2hsplit(best, h, l);
    Hh[gid] = h;
    Hl[gid] = l;
  }
}

// ---------------------------------------------------------------- final projection (512 -> 7)
__global__ __launch_bounds__(64) void end_kernel(const float* __restrict__ xn,
                                                 const float* __restrict__ ew,
                                                 const float* __restrict__ eb,
                                                 float* __restrict__ out) {
  __shared__ float xs[512];
  __shared__ float red[64];
  int row = blockIdx.x, tid = threadIdx.x;
#pragma unroll
  for (int i = 0; i < 8; i++) xs[tid + 64 * i] = xn[(size_t)row * DMODEL + tid + 64 * i];
  __syncthreads();
  for (int c = 0; c < 7; c++) {
    float p = 0.f;
    for (int d = tid; d < 512; d += 64) p += xs[d] * ew[c * DMODEL + d];
    red[tid] = p;
    __syncthreads();
    for (int s = 32; s > 0; s >>= 1) {
      if (tid < s) red[tid] += red[tid + s];
      __syncthreads();
    }
    if (tid == 0) out[row * 7 + c] = red[0] + eb[c];
    __syncthreads();
  }
}

// ---------------------------------------------------------------- host
extern "C" void kernel_launch(void* const* d_in, const int* in_sizes, int n_in,
                              void* d_out, int out_size, void* d_ws,
                              size_t ws_size, hipStream_t stream) {
  (void)in_sizes; (void)n_in; (void)out_size;
  const float* x_enc = (const float*)d_in[0];
  const float* tok_w = (const float*)d_in[1];
  const float* Wq = (const float*)d_in[2];
  const float* bq = (const float*)d_in[3];
  const float* Wk = (const float*)d_in[4];
  const float* bk = (const float*)d_in[5];
  const float* Wv = (const float*)d_in[6];
  const float* bv = (const float*)d_in[7];
  const float* Wo = (const float*)d_in[8];
  const float* bo = (const float*)d_in[9];
  const float* w1 = (const float*)d_in[10];
  const float* b1 = (const float*)d_in[11];
  const float* w2 = (const float*)d_in[12];
  const float* b2 = (const float*)d_in[13];
  const float* g1 = (const float*)d_in[14];
  const float* be1 = (const float*)d_in[15];
  const float* g2 = (const float*)d_in[16];
  const float* be2 = (const float*)d_in[17];
  const float* dw = (const float*)d_in[18];
  const float* db = (const float*)d_in[19];
  const float* bng = (const float*)d_in[20];
  const float* bnb = (const float*)d_in[21];
  const float* lnfg = (const float*)d_in[22];
  const float* lnfb = (const float*)d_in[23];
  const float* endw = (const float*)d_in[24];
  const float* endb = (const float*)d_in[25];
  float* out = (float*)d_out;
  char* ws = (char*)d_ws;

  const int B = 8;
  const int S = 2048;
  const int Uarr[3] = {24, 21, 21};
  const int NCHMAX = 32;

  // ---- MFMA-path arena ----
  size_t o = 0;
  float* buf0 = (float*)(ws + o); o += (size_t)16384 * 512 * 4;
  float* qbuf = (float*)(ws + o); o += (size_t)16384 * 512 * 4;
  float* kbuf = (float*)(ws + o); o += (size_t)16384 * 512 * 4;
  float* Mb    = (float*)(ws + o); o += (size_t)64 * 2048 * 4;
  int*   idxb  = (int*)(ws + o);   o += (size_t)2048 * 24 * 4;
  int*   topb  = (int*)(ws + o);   o += 8192;
  float* qsel  = (float*)(ws + o); o += (size_t)64 * 24 * 64 * 4;
  float* mvg   = (float*)(ws + o); o += (size_t)8 * 512 * 4;
  float* mvWog = (float*)(ws + o); o += (size_t)8 * 512 * 4;
  float* psumx = (float*)(ws + o); o += (size_t)64 * 512 * 4;
  float* psum  = (float*)(ws + o); o += (size_t)128 * 512 * 4;
  float* psq   = (float*)(ws + o); o += (size_t)128 * 512 * 4;
  float* muv   = (float*)(ws + o); o += 2048;
  float* varv  = (float*)(ws + o); o += 2048;
  float* pmb   = (float*)(ws + o); o += (size_t)64 * NCHMAX * 24 * 4;
  float* plb   = (float*)(ws + o); o += (size_t)64 * NCHMAX * 24 * 4;
  float* pOb   = (float*)(ws + o); o += (size_t)64 * NCHMAX * 24 * 64 * 4;
  unsigned short* P1h = (unsigned short*)(ws + o); o += (size_t)16384 * 512 * 2;
  unsigned short* P1l = (unsigned short*)(ws + o); o += (size_t)16384 * 512 * 2;
  unsigned short* P2h = (unsigned short*)(ws + o); o += (size_t)16384 * 512 * 2;
  unsigned short* P2l = (unsigned short*)(ws + o); o += (size_t)16384 * 512 * 2;
  unsigned short* Wqkvh = (unsigned short*)(ws + o); o += (size_t)1536 * 512 * 2;
  unsigned short* Wqkvl = (unsigned short*)(ws + o); o += (size_t)1536 * 512 * 2;
  unsigned short* w1h = (unsigned short*)(ws + o); o += (size_t)2048 * 512 * 2;
  unsigned short* w1l = (unsigned short*)(ws + o); o += (size_t)2048 * 512 * 2;
  unsigned short* w2h = (unsigned short*)(ws + o); o += (size_t)512 * 2048 * 2;
  unsigned short* w2l = (unsigned short*)(ws + o); o += (size_t)512 * 2048 * 2;
  unsigned short* wph = (unsigned short*)(ws + o); o += (size_t)512 * 1536 * 2;
  unsigned short* wpl = (unsigned short*)(ws + o); o += (size_t)512 * 1536 * 2;
  const bool use_mfma = (ws_size >= o);
  float* vbuf = (float*)(ws + o); o += (size_t)16384 * 512 * 4;
  const bool fuseqkv = (ws_size >= o);
  unsigned short* CHh = (unsigned short*)(ws + o); o += (size_t)16384 * 2048 * 2;
  unsigned short* CHl = (unsigned short*)(ws + o); o += (size_t)16384 * 2048 * 2;
  const bool fullffn = (ws_size >= o);
  // chunked-FFN scratch (aliased over dead buffers):
  //  fuseqkv: CH chunk (33.5 MB) -> vbuf (V dead after attnflash);
  //           FFN2 K-split partials (33.5 MB) -> kbuf (K dead; z never built)
  //  !fuseqkv fallback: CH chunk -> buf0, partials -> P1 region (round-3 layout)
  unsigned short* CHb0 = (unsigned short*)buf0;
  float* partmP1 = (float*)P1h;
  unsigned short* CHv = (unsigned short*)vbuf;
  float* partk = kbuf;

  if (use_mfma) {
    tokpe_kernel<1><<<B * S * DMODEL / 256, 256, 0, stream>>>(x_enc, tok_w,
                                                              buf0, P1h, P1l, S);
    int L = S;
    for (int l = 0; l < 3; l++) {
      int U = Uarr[l];
      int u = Uarr[l];
      int BL = B * L;
      int nty = BL >> 7;
      int nch = L >> 6;
      if (nch > NCHMAX) nch = NCHMAX;
      idx_kernel<<<(L * U + 255) / 256, 256, 0, stream>>>(idxb, L * U, l, L - 1);
      // weights -> packed fp16 hi/lo
      cvt_kernel<<<128, 256, 0, stream>>>(Wq + (size_t)l * 262144, Wqkvh, Wqkvl, 32768);
      cvt_kernel<<<128, 256, 0, stream>>>(Wk + (size_t)l * 262144, Wqkvh + 262144,
                                          Wqkvl + 262144, 32768);
      cvt_kernel<<<128, 256, 0, stream>>>(Wv + (size_t)l * 262144, Wqkvh + 524288,
                                          Wqkvl + 524288, 32768);
      if (fuseqkv) {
        gemm_mfma<0, 0, 0, 0, 1, 0><<<12 * nty, 256, 0, stream>>>(
            P1h, P1l, Wqkvh, Wqkvl, bq + l * 512, bk + l * 512, bv + l * 512,
            nullptr, qbuf, kbuf, vbuf, nullptr, nullptr, 1536, 512, 0, 12, nty,
            512);
      } else {
        gemm_mfma<0, 0, 0, 0, 0, 0><<<4 * nty, 256, 0, stream>>>(
            P1h, P1l, Wqkvh, Wqkvl, bq + l * 512, nullptr, nullptr, nullptr,
            qbuf, nullptr, nullptr, nullptr, nullptr, 512, 512, 0, 4, nty, 512);
        gemm_mfma<0, 0, 0, 0, 0, 0><<<4 * nty, 256, 0, stream>>>(
            P1h, P1l, Wqkvh + 262144, Wqkvl + 262144, bk + l * 512, nullptr,
            nullptr, nullptr, kbuf, nullptr, nullptr, nullptr, nullptr, 512,
            512, 0, 4, nty, 512);
      }
      mscore4_kernel<<<64 * (L >> 6), 256, 0, stream>>>(qbuf, kbuf, idxb, Mb, L, U);
      topk_kernel<<<64, 256, 0, stream>>>(Mb, topb, L, u);
      gatherq_kernel<<<64 * u, 64, 0, stream>>>(qbuf, topb, qsel, L, u);
      xmean_kernel<<<64, 256, 0, stream>>>(buf0, psumx, L);
      mvmake_kernel<<<8, 256, 0, stream>>>(psumx, Wv + (size_t)l * 262144,
                                           bv + l * 512, Wo + (size_t)l * 262144,
                                           bo + l * 512, mvg, mvWog, L);
      const float* Vb;
      if (fuseqkv) {
        Vb = vbuf;
      } else {
        gemm_mfma<0, 0, 0, 0, 0, 0><<<4 * nty, 256, 0, stream>>>(
            P1h, P1l, Wqkvh + 524288, Wqkvl + 524288, bv + l * 512, nullptr,
            nullptr, nullptr, qbuf, nullptr, nullptr, nullptr, nullptr, 512,
            512, 0, 4, nty, 512);
        Vb = qbuf;
      }
      attnflash_kernel<<<64 * nch, 256, 0, stream>>>(qsel, kbuf, Vb, pmb, plb,
                                                     pOb, L, u, nch);
      // delta accumulates straight into x (buf0); mvWo broadcast folded into LN1
      deltaWo_kernel<<<64 * u, 256, 0, stream>>>(pmb, plb, pOb, mvg, topb,
                                                 Wo + (size_t)l * 262144, buf0, L,
                                                 u, nch);
      // xa = LN1(x + delta + mvWo) -> qbuf (+hi/lo -> P2); buf0 x now dead
      ln_kernel<1, 1><<<BL, 256, 0, stream>>>(buf0, g1 + l * 512, be1 + l * 512,
                                              qbuf, P2h, P2l, mvWog, L);
      cvt_kernel<<<512, 256, 0, stream>>>(w1 + (size_t)l * 1048576, w1h, w1l, 131072);
      cvt_kernel<<<512, 256, 0, stream>>>(w2 + (size_t)l * 1048576, w2h, w2l, 131072);
      if (fullffn) {
        gemm_mfma<1, 0, 0, 1, 0, 0><<<16 * nty, 256, 0, stream>>>(
            P2h, P2l, w1h, w1l, b1 + l * 2048, nullptr, nullptr, nullptr,
            nullptr, nullptr, nullptr, CHh, CHl, 2048, 512, 0, 16, nty, 512);
        gemm_mfma<0, 1, 0, 0, 0, 0><<<4 * nty, 256, 0, stream>>>(
            CHh, CHl, w2h, w2l, b2 + l * 512, nullptr, nullptr, qbuf, kbuf,
            nullptr, nullptr, nullptr, nullptr, 512, 2048, 0, 4, nty, 2048);
        if (l < 2) {
          ln_kernel<1, 0><<<BL, 256, 0, stream>>>(kbuf, g2 + l * 512,
                                                  be2 + l * 512, buf0, P1h, P1l,
                                                  nullptr, 1);
        } else {
          ln_kernel<0, 0><<<BL, 256, 0, stream>>>(kbuf, g2 + l * 512,
                                                  be2 + l * 512, buf0, nullptr,
                                                  nullptr, nullptr, 1);
        }
      } else if (fuseqkv) {
        // chunked FFN + fused combine/LN2: CH -> vbuf, partials -> kbuf.
        unsigned short* CHvl = CHv + (size_t)4096 * 2048;
        for (int r0 = 0; r0 < BL; r0 += 4096) {
          gemm_mfma<1, 0, 0, 1, 0, 0><<<16 * 32, 256, 0, stream>>>(
              P2h + (size_t)r0 * 512, P2l + (size_t)r0 * 512, w1h, w1l,
              b1 + l * 2048, nullptr, nullptr, nullptr, nullptr, nullptr,
              nullptr, CHv, CHvl, 2048, 512, 0, 16, 32, 512);
          gemm_mfma<0, 0, 0, 0, 0, 1><<<4 * 32 * 4, 256, 0, stream>>>(
              CHv, CHvl, w2h, w2l, nullptr, nullptr, nullptr, nullptr, partk,
              nullptr, nullptr, nullptr, nullptr, 512, 2048, 0, 4, 32, 512);
          if (l < 2) {
            lncomb_kernel<1><<<4096, 256, 0, stream>>>(
                partk, b2 + l * 512, qbuf, g2 + l * 512, be2 + l * 512, nullptr,
                P1h, P1l, r0, (size_t)4096 * 512);
          } else {
            lncomb_kernel<0><<<4096, 256, 0, stream>>>(
                partk, b2 + l * 512, qbuf, g2 + l * 512, be2 + l * 512, buf0,
                nullptr, nullptr, r0, (size_t)4096 * 512);
          }
        }
      } else {
        // fallback chunked path (round-3 layout): CH -> buf0, partials -> P1
        unsigned short* CHlch = CHb0 + (size_t)4096 * 2048;
        for (int r0 = 0; r0 < BL; r0 += 4096) {
          gemm_mfma<1, 0, 0, 1, 0, 0><<<16 * 32, 256, 0, stream>>>(
              P2h + (size_t)r0 * 512, P2l + (size_t)r0 * 512, w1h, w1l,
              b1 + l * 2048, nullptr, nullptr, nullptr, nullptr, nullptr,
              nullptr, CHb0, CHlch, 2048, 512, 0, 16, 32, 512);
          gemm_mfma<0, 0, 0, 0, 0, 1><<<4 * 32 * 4, 256, 0, stream>>>(
              CHb0, CHlch, w2h, w2l, nullptr, nullptr, nullptr, nullptr,
              partmP1, nullptr, nullptr, nullptr, nullptr, 512, 2048, 0, 4, 32,
              512);
          combine_kernel<1><<<4096 * 512 / 256, 256, 0, stream>>>(
              partmP1, b2 + l * 512, qbuf + (size_t)r0 * 512,
              kbuf + (size_t)r0 * 512, (size_t)4096 * 512, 4);
        }
        if (l < 2) {
          ln_kernel<1, 0><<<BL, 256, 0, stream>>>(kbuf, g2 + l * 512,
                                                  be2 + l * 512, buf0, P1h, P1l,
                                                  nullptr, 1);
        } else {
          ln_kernel<0, 0><<<BL, 256, 0, stream>>>(kbuf, g2 + l * 512,
                                                  be2 + l * 512, buf0, nullptr,
                                                  nullptr, nullptr, 1);
        }
      }
      if (l < 2) {
        packw2_kernel<<<512 * 1536 / 256, 256, 0, stream>>>(
            dw + (size_t)l * 512 * 512 * 3, wph, wpl);
        gemm_mfma<0, 0, 1, 0, 0, 0><<<4 * nty, 256, 0, stream>>>(
            P1h, P1l, wph, wpl, db + l * 512, nullptr, nullptr, nullptr, kbuf,
            nullptr, nullptr, nullptr, nullptr, 512, 1536, L - 1, 4, nty, 1536);
        int nb = BL / 128;
        bnpart_kernel<<<nb, 256, 0, stream>>>(kbuf, psum, psq, 128);
        bnfin_kernel<<<2, 256, 0, stream>>>(psum, psq, muv, varv, nb, BL);
        bnpool_kernel<1><<<(BL / 2) * 512 / 256, 256, 0, stream>>>(
            kbuf, muv, varv, bng + l * 512, bnb + l * 512, buf0, P1h, P1l, L);
        L >>= 1;
      }
    }
    int BL = B * L;  // 4096
    ln_kernel<0, 0><<<BL, 256, 0, stream>>>(buf0, lnfg, lnfb, qbuf, nullptr,
                                            nullptr, nullptr, 1);
    end_kernel<<<BL, 64, 0, stream>>>(qbuf, endw, endb, out);
    return;
  }

  // ================= fallback: verified fp32 path =================
  {
    const int NCH = 8;
    size_t o2 = 0;
    float* buf0f = (float*)(ws + o2); o2 += (size_t)16384 * 512 * 4;
    float* qbuff = (float*)(ws + o2); o2 += (size_t)16384 * 512 * 4;
    float* kbuff = (float*)(ws + o2); o2 += (size_t)16384 * 512 * 4;
    float* wpack = (float*)(ws + o2); o2 += (size_t)512 * 1536 * 4;
    float* Mbf    = (float*)(ws + o2); o2 += (size_t)64 * 2048 * 4;
    int*   idxbf  = (int*)(ws + o2);   o2 += (size_t)2048 * 24 * 4;
    int*   topbf  = (int*)(ws + o2);   o2 += 8192;
    float* qself  = (float*)(ws + o2); o2 += (size_t)64 * 24 * 64 * 4;
    float* mvgf   = (float*)(ws + o2); o2 += (size_t)8 * 512 * 4;
    float* mvWogf = (float*)(ws + o2); o2 += (size_t)8 * 512 * 4;
    float* psumxf = (float*)(ws + o2); o2 += (size_t)64 * 512 * 4;
    float* psumf  = (float*)(ws + o2); o2 += (size_t)128 * 512 * 4;
    float* psqf   = (float*)(ws + o2); o2 += (size_t)128 * 512 * 4;
    float* muvf   = (float*)(ws + o2); o2 += 2048;
    float* varvf  = (float*)(ws + o2); o2 += 2048;
    float* pmbf   = (float*)(ws + o2); o2 += (size_t)64 * NCH * 24 * 4;
    float* plbf   = (float*)(ws + o2); o2 += (size_t)64 * NCH * 24 * 4;
    float* pObf   = (float*)(ws + o2); o2 += (size_t)64 * NCH * 24 * 64 * 4;
    float* partb  = (float*)(ws + o2); o2 += (size_t)4 * 4096 * 2048;
    const bool uks = (ws_size >= o2);

    tokpe_kernel<0><<<B * S * DMODEL / 256, 256, 0, stream>>>(
        x_enc, tok_w, buf0f, nullptr, nullptr, S);
    int L = S;
    for (int l = 0; l < 3; l++) {
      int U = Uarr[l];
      int u = U;
      int BL = B * L;
      int nty = BL / 128;
      size_t MN = (size_t)BL * 512;
      int gq = 4 * nty;
      int ksq = (gq >= 512 || !uks) ? 1 : (512 / gq);
      idx_kernel<<<(L * U + 255) / 256, 256, 0, stream>>>(idxbf, L * U, l, L - 1);
      if (ksq == 1) {
        gemm128<0, 0, 0, 0><<<gq, 256, 0, stream>>>(
            buf0f, Wq + (size_t)l * 262144, bq + l * 512, nullptr, qbuff, 512,
            512, 0, 4, nty, 512, 1);
        gemm128<0, 0, 0, 0><<<gq, 256, 0, stream>>>(
            buf0f, Wk + (size_t)l * 262144, bk + l * 512, nullptr, kbuff, 512,
            512, 0, 4, nty, 512, 1);
      } else {
        gemm128<0, 0, 0, 1><<<gq * ksq, 256, 0, stream>>>(
            buf0f, Wq + (size_t)l * 262144, nullptr, nullptr, partb, 512, 512, 0,
            4, nty, 512 / ksq, ksq);
        combine_kernel<0><<<(unsigned)(MN / 256), 256, 0, stream>>>(
            partb, bq + l * 512, nullptr, qbuff, MN, ksq);
        gemm128<0, 0, 0, 1><<<gq * ksq, 256, 0, stream>>>(
            buf0f, Wk + (size_t)l * 262144, nullptr, nullptr, partb, 512, 512, 0,
            4, nty, 512 / ksq, ksq);
        combine_kernel<0><<<(unsigned)(MN / 256), 256, 0, stream>>>(
            partb, bk + l * 512, nullptr, kbuff, MN, ksq);
      }
      mscore_kernel<<<8 * 8 * L / 256, 256, 0, stream>>>(qbuff, kbuff, idxbf, Mbf, L, U);
      topk_kernel<<<64, 256, 0, stream>>>(Mbf, topbf, L, u);
      gatherq_kernel<<<64 * u, 64, 0, stream>>>(qbuff, topbf, qself, L, u);
      xmean_kernel<<<64, 256, 0, stream>>>(buf0f, psumxf, L);
      mvmake_kernel<<<8, 256, 0, stream>>>(psumxf, Wv + (size_t)l * 262144,
                                           bv + l * 512, Wo + (size_t)l * 262144,
                                           bo + l * 512, mvgf, mvWogf, L);
      if (ksq == 1) {
        gemm128<0, 0, 0, 0><<<gq, 256, 0, stream>>>(
            buf0f, Wv + (size_t)l * 262144, bv + l * 512, nullptr, qbuff, 512,
            512, 0, 4, nty, 512, 1);
      } else {
        gemm128<0, 0, 0, 1><<<gq * ksq, 256, 0, stream>>>(
            buf0f, Wv + (size_t)l * 262144, nullptr, nullptr, partb, 512, 512, 0,
            4, nty, 512 / ksq, ksq);
        combine_kernel<0><<<(unsigned)(MN / 256), 256, 0, stream>>>(
            partb, bv + l * 512, nullptr, qbuff, MN, ksq);
      }
      attnflash_kernel<<<64 * NCH, 256, 0, stream>>>(qself, kbuff, qbuff, pmbf,
                                                     plbf, pObf, L, u, NCH);
      x1bcast_kernel<<<(unsigned)(MN / 256), 256, 0, stream>>>(buf0f, mvWogf, kbuff, L);
      deltaWo_kernel<<<64 * u, 256, 0, stream>>>(pmbf, plbf, pObf, mvgf, topbf,
                                                 Wo + (size_t)l * 262144, kbuff,
                                                 L, u, NCH);
      ln_kernel<0, 0><<<BL, 256, 0, stream>>>(kbuff, g1 + l * 512, be1 + l * 512,
                                              qbuff, nullptr, nullptr, nullptr, 1);
      for (int r0 = 0; r0 < BL; r0 += 4096) {
        gemm128<1, 0, 0, 0><<<16 * 32, 256, 0, stream>>>(
            qbuff + (size_t)r0 * 512, w1 + (size_t)l * 2048 * 512, b1 + l * 2048,
            nullptr, buf0f, 2048, 512, 0, 16, 32, 512, 1);
        if (uks) {
          gemm128<0, 0, 0, 1><<<4 * 32 * 4, 256, 0, stream>>>(
              buf0f, w2 + (size_t)l * 512 * 2048, nullptr, nullptr, partb, 512,
              2048, 0, 4, 32, 512, 4);
          combine_kernel<1><<<4096 * 512 / 256, 256, 0, stream>>>(
              partb, b2 + l * 512, qbuff + (size_t)r0 * 512,
              kbuff + (size_t)r0 * 512, (size_t)4096 * 512, 4);
        } else {
          gemm128<0, 1, 0, 0><<<4 * 32, 256, 0, stream>>>(
              buf0f, w2 + (size_t)l * 512 * 2048, b2 + l * 512,
              qbuff + (size_t)r0 * 512, kbuff + (size_t)r0 * 512, 512, 2048, 0,
              4, 32, 2048, 1);
        }
      }
      ln_kernel<0, 0><<<BL, 256, 0, stream>>>(kbuff, g2 + l * 512, be2 + l * 512,
                                              buf0f, nullptr, nullptr, nullptr, 1);

      if (l < 2) {
        packw_kernel<<<512 * 1536 / 256, 256, 0, stream>>>(
            dw + (size_t)l * 512 * 512 * 3, wpack);
        int ksc = (gq >= 512 || !uks) ? 1 : 2;
        if (ksc == 1) {
          gemm128<0, 0, 1, 0><<<gq, 256, 0, stream>>>(
              buf0f, wpack, db + l * 512, nullptr, kbuff, 512, 1536, L - 1, 4,
              nty, 1536, 1);
        } else {
          gemm128<0, 0, 1, 1><<<gq * 2, 256, 0, stream>>>(
              buf0f, wpack, nullptr, nullptr, partb, 512, 1536, L - 1, 4, nty,
              768, 2);
          combine_kernel<0><<<(unsigned)(MN / 256), 256, 0, stream>>>(
              partb, db + l * 512, nullptr, kbuff, MN, 2);
        }
        int nb = BL / 128;
        bnpart_kernel<<<nb, 256, 0, stream>>>(kbuff, psumf, psqf, 128);
        bnfin_kernel<<<2, 256, 0, stream>>>(psumf, psqf, muvf, varvf, nb, BL);
        bnpool_kernel<0><<<(BL / 2) * 512 / 256, 256, 0, stream>>>(
            kbuff, muvf, varvf, bng + l * 512, bnb + l * 512, buf0f, nullptr,
            nullptr, L);
        L >>= 1;
      }
    }
    int BL = B * L;
    ln_kernel<0, 0><<<BL, 256, 0, stream>>>(buf0f, lnfg, lnfb, qbuff, nullptr,
                                            nullptr, nullptr, 1);
    end_kernel<<<BL, 64, 0, stream>>>(qbuff, endw, endb, out);
  }
}

// Round 8
// 1966.076 us; speedup vs baseline: 1.9649x; 1.0653x over previous
//
#include <hip/hip_runtime.h>
#include <cstdint>
#include <cstddef>

#define DMODEL 512
#define NHEAD 8
#define HD 64

typedef _Float16 half8 __attribute__((ext_vector_type(8)));
typedef float f32x4 __attribute__((ext_vector_type(4)));

// ---------------------------------------------------------------- threefry
__device__ __forceinline__ uint32_t rotl32(uint32_t x, int r) {
  return (x << r) | (x >> (32 - r));
}

__device__ __forceinline__ void tf_block(uint32_t k0, uint32_t k1,
                                         uint32_t& x0, uint32_t& x1) {
  uint32_t ks0 = k0, ks1 = k1, ks2 = k0 ^ k1 ^ 0x1BD11BDAu;
  x0 += ks0; x1 += ks1;
  x0 += x1; x1 = rotl32(x1, 13); x1 ^= x0;
  x0 += x1; x1 = rotl32(x1, 15); x1 ^= x0;
  x0 += x1; x1 = rotl32(x1, 26); x1 ^= x0;
  x0 += x1; x1 = rotl32(x1, 6);  x1 ^= x0;
  x0 += ks1; x1 += ks2 + 1u;
  x0 += x1; x1 = rotl32(x1, 17); x1 ^= x0;
  x0 += x1; x1 = rotl32(x1, 29); x1 ^= x0;
  x0 += x1; x1 = rotl32(x1, 16); x1 ^= x0;
  x0 += x1; x1 = rotl32(x1, 24); x1 ^= x0;
  x0 += ks2; x1 += ks0 + 2u;
  x0 += x1; x1 = rotl32(x1, 13); x1 ^= x0;
  x0 += x1; x1 = rotl32(x1, 15); x1 ^= x0;
  x0 += x1; x1 = rotl32(x1, 26); x1 ^= x0;
  x0 += x1; x1 = rotl32(x1, 6);  x1 ^= x0;
  x0 += ks0; x1 += ks1 + 3u;
  x0 += x1; x1 = rotl32(x1, 17); x1 ^= x0;
  x0 += x1; x1 = rotl32(x1, 29); x1 ^= x0;
  x0 += x1; x1 = rotl32(x1, 16); x1 ^= x0;
  x0 += x1; x1 = rotl32(x1, 24); x1 ^= x0;
  x0 += ks1; x1 += ks2 + 4u;
  x0 += x1; x1 = rotl32(x1, 13); x1 ^= x0;
  x0 += x1; x1 = rotl32(x1, 15); x1 ^= x0;
  x0 += x1; x1 = rotl32(x1, 26); x1 ^= x0;
  x0 += x1; x1 = rotl32(x1, 6);  x1 ^= x0;
  x0 += ks2; x1 += ks0 + 5u;
}

__global__ void idx_kernel(int* __restrict__ idxb, int n, int layer, int mask) {
  int e = blockIdx.x * 256 + threadIdx.x;
  if (e >= n) return;
  uint32_t f0 = 0u, f1 = (uint32_t)layer;
  tf_block(0u, 42u, f0, f1);
  uint32_t s0 = 0u, s1 = 1u;
  tf_block(f0, f1, s0, s1);
  uint32_t x0 = 0u, x1 = (uint32_t)e;
  tf_block(s0, s1, x0, x1);
  uint32_t bits = x0 ^ x1;
  idxb[e] = (int)(bits & (uint32_t)mask);
}

// ---------------------------------------------------------------- fp16 hi/lo split helpers
__device__ __forceinline__ void f2hsplit(float v, unsigned short& h,
                                         unsigned short& l) {
  _Float16 hh = (_Float16)v;          // RNE
  float r = v - (float)hh;            // exact
  _Float16 ll = (_Float16)r;
  h = __builtin_bit_cast(unsigned short, hh);
  l = __builtin_bit_cast(unsigned short, ll);
}

__device__ __forceinline__ float gelu_f(float v) {
  return 0.5f * v * (1.0f + erff(v * 0.7071067811865476f));
}

// address-space cast helpers for global_load_lds
#define AS1G(p) ((const __attribute__((address_space(1))) void*)(size_t)(p))
#define AS3L(p) ((__attribute__((address_space(3))) void*)(unsigned)(size_t)(p))
#define GLD16(g, l) __builtin_amdgcn_global_load_lds(AS1G(g), AS3L(l), 16, 0, 0)

// ---------------------------------------------------------------- fp32 -> fp16 hi/lo conversion (weights)
__global__ __launch_bounds__(256) void cvt_kernel(const float* __restrict__ X,
                                                  unsigned short* __restrict__ H,
                                                  unsigned short* __restrict__ Lo,
                                                  int n8) {
  int i = blockIdx.x * 256 + threadIdx.x;
  if (i >= n8) return;
  const float4* xp = (const float4*)X + 2 * (size_t)i;
  float4 a = xp[0], b = xp[1];
  float v[8] = {a.x, a.y, a.z, a.w, b.x, b.y, b.z, b.w};
  unsigned hu[4], lu[4];
#pragma unroll
  for (int q = 0; q < 4; ++q) {
    unsigned short h0, l0, h1, l1;
    f2hsplit(v[2 * q], h0, l0);
    f2hsplit(v[2 * q + 1], h1, l1);
    hu[q] = (unsigned)h0 | ((unsigned)h1 << 16);
    lu[q] = (unsigned)l0 | ((unsigned)l1 << 16);
  }
  uint4 hv; hv.x = hu[0]; hv.y = hu[1]; hv.z = hu[2]; hv.w = hu[3];
  uint4 lv; lv.x = lu[0]; lv.y = lu[1]; lv.z = lu[2]; lv.w = lu[3];
  *(uint4*)(H + 8 * (size_t)i) = hv;
  *(uint4*)(Lo + 8 * (size_t)i) = lv;
}

// conv weight pack + split: wp[o][w*512+c] = dw[o][c][w]
__global__ void packw2_kernel(const float* __restrict__ dw,
                              unsigned short* __restrict__ Hh,
                              unsigned short* __restrict__ Hl) {
  int gid = blockIdx.x * 256 + threadIdx.x;  // 512*1536
  int o = gid / 1536;
  int kk = gid - o * 1536;
  int ww = kk / 512;
  int c = kk - ww * 512;
  float v = dw[((size_t)o * 512 + c) * 3 + ww];
  unsigned short h, l;
  f2hsplit(v, h, l);
  Hh[gid] = h;
  Hl[gid] = l;
}

// ---------------------------------------------------------------- MFMA GEMM 128x128, split-fp16 3-product, BK=32
// __launch_bounds__(256,4): acc alone is 64 VGPRs; (256,5) -> spill (r5).
// LDS 32 KB. Swizzle: slot ^= (row>>1)&3 (conflict-free, r4 verified).
// PART: K-split partials (raw fp32, no bias/act) -> C + kb*M*N.
template <int ACT, int HASR, int CONV, int F16OUT, int QKV, int PART>
__global__ __launch_bounds__(256, 4) void gemm_mfma(
    const unsigned short* __restrict__ Ah, const unsigned short* __restrict__ Al,
    const unsigned short* __restrict__ Wh, const unsigned short* __restrict__ Wl,
    const float* __restrict__ bias, const float* __restrict__ bias2,
    const float* __restrict__ bias3, const float* __restrict__ Rres,
    float* __restrict__ C, float* __restrict__ C2, float* __restrict__ C3,
    unsigned short* __restrict__ Ch, unsigned short* __restrict__ Cl,
    int N, int K, int Lmask, int ntx, int nty, int kloop) {
  __shared__ __attribute__((aligned(16))) unsigned short AsH[4096];
  __shared__ __attribute__((aligned(16))) unsigned short AsL[4096];
  __shared__ __attribute__((aligned(16))) unsigned short WsH[4096];
  __shared__ __attribute__((aligned(16))) unsigned short WsL[4096];
  const int tid = threadIdx.x;
  int blk = blockIdx.x;
  int kb = 0;
  if (PART) {
    const int tiles = ntx * nty;
    kb = blk / tiles;
    blk -= kb * tiles;
  }
  const int koff = PART ? kb * kloop : 0;
  const int xcd = blk & 7;
  const int j = blk >> 3;
  const int jr = j / ntx;
  const int row_t = xcd * (nty >> 3) + jr;
  const int col_t = j - jr * ntx;
  const int row0 = row_t << 7, col0 = col_t << 7;
  const int lane = tid & 63;
  const int wv = tid >> 6;
  const int wr = wv >> 1, wc = wv & 1;  // wave's 64x64 quadrant
  const int srow = lane >> 2;                          // 0..15
  const int skoff = (((lane & 3) ^ ((lane >> 3) & 3)) << 3);
  const int l15 = lane & 15, lg = lane >> 4;
  const int slotx = ((lg ^ ((l15 >> 1) & 3)) << 4);
  int oa[4], ow[4];
#pragma unroll
  for (int t = 0; t < 4; ++t) {
    oa[t] = (((wr << 6) + (t << 4) + l15) << 6) + slotx;
    ow[t] = (((wc << 6) + (t << 4) + l15) << 6) + slotx;
  }
  f32x4 acc[4][4] = {};
  const int T = (PART ? kloop : K) >> 5;
  for (int it = 0; it < T; ++it) {
    const int k0 = koff + (it << 5);
    int wwin = 0, kc = k0;
    if (CONV) { wwin = k0 >> 9; kc = k0 & 511; }
#pragma unroll
    for (int g = 0; g < 2; ++g) {
      const int R0 = (wv << 5) + (g << 4);
      const int rr = R0 + srow;
      size_t aoff;
      if (CONV) {
        int t0 = row0 + rr;
        int tcv = t0 & Lmask, bb = t0 & ~Lmask;
        int src = bb | ((tcv - 1 + wwin) & Lmask);
        aoff = (size_t)src * 512 + (kc + skoff);
      } else {
        aoff = (size_t)(row0 + rr) * K + (k0 + skoff);
      }
      size_t woff = (size_t)(col0 + rr) * K + (k0 + skoff);
      GLD16(Ah + aoff, AsH + R0 * 32);
      GLD16(Al + aoff, AsL + R0 * 32);
      GLD16(Wh + woff, WsH + R0 * 32);
      GLD16(Wl + woff, WsL + R0 * 32);
    }
    __syncthreads();
    half8 fah[4], fal[4];
#pragma unroll
    for (int t = 0; t < 4; ++t) {
      fah[t] = *(const half8*)((const char*)AsH + oa[t]);
      fal[t] = *(const half8*)((const char*)AsL + oa[t]);
    }
#pragma unroll
    for (int ni = 0; ni < 4; ++ni) {
      half8 bh = *(const half8*)((const char*)WsH + ow[ni]);
      half8 bl = *(const half8*)((const char*)WsL + ow[ni]);
#pragma unroll
      for (int mi = 0; mi < 4; ++mi) {
        acc[mi][ni] = __builtin_amdgcn_mfma_f32_16x16x32_f16(
            fah[mi], bh, acc[mi][ni], 0, 0, 0);
        acc[mi][ni] = __builtin_amdgcn_mfma_f32_16x16x32_f16(
            fah[mi], bl, acc[mi][ni], 0, 0, 0);
        acc[mi][ni] = __builtin_amdgcn_mfma_f32_16x16x32_f16(
            fal[mi], bh, acc[mi][ni], 0, 0, 0);
      }
    }
    __syncthreads();
  }
  // epilogue: D lane mapping col=l15, row=lg*4+q
  if (PART) {
    float* Cp = C + (size_t)kb * ((size_t)(nty << 7)) * N;
#pragma unroll
    for (int mi = 0; mi < 4; ++mi)
#pragma unroll
      for (int q = 0; q < 4; ++q) {
        const int m = row0 + (wr << 6) + (mi << 4) + (lg << 2) + q;
#pragma unroll
        for (int ni = 0; ni < 4; ++ni) {
          const int col = col0 + (wc << 6) + (ni << 4) + l15;
          Cp[(size_t)m * N + col] = acc[mi][ni][q];
        }
      }
    return;
  }
  int cbase = col0;
  float* Cb = C;
  const float* bb = bias;
  if (QKV) {
    const int cb = col0 >> 9;
    cbase = col0 & 511;
    Cb = (cb == 0) ? C : ((cb == 1) ? C2 : C3);
    bb = (cb == 0) ? bias : ((cb == 1) ? bias2 : bias3);
  }
  const int OSTR = QKV ? 512 : N;
  float bsv[4];
#pragma unroll
  for (int ni = 0; ni < 4; ++ni)
    bsv[ni] = bb[cbase + (wc << 6) + (ni << 4) + l15];
#pragma unroll
  for (int mi = 0; mi < 4; ++mi) {
#pragma unroll
    for (int q = 0; q < 4; ++q) {
      const int m = row0 + (wr << 6) + (mi << 4) + (lg << 2) + q;
#pragma unroll
      for (int ni = 0; ni < 4; ++ni) {
        const int col = cbase + (wc << 6) + (ni << 4) + l15;
        float v = acc[mi][ni][q] + bsv[ni];
        if (HASR) v += Rres[(size_t)m * OSTR + col];
        if (ACT == 1) v = gelu_f(v);
        if (F16OUT) {
          unsigned short h, lo;
          f2hsplit(v, h, lo);
          Ch[(size_t)m * OSTR + col] = h;
          Cl[(size_t)m * OSTR + col] = lo;
        } else {
          Cb[(size_t)m * OSTR + col] = v;
        }
      }
    }
  }
}

// ---------------------------------------------------------------- fp32 GEMM (fallback path only)
template <int ACT, int HASR, int CONV, int PART>
__global__ __launch_bounds__(256, 2) void gemm128(
    const float* __restrict__ A, const float* __restrict__ W,
    const float* __restrict__ bias, const float* Rres, float* C,
    int N, int K, int Lmask, int ntx, int nty, int kloop, int ks) {
  __shared__ float As[16][140];
  __shared__ float Ws[16][140];
  const int tid = threadIdx.x;
  int blk = blockIdx.x;
  const int tiles = ntx * nty;
  int kb = 0;
  if (PART) { kb = blk / tiles; blk -= kb * tiles; }
  const int koff = kb * kloop;
  const int xcd = blk & 7;
  const int j = blk >> 3;
  const int jr = j / ntx;
  const int row_t = xcd * (nty >> 3) + jr;
  const int col_t = j - jr * ntx;
  const int row0 = row_t * 128, col0 = col_t * 128;

  const int ar = tid >> 1;
  const int ac = (tid & 1) << 3;
  const int arp = ar + ((ar >> 5) << 2);
  const int tx = tid & 15, ty = tid >> 4;
  const int wcol = tx * 8 + ((tx >> 2) << 2);
  const int acol = ty * 8 + ((ty >> 2) << 2);
  const int arow = row0 + ar;
  const float* Wp = W + (size_t)(col0 + ar) * K + koff + ac;
  const float* Ap = A + (size_t)arow * K + koff + ac;
  int tcv = 0, bbase = 0;
  if (CONV) { tcv = arow & Lmask; bbase = arow & ~Lmask; }
  float4 ra0, ra1, rw0, rw1;
  float acc[8][8] = {};
  const int T = kloop >> 4;

  {
    const float* ap;
    if (CONV) {
      int kabs = koff;
      int w = kabs >> 9;
      int src = bbase | ((tcv - 1 + w) & Lmask);
      ap = A + (size_t)src * 512 + (kabs & 511) + ac;
    } else {
      ap = Ap;
    }
    ra0 = *(const float4*)(ap);
    ra1 = *(const float4*)(ap + 4);
    rw0 = *(const float4*)(Wp);
    rw1 = *(const float4*)(Wp + 4);
  }

  for (int it = 0; it < T; ++it) {
#pragma unroll
    for (int q = 0; q < 4; q++) {
      As[ac + q][arp] = ((float*)&ra0)[q];
      As[ac + 4 + q][arp] = ((float*)&ra1)[q];
      Ws[ac + q][arp] = ((float*)&rw0)[q];
      Ws[ac + 4 + q][arp] = ((float*)&rw1)[q];
    }
    __syncthreads();
    if (it + 1 < T) {
      const int k0 = (it + 1) << 4;
      const float* ap;
      if (CONV) {
        int kabs = koff + k0;
        int w = kabs >> 9;
        int src = bbase | ((tcv - 1 + w) & Lmask);
        ap = A + (size_t)src * 512 + (kabs & 511) + ac;
      } else {
        ap = Ap + k0;
      }
      ra0 = *(const float4*)(ap);
      ra1 = *(const float4*)(ap + 4);
      rw0 = *(const float4*)(Wp + k0);
      rw1 = *(const float4*)(Wp + k0 + 4);
    }
#pragma unroll
    for (int k = 0; k < 16; k++) {
      float av[8], wvv[8];
      *(float4*)(av) = *(const float4*)&As[k][acol];
      *(float4*)(av + 4) = *(const float4*)&As[k][acol + 4];
      *(float4*)(wvv) = *(const float4*)&Ws[k][wcol];
      *(float4*)(wvv + 4) = *(const float4*)&Ws[k][wcol + 4];
#pragma unroll
      for (int i = 0; i < 8; i++)
#pragma unroll
        for (int q = 0; q < 8; q++) acc[i][q] += av[i] * wvv[q];
    }
    __syncthreads();
  }

  if (PART) {
    float* Cp = C + (size_t)kb * (nty << 7) * N;
#pragma unroll
    for (int i = 0; i < 8; i++) {
      const int m = row0 + ty * 8 + i;
      const int c0 = col0 + tx * 8;
      *(float4*)(Cp + (size_t)m * N + c0) = *(float4*)(&acc[i][0]);
      *(float4*)(Cp + (size_t)m * N + c0 + 4) = *(float4*)(&acc[i][4]);
    }
  } else {
#pragma unroll
    for (int i = 0; i < 8; i++) {
      const int m = row0 + ty * 8 + i;
      const int c0 = col0 + tx * 8;
      float vout[8];
#pragma unroll
      for (int q = 0; q < 8; q++) {
        float v = acc[i][q] + bias[c0 + q];
        if (HASR) v += Rres[(size_t)m * N + c0 + q];
        if (ACT == 1) v = gelu_f(v);
        vout[q] = v;
      }
      *(float4*)(C + (size_t)m * N + c0) = *(float4*)(vout);
      *(float4*)(C + (size_t)m * N + c0 + 4) = *(float4*)(vout + 4);
    }
  }
}

template <int HASR>
__global__ __launch_bounds__(256) void combine_kernel(
    const float* __restrict__ part, const float* __restrict__ bias,
    const float* Rres, float* __restrict__ Cout, size_t MN, int ks) {
  size_t gid = (size_t)blockIdx.x * 256 + threadIdx.x;
  int c = (int)(gid & 511);
  float v = 0.f;
  for (int kb = 0; kb < ks; kb++) v += part[kb * MN + gid];
  v += bias[c];
  if (HASR) v += Rres[gid];
  Cout[gid] = v;
}

// ---------------------------------------------------------------- positional-encoding table (batch-invariant)
__global__ void petab_kernel(float* __restrict__ pe, int S) {
  int gid = blockIdx.x * 256 + threadIdx.x;  // S*512
  int o = gid & 511;
  int t = gid >> 9;
  int i2 = o >> 1;
  float dv = expf((float)(2 * i2) * (-9.210340371976184f / 512.0f));
  float ang = (float)t * dv;
  pe[gid] = (o & 1) ? cosf(ang) : sinf(ang);
}

// ---------------------------------------------------------------- token conv + pos embed (+hi/lo)
// PE=1: add from precomputed table (bit-identical trig, computed once).
template <int EMIT, int PE>
__global__ void tokpe_kernel(const float* __restrict__ xe,
                             const float* __restrict__ w,
                             const float* __restrict__ pe,
                             float* __restrict__ out,
                             unsigned short* __restrict__ Hh,
                             unsigned short* __restrict__ Hl, int S) {
  int gid = blockIdx.x * 256 + threadIdx.x;  // B*S*512
  int o = gid & 511;
  int bt = gid >> 9;
  int t = bt % S, b = bt / S;
  float acc = 0.f;
#pragma unroll
  for (int ww = 0; ww < 3; ww++) {
    int tt = t - 1 + ww;
    tt = (tt < 0) ? tt + S : (tt >= S ? tt - S : tt);
    const float* xr = xe + ((size_t)(b * S + tt)) * 7;
#pragma unroll
    for (int i = 0; i < 7; i++) acc += xr[i] * w[o * 21 + i * 3 + ww];
  }
  if (PE) {
    acc += pe[(t << 9) | o];
  } else {
    int i2 = o >> 1;
    float dv = expf((float)(2 * i2) * (-9.210340371976184f / 512.0f));
    float ang = (float)t * dv;
    acc += (o & 1) ? cosf(ang) : sinf(ang);
  }
  out[gid] = acc;
  if (EMIT) {
    unsigned short h, l;
    f2hsplit(acc, h, l);
    Hh[gid] = h;
    Hl[gid] = l;
  }
}

// ---------------------------------------------------------------- conv weight pack (fallback fp32)
__global__ void packw_kernel(const float* __restrict__ dw, float* __restrict__ wp) {
  int gid = blockIdx.x * 256 + threadIdx.x;  // 512*1536
  int o = gid / 1536;
  int kk = gid - o * 1536;
  int ww = kk / 512;
  int c = kk - ww * 512;
  wp[gid] = dw[((size_t)o * 512 + c) * 3 + ww];
}

// ---------------------------------------------------------------- M score, 4 lanes per query, threefry fused
__global__ __launch_bounds__(256) void mscore4_kernel(
    const float* __restrict__ Q, const float* __restrict__ Kb,
    float* __restrict__ Mout, int L, int U, int layer) {
  __shared__ int sidx[64 * 24];
  int i = blockIdx.x;  // b + 8*(h*chunks + c), 64 queries per block
  int b = i & 7;
  int j = i >> 3;
  int chunks = L >> 6;
  int h = j / chunks;
  int c = j - h * chunks;
  int t0 = c << 6;
  int tid = threadIdx.x;
  const int nidx = 64 * U;
  const int mask = L - 1;
  {
    // key schedule is e-independent: hoist
    uint32_t f0 = 0u, f1 = (uint32_t)layer;
    tf_block(0u, 42u, f0, f1);
    uint32_t s0 = 0u, s1 = 1u;
    tf_block(f0, f1, s0, s1);
    for (int k = tid; k < nidx; k += 256) {
      int e = t0 * U + k;
      uint32_t x0 = 0u, x1 = (uint32_t)e;
      tf_block(s0, s1, x0, x1);
      sidx[k] = (int)((x0 ^ x1) & (uint32_t)mask);
    }
  }
  __syncthreads();
  int tsub = tid >> 2, sub = tid & 3;
  int t = t0 + tsub;
  const float4* qr =
      (const float4*)(Q + ((size_t)(b * L + t)) * DMODEL + h * HD + sub * 16);
  float4 q0 = qr[0], q1 = qr[1], q2 = qr[2], q3 = qr[3];
  const float* Kh = Kb + (size_t)b * L * DMODEL + h * HD + sub * 16;
  float mx = -3.4e38f, sm = 0.f;
  int krn = sidx[tsub * U];
  for (int jj = 0; jj < U; ++jj) {
    const float4* kp = (const float4*)(Kh + (size_t)krn * DMODEL);
    krn = sidx[tsub * U + ((jj + 1 < U) ? jj + 1 : jj)];
    float4 k0 = kp[0], k1 = kp[1], k2 = kp[2], k3 = kp[3];
    float dot = q0.x * k0.x + q0.y * k0.y + q0.z * k0.z + q0.w * k0.w +
                q1.x * k1.x + q1.y * k1.y + q1.z * k1.z + q1.w * k1.w +
                q2.x * k2.x + q2.y * k2.y + q2.z * k2.z + q2.w * k2.w +
                q3.x * k3.x + q3.y * k3.y + q3.z * k3.z + q3.w * k3.w;
    dot += __shfl_xor(dot, 1);
    dot += __shfl_xor(dot, 2);
    mx = fmaxf(mx, dot);
    sm += dot;
  }
  if (sub == 0) Mout[(size_t)(b * 8 + h) * L + t] = mx - sm / (float)L;
}

// ---------------------------------------------------------------- M score (fallback)
__global__ __launch_bounds__(256) void mscore_kernel(
    const float* __restrict__ Q, const float* __restrict__ Kb,
    const int* __restrict__ idxb, float* __restrict__ Mout, int L, int U) {
  int i = blockIdx.x;
  int b = i & 7;
  int j = i >> 3;
  int chunks = L >> 8;
  int h = j / chunks;
  int c = j - h * chunks;
  int t = c * 256 + threadIdx.x;
  const float4* qr = (const float4*)(Q + ((size_t)(b * L + t)) * DMODEL + h * HD);
  float4 qv[16];
#pragma unroll
  for (int ii = 0; ii < 16; ii++) qv[ii] = qr[ii];
  float mx = -3.4e38f, sm = 0.f;
  for (int jj = 0; jj < U; jj++) {
    int kr = idxb[t * U + jj];
    const float4* kp =
        (const float4*)(Kb + ((size_t)(b * L + kr)) * DMODEL + h * HD);
    float dot = 0.f;
#pragma unroll
    for (int ii = 0; ii < 16; ii++) {
      float4 kv = kp[ii];
      dot += qv[ii].x * kv.x + qv[ii].y * kv.y + qv[ii].z * kv.z + qv[ii].w * kv.w;
    }
    mx = fmaxf(mx, dot);
    sm += dot;
  }
  Mout[(size_t)(b * 8 + h) * L + t] = mx - sm / (float)L;
}

// ---------------------------------------------------------------- top-k
__global__ __launch_bounds__(256) void topk_kernel(const float* __restrict__ Mv,
                                                   int* __restrict__ topb, int L,
                                                   int u) {
  __shared__ float wv_s[4];
  __shared__ int wi_s[4];
  __shared__ int best_s;
  int bh = blockIdx.x, tid = threadIdx.x;
  int lane = tid & 63, w = tid >> 6;
  int cnt = L >> 8;
  float lv[8];
  for (int i = 0; i < cnt; i++) lv[i] = Mv[(size_t)bh * L + i * 256 + tid];
  for (int r = 0; r < u; r++) {
    float bv = -3.4e38f;
    int bi = 0x7fffffff;
    for (int i = 0; i < cnt; i++) {
      if (lv[i] > bv) { bv = lv[i]; bi = i * 256 + tid; }
    }
    for (int s = 32; s > 0; s >>= 1) {
      float ov = __shfl_down(bv, s);
      int oi = __shfl_down(bi, s);
      if (ov > bv || (ov == bv && oi < bi)) { bv = ov; bi = oi; }
    }
    if (lane == 0) { wv_s[w] = bv; wi_s[w] = bi; }
    __syncthreads();
    if (tid == 0) {
      float fv = wv_s[0];
      int fi = wi_s[0];
      for (int q = 1; q < 4; q++) {
        if (wv_s[q] > fv || (wv_s[q] == fv && wi_s[q] < fi)) {
          fv = wv_s[q];
          fi = wi_s[q];
        }
      }
      best_s = fi;
      topb[bh * u + r] = fi;
    }
    __syncthreads();
    int win = best_s;
    if ((win & 255) == tid) lv[win >> 8] = -3.4e38f;
  }
}

// ---------------------------------------------------------------- gather selected q rows (fallback paths)
__global__ void gatherq_kernel(const float* __restrict__ Q,
                               const int* __restrict__ topb,
                               float* __restrict__ qsel, int L, int u) {
  int i = blockIdx.x;
  int bh = i / u;
  int b = bh >> 3, h = bh & 7;
  int t = topb[i];
  qsel[i * HD + threadIdx.x] =
      Q[((size_t)(b * L + t)) * DMODEL + h * HD + threadIdx.x];
}

// ---------------------------------------------------------------- mean of x rows per batch
__global__ __launch_bounds__(256) void xmean_kernel(const float* __restrict__ x,
                                                    float* __restrict__ psumx,
                                                    int L) {
  int i = blockIdx.x;
  int b = i >> 3, g = i & 7;
  int rows = L >> 3;
  int tid = threadIdx.x;
  const float* base = x + ((size_t)b * L + (size_t)g * rows) * DMODEL;
  float s0 = 0.f, s1 = 0.f;
  for (int t = 0; t < rows; t++) {
    s0 += base[(size_t)t * DMODEL + tid];
    s1 += base[(size_t)t * DMODEL + tid + 256];
  }
  psumx[i * DMODEL + tid] = s0;
  psumx[i * DMODEL + tid + 256] = s1;
}

__global__ __launch_bounds__(256) void mvmake_kernel(
    const float* __restrict__ psumx, const float* __restrict__ Wv,
    const float* __restrict__ bv, const float* __restrict__ Wo,
    const float* __restrict__ bo, float* __restrict__ mvg,
    float* __restrict__ mvWog, int L) {
  __shared__ float xm[512];
  __shared__ float mvs[512];
  int b = blockIdx.x, tid = threadIdx.x;
  float inv = 1.0f / (float)L;
  for (int nn = 0; nn < 2; nn++) {
    int c = tid + nn * 256;
    float s = 0.f;
    for (int g = 0; g < 8; g++) s += psumx[(b * 8 + g) * DMODEL + c];
    xm[c] = s * inv;
  }
  __syncthreads();
  for (int nn = 0; nn < 2; nn++) {
    int n = tid + nn * 256;
    const float* wr = Wv + (size_t)n * 512;
    float s = bv[n];
    for (int k = 0; k < 512; k += 4) {
      float4 w4 = *(const float4*)(wr + k);
      s += xm[k] * w4.x + xm[k + 1] * w4.y + xm[k + 2] * w4.z + xm[k + 3] * w4.w;
    }
    mvs[n] = s;
    mvg[b * DMODEL + n] = s;
  }
  __syncthreads();
  for (int nn = 0; nn < 2; nn++) {
    int n = tid + nn * 256;
    const float* wr = Wo + (size_t)n * 512;
    float s = bo[n];
    for (int k = 0; k < 512; k += 4) {
      float4 w4 = *(const float4*)(wr + k);
      s += mvs[k] * w4.x + mvs[k + 1] * w4.y + mvs[k + 2] * w4.z +
           mvs[k + 3] * w4.w;
    }
    mvWog[b * DMODEL + n] = s;
  }
}

__global__ void x1bcast_kernel(const float* __restrict__ x,
                               const float* __restrict__ mvWog,
                               float* __restrict__ x1, int L) {
  int gid = blockIdx.x * 256 + threadIdx.x;
  int c = gid & 511;
  int r = gid >> 9;
  int b = r / L;
  x1[gid] = x[gid] + mvWog[b * DMODEL + c];
}

// ---------------------------------------------------------------- chunked flash attention for selected rows
// GQ=1: gather q rows directly from Q via topb (Q must still be live).
// GQ=0: read pre-gathered qsel (fallback paths).
template <int GQ>
__global__ __launch_bounds__(256) void attnflash_kernel(
    const float* __restrict__ qsrc, const int* __restrict__ topb,
    const float* __restrict__ Kb, const float* __restrict__ Vb,
    float* __restrict__ pm, float* __restrict__ pl, float* __restrict__ pO,
    int L, int u, int nchunk) {
  __shared__ float qs[24][64];
  __shared__ float Kt[64][68];
  __shared__ float Ps[24][68];
  int blk = blockIdx.x;
  int bh = blk / nchunk;
  int c = blk - bh * nchunk;
  int b = bh >> 3, h = bh & 7;
  int cs = L / nchunk;
  int tid = threadIdx.x;
  int lane = tid & 63;
  int w = tid >> 6;
  if (GQ) {
    for (int i = tid; i < u * 64; i += 256) {
      int r = i >> 6, d = i & 63;
      int t = topb[bh * u + r];
      qs[r][d] = qsrc[((size_t)(b * L + t)) * DMODEL + h * HD + d];
    }
  } else {
    for (int i = tid; i < u * 64; i += 256)
      qs[i >> 6][i & 63] = qsrc[(size_t)bh * u * 64 + i];
  }
  float m[6], l[6], O[6];
#pragma unroll
  for (int k = 0; k < 6; k++) { m[k] = -3.4e38f; l[k] = 0.f; O[k] = 0.f; }
  const float* Kbase = Kb + (size_t)b * L * DMODEL + h * HD;
  const float* Vbase = Vb + (size_t)b * L * DMODEL + h * HD;
  const int jrow = tid & 63;
  const int dch = (tid >> 6) << 4;
  for (int j0 = c * cs; j0 < (c + 1) * cs; j0 += 64) {
    __syncthreads();
    const float* kr = Kbase + (size_t)(j0 + jrow) * DMODEL + dch;
    float4 k0 = *(const float4*)(kr);
    float4 k1 = *(const float4*)(kr + 4);
    float4 k2 = *(const float4*)(kr + 8);
    float4 k3 = *(const float4*)(kr + 12);
#pragma unroll
    for (int q = 0; q < 4; q++) {
      Kt[dch + q][jrow] = ((float*)&k0)[q];
      Kt[dch + 4 + q][jrow] = ((float*)&k1)[q];
      Kt[dch + 8 + q][jrow] = ((float*)&k2)[q];
      Kt[dch + 12 + q][jrow] = ((float*)&k3)[q];
    }
    __syncthreads();
#pragma unroll
    for (int k = 0; k < 6; k++) {
      int qi = 4 * k + w;
      if (qi >= u) break;
      float s = 0.f;
#pragma unroll
      for (int d = 0; d < 64; d++) s += qs[qi][d] * Kt[d][lane];
      s *= 0.125f;
      float mx = s;
#pragma unroll
      for (int off = 32; off > 0; off >>= 1)
        mx = fmaxf(mx, __shfl_down(mx, off));
      mx = __shfl(mx, 0);
      float mnew = fmaxf(m[k], mx);
      float p = expf(s - mnew);
      float ps = p;
#pragma unroll
      for (int off = 32; off > 0; off >>= 1) ps += __shfl_down(ps, off);
      ps = __shfl(ps, 0);
      float alpha = expf(m[k] - mnew);
      l[k] = l[k] * alpha + ps;
      m[k] = mnew;
      O[k] *= alpha;
      Ps[qi][lane] = p;
    }
    for (int jj = 0; jj < 64; jj += 4) {
      float v0 = Vbase[(size_t)(j0 + jj) * DMODEL + lane];
      float v1 = Vbase[(size_t)(j0 + jj + 1) * DMODEL + lane];
      float v2 = Vbase[(size_t)(j0 + jj + 2) * DMODEL + lane];
      float v3 = Vbase[(size_t)(j0 + jj + 3) * DMODEL + lane];
#pragma unroll
      for (int k = 0; k < 6; k++) {
        int qi = 4 * k + w;
        if (qi >= u) break;
        O[k] += Ps[qi][jj] * v0 + Ps[qi][jj + 1] * v1 + Ps[qi][jj + 2] * v2 +
                Ps[qi][jj + 3] * v3;
      }
    }
  }
#pragma unroll
  for (int k = 0; k < 6; k++) {
    int qi = 4 * k + w;
    if (qi < u) {
      int p = (bh * nchunk + c) * u + qi;
      if (lane == 0) { pm[p] = m[k]; pl[p] = l[k]; }
      pO[(size_t)p * 64 + lane] = O[k];
    }
  }
}

__global__ __launch_bounds__(256) void deltaWo_kernel(
    const float* __restrict__ pm, const float* __restrict__ pl,
    const float* __restrict__ pO, const float* __restrict__ mvg,
    const int* __restrict__ topb, const float* __restrict__ Wo, float* x1,
    int L, int u, int nchunk) {
  __shared__ float ds[64];
  int sel = blockIdx.x;
  int bh = sel / u;
  int qi = sel - bh * u;
  int b = bh >> 3, h = bh & 7;
  int t = topb[sel];
  int tid = threadIdx.x;
  if (tid < 64) {
    float mstar = -3.4e38f;
    for (int c = 0; c < nchunk; c++)
      mstar = fmaxf(mstar, pm[(bh * nchunk + c) * u + qi]);
    float lstar = 0.f, O = 0.f;
    for (int c = 0; c < nchunk; c++) {
      int p = (bh * nchunk + c) * u + qi;
      float wgt = expf(pm[p] - mstar);
      lstar += wgt * pl[p];
      O += wgt * pO[(size_t)p * 64 + tid];
    }
    ds[tid] = O / lstar - mvg[b * DMODEL + h * HD + tid];
  }
  __syncthreads();
  float* row = x1 + ((size_t)(b * L + t)) * DMODEL;
  for (int nn = 0; nn < 2; nn++) {
    int n = tid + nn * 256;
    const float* wr = Wo + (size_t)n * 512 + h * HD;
    float a = 0.f;
#pragma unroll
    for (int k = 0; k < 64; k += 4) {
      float4 w4 = *(const float4*)(wr + k);
      a += ds[k] * w4.x + ds[k + 1] * w4.y + ds[k + 2] * w4.z + ds[k + 3] * w4.w;
    }
    atomicAdd(row + n, a);
  }
}

// ---------------------------------------------------------------- layernorm (512 cols; wave-shuffle reduce; optional hi/lo emit; optional bcast add)
template <int EMIT, int ADDB>
__global__ __launch_bounds__(256) void ln_kernel(const float* __restrict__ X,
                                                 const float* __restrict__ g,
                                                 const float* __restrict__ bta,
                                                 float* __restrict__ Y,
                                                 unsigned short* __restrict__ Hh,
                                                 unsigned short* __restrict__ Hl,
                                                 const float* __restrict__ mvW,
                                                 int Lr) {
  __shared__ float ws[4];
  __shared__ float ws2[4];
  int row = blockIdx.x, tid = threadIdx.x;
  int lane = tid & 63, w = tid >> 6;
  size_t base = (size_t)row * DMODEL;
  float x0 = X[base + tid], x1 = X[base + tid + 256];
  if (ADDB) {
    int b = row / Lr;
    x0 += mvW[b * DMODEL + tid];
    x1 += mvW[b * DMODEL + tid + 256];
  }
  float s = x0 + x1;
#pragma unroll
  for (int off = 32; off > 0; off >>= 1) s += __shfl_xor(s, off);
  if (lane == 0) ws[w] = s;
  __syncthreads();
  float mean = (ws[0] + ws[1] + ws[2] + ws[3]) * (1.0f / 512.0f);
  float d0 = x0 - mean, d1 = x1 - mean;
  float q = d0 * d0 + d1 * d1;
#pragma unroll
  for (int off = 32; off > 0; off >>= 1) q += __shfl_xor(q, off);
  if (lane == 0) ws2[w] = q;
  __syncthreads();
  float inv =
      1.0f / sqrtf((ws2[0] + ws2[1] + ws2[2] + ws2[3]) * (1.0f / 512.0f) + 1e-5f);
  float y0 = d0 * inv * g[tid] + bta[tid];
  float y1 = d1 * inv * g[tid + 256] + bta[tid + 256];
  Y[base + tid] = y0;
  Y[base + tid + 256] = y1;
  if (EMIT) {
    unsigned short h, l;
    f2hsplit(y0, h, l);
    Hh[base + tid] = h;
    Hl[base + tid] = l;
    f2hsplit(y1, h, l);
    Hh[base + tid + 256] = h;
    Hl[base + tid + 256] = l;
  }
}

// ---------------------------------------------------------------- combine K-split partials + residual + LN2, fused (per chunk)
// z = sum_kb part + bias + resid (exact combine order); y = LN(z; g, bta).
// EMIT=1: write hi/lo only. EMIT=0: write fp32 Y only.
template <int EMIT>
__global__ __launch_bounds__(256) void lncomb_kernel(
    const float* __restrict__ part, const float* __restrict__ bias,
    const float* __restrict__ resid, const float* __restrict__ g,
    const float* __restrict__ bta, float* __restrict__ Y,
    unsigned short* __restrict__ Hh, unsigned short* __restrict__ Hl, int r0,
    size_t MNc, int ks) {
  __shared__ float ws[4];
  __shared__ float ws2[4];
  int lrow = blockIdx.x, tid = threadIdx.x;
  int lane = tid & 63, w = tid >> 6;
  size_t lbase = (size_t)lrow * DMODEL;
  size_t gbase = (size_t)(r0 + lrow) * DMODEL;
  float x0 = 0.f, x1 = 0.f;
  for (int kb = 0; kb < ks; kb++) {
    x0 += part[kb * MNc + lbase + tid];
    x1 += part[kb * MNc + lbase + tid + 256];
  }
  x0 += bias[tid];
  x1 += bias[tid + 256];
  x0 += resid[gbase + tid];
  x1 += resid[gbase + tid + 256];
  float s = x0 + x1;
#pragma unroll
  for (int off = 32; off > 0; off >>= 1) s += __shfl_xor(s, off);
  if (lane == 0) ws[w] = s;
  __syncthreads();
  float mean = (ws[0] + ws[1] + ws[2] + ws[3]) * (1.0f / 512.0f);
  float d0 = x0 - mean, d1 = x1 - mean;
  float q = d0 * d0 + d1 * d1;
#pragma unroll
  for (int off = 32; off > 0; off >>= 1) q += __shfl_xor(q, off);
  if (lane == 0) ws2[w] = q;
  __syncthreads();
  float inv =
      1.0f / sqrtf((ws2[0] + ws2[1] + ws2[2] + ws2[3]) * (1.0f / 512.0f) + 1e-5f);
  float y0 = d0 * inv * g[tid] + bta[tid];
  float y1 = d1 * inv * g[tid + 256] + bta[tid + 256];
  if (EMIT) {
    unsigned short h, l;
    f2hsplit(y0, h, l);
    Hh[gbase + tid] = h;
    Hl[gbase + tid] = l;
    f2hsplit(y1, h, l);
    Hh[gbase + tid + 256] = h;
    Hl[gbase + tid + 256] = l;
  } else {
    Y[gbase + tid] = y0;
    Y[gbase + tid + 256] = y1;
  }
}

// ---------------------------------------------------------------- BN stats + pool
__global__ __launch_bounds__(256) void bnpart_kernel(const float* __restrict__ z,
                                                     float* __restrict__ psum,
                                                     float* __restrict__ psq,
                                                     int rowsPer) {
  int blk = blockIdx.x, tid = threadIdx.x;
  size_t r0 = (size_t)blk * rowsPer;
  float s0 = 0, q0 = 0, s1 = 0, q1 = 0;
  for (int r = 0; r < rowsPer; r++) {
    const float* zp = z + (r0 + r) * DMODEL;
    float a = zp[tid];
    s0 += a; q0 += a * a;
    float c = zp[tid + 256];
    s1 += c; q1 += c * c;
  }
  psum[blk * DMODEL + tid] = s0;
  psum[blk * DMODEL + tid + 256] = s1;
  psq[blk * DMODEL + tid] = q0;
  psq[blk * DMODEL + tid + 256] = q1;
}

__global__ void bnfin_kernel(const float* __restrict__ psum,
                             const float* __restrict__ psq, float* __restrict__ mu,
                             float* __restrict__ var, int nb, int Rtot) {
  int c = blockIdx.x * 256 + threadIdx.x;
  float s = 0, q = 0;
  for (int b = 0; b < nb; b++) {
    s += psum[b * DMODEL + c];
    q += psq[b * DMODEL + c];
  }
  float m = s / (float)Rtot;
  mu[c] = m;
  var[c] = fmaxf(q / (float)Rtot - m * m, 0.f);
}

template <int EMIT>
__global__ void bnpool_kernel(const float* __restrict__ z,
                              const float* __restrict__ mu,
                              const float* __restrict__ var,
                              const float* __restrict__ g,
                              const float* __restrict__ bta,
                              float* __restrict__ out,
                              unsigned short* __restrict__ Hh,
                              unsigned short* __restrict__ Hl, int L) {
  int gid = blockIdx.x * 256 + threadIdx.x;
  int c = gid & 511;
  int bt = gid >> 9;
  int L2 = L >> 1;
  int t2 = bt % L2, b = bt / L2;
  float m = mu[c];
  float inv = 1.0f / sqrtf(var[c] + 1e-5f);
  float gg = g[c], bb = bta[c];
  float best = -3.4e38f;
#pragma unroll
  for (int ww = 0; ww < 3; ww++) {
    int t = 2 * t2 - 1 + ww;
    if (t < 0 || t >= L) continue;
    float yv = (z[((size_t)(b * L + t)) * DMODEL + c] - m) * inv * gg + bb;
    yv = (yv > 0.f) ? yv : expm1f(yv);
    best = fmaxf(best, yv);
  }
  out[gid] = best;
  if (EMIT) {
    unsigned short h, l;
    f2hsplit(best, h, l);
    Hh[gid] = h;
    Hl[gid] = l;
  }
}

// ---------------------------------------------------------------- final projection (512 -> 7)
__global__ __launch_bounds__(64) void end_kernel(const float* __restrict__ xn,
                                                 const float* __restrict__ ew,
                                                 const float* __restrict__ eb,
                                                 float* __restrict__ out) {
  __shared__ float xs[512];
  __shared__ float red[64];
  int row = blockIdx.x, tid = threadIdx.x;
#pragma unroll
  for (int i = 0; i < 8; i++) xs[tid + 64 * i] = xn[(size_t)row * DMODEL + tid + 64 * i];
  __syncthreads();
  for (int c = 0; c < 7; c++) {
    float p = 0.f;
    for (int d = tid; d < 512; d += 64) p += xs[d] * ew[c * DMODEL + d];
    red[tid] = p;
    __syncthreads();
    for (int s = 32; s > 0; s >>= 1) {
      if (tid < s) red[tid] += red[tid + s];
      __syncthreads();
    }
    if (tid == 0) out[row * 7 + c] = red[0] + eb[c];
    __syncthreads();
  }
}

// ---------------------------------------------------------------- host
extern "C" void kernel_launch(void* const* d_in, const int* in_sizes, int n_in,
                              void* d_out, int out_size, void* d_ws,
                              size_t ws_size, hipStream_t stream) {
  (void)in_sizes; (void)n_in; (void)out_size;
  const float* x_enc = (const float*)d_in[0];
  const float* tok_w = (const float*)d_in[1];
  const float* Wq = (const float*)d_in[2];
  const float* bq = (const float*)d_in[3];
  const float* Wk = (const float*)d_in[4];
  const float* bk = (const float*)d_in[5];
  const float* Wv = (const float*)d_in[6];
  const float* bv = (const float*)d_in[7];
  const float* Wo = (const float*)d_in[8];
  const float* bo = (const float*)d_in[9];
  const float* w1 = (const float*)d_in[10];
  const float* b1 = (const float*)d_in[11];
  const float* w2 = (const float*)d_in[12];
  const float* b2 = (const float*)d_in[13];
  const float* g1 = (const float*)d_in[14];
  const float* be1 = (const float*)d_in[15];
  const float* g2 = (const float*)d_in[16];
  const float* be2 = (const float*)d_in[17];
  const float* dw = (const float*)d_in[18];
  const float* db = (const float*)d_in[19];
  const float* bng = (const float*)d_in[20];
  const float* bnb = (const float*)d_in[21];
  const float* lnfg = (const float*)d_in[22];
  const float* lnfb = (const float*)d_in[23];
  const float* endw = (const float*)d_in[24];
  const float* endb = (const float*)d_in[25];
  float* out = (float*)d_out;
  char* ws = (char*)d_ws;

  const int B = 8;
  const int S = 2048;
  const int Uarr[3] = {24, 21, 21};
  const int NCHMAX = 32;

  // ---- MFMA-path arena (layout identical to r6) ----
  size_t o = 0;
  float* buf0 = (float*)(ws + o); o += (size_t)16384 * 512 * 4;
  float* qbuf = (float*)(ws + o); o += (size_t)16384 * 512 * 4;
  float* kbuf = (float*)(ws + o); o += (size_t)16384 * 512 * 4;
  float* Mb    = (float*)(ws + o); o += (size_t)64 * 2048 * 4;
  int*   idxb  = (int*)(ws + o);   o += (size_t)2048 * 24 * 4;
  int*   topb  = (int*)(ws + o);   o += 8192;
  float* qsel  = (float*)(ws + o); o += (size_t)64 * 24 * 64 * 4;
  float* mvg   = (float*)(ws + o); o += (size_t)8 * 512 * 4;
  float* mvWog = (float*)(ws + o); o += (size_t)8 * 512 * 4;
  float* psumx = (float*)(ws + o); o += (size_t)64 * 512 * 4;
  float* psum  = (float*)(ws + o); o += (size_t)128 * 512 * 4;
  float* psq   = (float*)(ws + o); o += (size_t)128 * 512 * 4;
  float* muv   = (float*)(ws + o); o += 2048;
  float* varv  = (float*)(ws + o); o += 2048;
  float* pmb   = (float*)(ws + o); o += (size_t)64 * NCHMAX * 24 * 4;
  float* plb   = (float*)(ws + o); o += (size_t)64 * NCHMAX * 24 * 4;
  float* pOb   = (float*)(ws + o); o += (size_t)64 * NCHMAX * 24 * 64 * 4;
  unsigned short* P1h = (unsigned short*)(ws + o); o += (size_t)16384 * 512 * 2;
  unsigned short* P1l = (unsigned short*)(ws + o); o += (size_t)16384 * 512 * 2;
  unsigned short* P2h = (unsigned short*)(ws + o); o += (size_t)16384 * 512 * 2;
  unsigned short* P2l = (unsigned short*)(ws + o); o += (size_t)16384 * 512 * 2;
  unsigned short* Wqkvh = (unsigned short*)(ws + o); o += (size_t)1536 * 512 * 2;
  unsigned short* Wqkvl = (unsigned short*)(ws + o); o += (size_t)1536 * 512 * 2;
  unsigned short* w1h = (unsigned short*)(ws + o); o += (size_t)2048 * 512 * 2;
  unsigned short* w1l = (unsigned short*)(ws + o); o += (size_t)2048 * 512 * 2;
  unsigned short* w2h = (unsigned short*)(ws + o); o += (size_t)512 * 2048 * 2;
  unsigned short* w2l = (unsigned short*)(ws + o); o += (size_t)512 * 2048 * 2;
  unsigned short* wph = (unsigned short*)(ws + o); o += (size_t)512 * 1536 * 2;
  unsigned short* wpl = (unsigned short*)(ws + o); o += (size_t)512 * 1536 * 2;
  const bool use_mfma = (ws_size >= o);
  float* vbuf = (float*)(ws + o); o += (size_t)16384 * 512 * 4;
  const bool fuseqkv = (ws_size >= o);
  unsigned short* CHh = (unsigned short*)(ws + o); o += (size_t)16384 * 2048 * 2;
  unsigned short* CHl = (unsigned short*)(ws + o); o += (size_t)16384 * 2048 * 2;
  const bool fullffn = (ws_size >= o);
  // chunked-FFN scratch (aliased over dead buffers):
  //  fuseqkv l<2: 8192-row chunks. CHh -> vbuf (33.5MB, V dead), CHl -> kbuf
  //   (33.5MB, K dead), K-split 2 partials -> buf0 (33.5MB, x dead after LN1).
  //  fuseqkv l=2: 4096-row single chunk. CH both halves -> vbuf, partials -> kbuf,
  //   lncomb Y -> buf0.
  //  !fuseqkv fallback: r3 layout (CH -> buf0, partials -> P1, combine+ln).
  unsigned short* CHb0 = (unsigned short*)buf0;
  float* partmP1 = (float*)P1h;
  float* petab = (float*)pOb;  // 2048*512*4 = 4MB <= pOb (12.6MB), dead at start

  if (use_mfma) {
    petab_kernel<<<S * DMODEL / 256, 256, 0, stream>>>(petab, S);
    tokpe_kernel<1, 1><<<B * S * DMODEL / 256, 256, 0, stream>>>(
        x_enc, tok_w, petab, buf0, P1h, P1l, S);
    int L = S;
    for (int l = 0; l < 3; l++) {
      int U = Uarr[l];
      int u = Uarr[l];
      int BL = B * L;
      int nty = BL >> 7;
      int nch = L >> 6;
      if (nch > NCHMAX) nch = NCHMAX;
      // weights -> packed fp16 hi/lo
      cvt_kernel<<<128, 256, 0, stream>>>(Wq + (size_t)l * 262144, Wqkvh, Wqkvl, 32768);
      cvt_kernel<<<128, 256, 0, stream>>>(Wk + (size_t)l * 262144, Wqkvh + 262144,
                                          Wqkvl + 262144, 32768);
      cvt_kernel<<<128, 256, 0, stream>>>(Wv + (size_t)l * 262144, Wqkvh + 524288,
                                          Wqkvl + 524288, 32768);
      if (fuseqkv) {
        gemm_mfma<0, 0, 0, 0, 1, 0><<<12 * nty, 256, 0, stream>>>(
            P1h, P1l, Wqkvh, Wqkvl, bq + l * 512, bk + l * 512, bv + l * 512,
            nullptr, qbuf, kbuf, vbuf, nullptr, nullptr, 1536, 512, 0, 12, nty,
            512);
      } else {
        idx_kernel<<<(L * U + 255) / 256, 256, 0, stream>>>(idxb, L * U, l, L - 1);
        gemm_mfma<0, 0, 0, 0, 0, 0><<<4 * nty, 256, 0, stream>>>(
            P1h, P1l, Wqkvh, Wqkvl, bq + l * 512, nullptr, nullptr, nullptr,
            qbuf, nullptr, nullptr, nullptr, nullptr, 512, 512, 0, 4, nty, 512);
        gemm_mfma<0, 0, 0, 0, 0, 0><<<4 * nty, 256, 0, stream>>>(
            P1h, P1l, Wqkvh + 262144, Wqkvl + 262144, bk + l * 512, nullptr,
            nullptr, nullptr, kbuf, nullptr, nullptr, nullptr, nullptr, 512,
            512, 0, 4, nty, 512);
      }
      mscore4_kernel<<<64 * (L >> 6), 256, 0, stream>>>(qbuf, kbuf, Mb, L, U, l);
      topk_kernel<<<64, 256, 0, stream>>>(Mb, topb, L, u);
      xmean_kernel<<<64, 256, 0, stream>>>(buf0, psumx, L);
      mvmake_kernel<<<8, 256, 0, stream>>>(psumx, Wv + (size_t)l * 262144,
                                           bv + l * 512, Wo + (size_t)l * 262144,
                                           bo + l * 512, mvg, mvWog, L);
      if (fuseqkv) {
        // q rows gathered inside attnflash (Q still live in qbuf)
        attnflash_kernel<1><<<64 * nch, 256, 0, stream>>>(
            qbuf, topb, kbuf, vbuf, pmb, plb, pOb, L, u, nch);
      } else {
        gatherq_kernel<<<64 * u, 64, 0, stream>>>(qbuf, topb, qsel, L, u);
        gemm_mfma<0, 0, 0, 0, 0, 0><<<4 * nty, 256, 0, stream>>>(
            P1h, P1l, Wqkvh + 524288, Wqkvl + 524288, bv + l * 512, nullptr,
            nullptr, nullptr, qbuf, nullptr, nullptr, nullptr, nullptr, 512,
            512, 0, 4, nty, 512);
        attnflash_kernel<0><<<64 * nch, 256, 0, stream>>>(
            qsel, nullptr, kbuf, qbuf, pmb, plb, pOb, L, u, nch);
      }
      // delta accumulates straight into x (buf0); mvWo broadcast folded into LN1
      deltaWo_kernel<<<64 * u, 256, 0, stream>>>(pmb, plb, pOb, mvg, topb,
                                                 Wo + (size_t)l * 262144, buf0, L,
                                                 u, nch);
      // xa = LN1(x + delta + mvWo) -> qbuf (+hi/lo -> P2); buf0 x now dead
      ln_kernel<1, 1><<<BL, 256, 0, stream>>>(buf0, g1 + l * 512, be1 + l * 512,
                                              qbuf, P2h, P2l, mvWog, L);
      cvt_kernel<<<512, 256, 0, stream>>>(w1 + (size_t)l * 1048576, w1h, w1l, 131072);
      cvt_kernel<<<512, 256, 0, stream>>>(w2 + (size_t)l * 1048576, w2h, w2l, 131072);
      if (fullffn) {
        gemm_mfma<1, 0, 0, 1, 0, 0><<<16 * nty, 256, 0, stream>>>(
            P2h, P2l, w1h, w1l, b1 + l * 2048, nullptr, nullptr, nullptr,
            nullptr, nullptr, nullptr, CHh, CHl, 2048, 512, 0, 16, nty, 512);
        gemm_mfma<0, 1, 0, 0, 0, 0><<<4 * nty, 256, 0, stream>>>(
            CHh, CHl, w2h, w2l, b2 + l * 512, nullptr, nullptr, qbuf, kbuf,
            nullptr, nullptr, nullptr, nullptr, 512, 2048, 0, 4, nty, 2048);
        if (l < 2) {
          ln_kernel<1, 0><<<BL, 256, 0, stream>>>(kbuf, g2 + l * 512,
                                                  be2 + l * 512, buf0, P1h, P1l,
                                                  nullptr, 1);
        } else {
          ln_kernel<0, 0><<<BL, 256, 0, stream>>>(kbuf, g2 + l * 512,
                                                  be2 + l * 512, buf0, nullptr,
                                                  nullptr, nullptr, 1);
        }
      } else if (fuseqkv) {
        if (l < 2) {
          // 8192-row chunks: CHh->vbuf, CHl->kbuf, K-split2 partials->buf0
          const int R = 8192;
          const int Rt = R >> 7;  // 64
          unsigned short* CHhp = (unsigned short*)vbuf;
          unsigned short* CHlp = (unsigned short*)kbuf;
          float* partp = buf0;
          for (int r0 = 0; r0 < BL; r0 += R) {
            gemm_mfma<1, 0, 0, 1, 0, 0><<<16 * Rt, 256, 0, stream>>>(
                P2h + (size_t)r0 * 512, P2l + (size_t)r0 * 512, w1h, w1l,
                b1 + l * 2048, nullptr, nullptr, nullptr, nullptr, nullptr,
                nullptr, CHhp, CHlp, 2048, 512, 0, 16, Rt, 512);
            gemm_mfma<0, 0, 0, 0, 0, 1><<<4 * Rt * 2, 256, 0, stream>>>(
                CHhp, CHlp, w2h, w2l, nullptr, nullptr, nullptr, nullptr, partp,
                nullptr, nullptr, nullptr, nullptr, 512, 2048, 0, 4, Rt, 1024);
            lncomb_kernel<1><<<R, 256, 0, stream>>>(
                partp, b2 + l * 512, qbuf, g2 + l * 512, be2 + l * 512, nullptr,
                P1h, P1l, r0, (size_t)R * 512, 2);
          }
        } else {
          // l=2: single 4096-row chunk: CH fully in vbuf, partials -> kbuf
          unsigned short* CHhp = (unsigned short*)vbuf;
          unsigned short* CHlp = CHhp + (size_t)4096 * 2048;
          gemm_mfma<1, 0, 0, 1, 0, 0><<<16 * 32, 256, 0, stream>>>(
              P2h, P2l, w1h, w1l, b1 + l * 2048, nullptr, nullptr, nullptr,
              nullptr, nullptr, nullptr, CHhp, CHlp, 2048, 512, 0, 16, 32, 512);
          gemm_mfma<0, 0, 0, 0, 0, 1><<<4 * 32 * 4, 256, 0, stream>>>(
              CHhp, CHlp, w2h, w2l, nullptr, nullptr, nullptr, nullptr, kbuf,
              nullptr, nullptr, nullptr, nullptr, 512, 2048, 0, 4, 32, 512);
          lncomb_kernel<0><<<4096, 256, 0, stream>>>(
              kbuf, b2 + l * 512, qbuf, g2 + l * 512, be2 + l * 512, buf0,
              nullptr, nullptr, 0, (size_t)4096 * 512, 4);
        }
      } else {
        // fallback chunked path (round-3 layout): CH -> buf0, partials -> P1
        unsigned short* CHlch = CHb0 + (size_t)4096 * 2048;
        for (int r0 = 0; r0 < BL; r0 += 4096) {
          gemm_mfma<1, 0, 0, 1, 0, 0><<<16 * 32, 256, 0, stream>>>(
              P2h + (size_t)r0 * 512, P2l + (size_t)r0 * 512, w1h, w1l,
              b1 + l * 2048, nullptr, nullptr, nullptr, nullptr, nullptr,
              nullptr, CHb0, CHlch, 2048, 512, 0, 16, 32, 512);
          gemm_mfma<0, 0, 0, 0, 0, 1><<<4 * 32 * 4, 256, 0, stream>>>(
              CHb0, CHlch, w2h, w2l, nullptr, nullptr, nullptr, nullptr,
              partmP1, nullptr, nullptr, nullptr, nullptr, 512, 2048, 0, 4, 32,
              512);
          combine_kernel<1><<<4096 * 512 / 256, 256, 0, stream>>>(
              partmP1, b2 + l * 512, qbuf + (size_t)r0 * 512,
              kbuf + (size_t)r0 * 512, (size_t)4096 * 512, 4);
        }
        if (l < 2) {
          ln_kernel<1, 0><<<BL, 256, 0, stream>>>(kbuf, g2 + l * 512,
                                                  be2 + l * 512, buf0, P1h, P1l,
                                                  nullptr, 1);
        } else {
          ln_kernel<0, 0><<<BL, 256, 0, stream>>>(kbuf, g2 + l * 512,
                                                  be2 + l * 512, buf0, nullptr,
                                                  nullptr, nullptr, 1);
        }
      }
      if (l < 2) {
        packw2_kernel<<<512 * 1536 / 256, 256, 0, stream>>>(
            dw + (size_t)l * 512 * 512 * 3, wph, wpl);
        gemm_mfma<0, 0, 1, 0, 0, 0><<<4 * nty, 256, 0, stream>>>(
            P1h, P1l, wph, wpl, db + l * 512, nullptr, nullptr, nullptr, kbuf,
            nullptr, nullptr, nullptr, nullptr, 512, 1536, L - 1, 4, nty, 1536);
        int nb = BL / 128;
        bnpart_kernel<<<nb, 256, 0, stream>>>(kbuf, psum, psq, 128);
        bnfin_kernel<<<2, 256, 0, stream>>>(psum, psq, muv, varv, nb, BL);
        bnpool_kernel<1><<<(BL / 2) * 512 / 256, 256, 0, stream>>>(
            kbuf, muv, varv, bng + l * 512, bnb + l * 512, buf0, P1h, P1l, L);
        L >>= 1;
      }
    }
    int BL = B * L;  // 4096
    ln_kernel<0, 0><<<BL, 256, 0, stream>>>(buf0, lnfg, lnfb, qbuf, nullptr,
                                            nullptr, nullptr, 1);
    end_kernel<<<BL, 64, 0, stream>>>(qbuf, endw, endb, out);
    return;
  }

  // ================= fallback: verified fp32 path =================
  {
    const int NCH = 8;
    size_t o2 = 0;
    float* buf0f = (float*)(ws + o2); o2 += (size_t)16384 * 512 * 4;
    float* qbuff = (float*)(ws + o2); o2 += (size_t)16384 * 512 * 4;
    float* kbuff = (float*)(ws + o2); o2 += (size_t)16384 * 512 * 4;
    float* wpack = (float*)(ws + o2); o2 += (size_t)512 * 1536 * 4;
    float* Mbf    = (float*)(ws + o2); o2 += (size_t)64 * 2048 * 4;
    int*   idxbf  = (int*)(ws + o2);   o2 += (size_t)2048 * 24 * 4;
    int*   topbf  = (int*)(ws + o2);   o2 += 8192;
    float* qself  = (float*)(ws + o2); o2 += (size_t)64 * 24 * 64 * 4;
    float* mvgf   = (float*)(ws + o2); o2 += (size_t)8 * 512 * 4;
    float* mvWogf = (float*)(ws + o2); o2 += (size_t)8 * 512 * 4;
    float* psumxf = (float*)(ws + o2); o2 += (size_t)64 * 512 * 4;
    float* psumf  = (float*)(ws + o2); o2 += (size_t)128 * 512 * 4;
    float* psqf   = (float*)(ws + o2); o2 += (size_t)128 * 512 * 4;
    float* muvf   = (float*)(ws + o2); o2 += 2048;
    float* varvf  = (float*)(ws + o2); o2 += 2048;
    float* pmbf   = (float*)(ws + o2); o2 += (size_t)64 * NCH * 24 * 4;
    float* plbf   = (float*)(ws + o2); o2 += (size_t)64 * NCH * 24 * 4;
    float* pObf   = (float*)(ws + o2); o2 += (size_t)64 * NCH * 24 * 64 * 4;
    float* partb  = (float*)(ws + o2); o2 += (size_t)4 * 4096 * 2048;
    const bool uks = (ws_size >= o2);

    tokpe_kernel<0, 0><<<B * S * DMODEL / 256, 256, 0, stream>>>(
        x_enc, tok_w, nullptr, buf0f, nullptr, nullptr, S);
    int L = S;
    for (int l = 0; l < 3; l++) {
      int U = Uarr[l];
      int u = U;
      int BL = B * L;
      int nty = BL / 128;
      size_t MN = (size_t)BL * 512;
      int gq = 4 * nty;
      int ksq = (gq >= 512 || !uks) ? 1 : (512 / gq);
      idx_kernel<<<(L * U + 255) / 256, 256, 0, stream>>>(idxbf, L * U, l, L - 1);
      if (ksq == 1) {
        gemm128<0, 0, 0, 0><<<gq, 256, 0, stream>>>(
            buf0f, Wq + (size_t)l * 262144, bq + l * 512, nullptr, qbuff, 512,
            512, 0, 4, nty, 512, 1);
        gemm128<0, 0, 0, 0><<<gq, 256, 0, stream>>>(
            buf0f, Wk + (size_t)l * 262144, bk + l * 512, nullptr, kbuff, 512,
            512, 0, 4, nty, 512, 1);
      } else {
        gemm128<0, 0, 0, 1><<<gq * ksq, 256, 0, stream>>>(
            buf0f, Wq + (size_t)l * 262144, nullptr, nullptr, partb, 512, 512, 0,
            4, nty, 512 / ksq, ksq);
        combine_kernel<0><<<(unsigned)(MN / 256), 256, 0, stream>>>(
            partb, bq + l * 512, nullptr, qbuff, MN, ksq);
        gemm128<0, 0, 0, 1><<<gq * ksq, 256, 0, stream>>>(
            buf0f, Wk + (size_t)l * 262144, nullptr, nullptr, partb, 512, 512, 0,
            4, nty, 512 / ksq, ksq);
        combine_kernel<0><<<(unsigned)(MN / 256), 256, 0, stream>>>(
            partb, bk + l * 512, nullptr, kbuff, MN, ksq);
      }
      mscore_kernel<<<8 * 8 * L / 256, 256, 0, stream>>>(qbuff, kbuff, idxbf, Mbf, L, U);
      topk_kernel<<<64, 256, 0, stream>>>(Mbf, topbf, L, u);
      gatherq_kernel<<<64 * u, 64, 0, stream>>>(qbuff, topbf, qself, L, u);
      xmean_kernel<<<64, 256, 0, stream>>>(buf0f, psumxf, L);
      mvmake_kernel<<<8, 256, 0, stream>>>(psumxf, Wv + (size_t)l * 262144,
                                           bv + l * 512, Wo + (size_t)l * 262144,
                                           bo + l * 512, mvgf, mvWogf, L);
      if (ksq == 1) {
        gemm128<0, 0, 0, 0><<<gq, 256, 0, stream>>>(
            buf0f, Wv + (size_t)l * 262144, bv + l * 512, nullptr, qbuff, 512,
            512, 0, 4, nty, 512, 1);
      } else {
        gemm128<0, 0, 0, 1><<<gq * ksq, 256, 0, stream>>>(
            buf0f, Wv + (size_t)l * 262144, nullptr, nullptr, partb, 512, 512, 0,
            4, nty, 512 / ksq, ksq);
        combine_kernel<0><<<(unsigned)(MN / 256), 256, 0, stream>>>(
            partb, bv + l * 512, nullptr, qbuff, MN, ksq);
      }
      attnflash_kernel<0><<<64 * NCH, 256, 0, stream>>>(
          qself, nullptr, kbuff, qbuff, pmbf, plbf, pObf, L, u, NCH);
      x1bcast_kernel<<<(unsigned)(MN / 256), 256, 0, stream>>>(buf0f, mvWogf, kbuff, L);
      deltaWo_kernel<<<64 * u, 256, 0, stream>>>(pmbf, plbf, pObf, mvgf, topbf,
                                                 Wo + (size_t)l * 262144, kbuff,
                                                 L, u, NCH);
      ln_kernel<0, 0><<<BL, 256, 0, stream>>>(kbuff, g1 + l * 512, be1 + l * 512,
                                              qbuff, nullptr, nullptr, nullptr, 1);
      for (int r0 = 0; r0 < BL; r0 += 4096) {
        gemm128<1, 0, 0, 0><<<16 * 32, 256, 0, stream>>>(
            qbuff + (size_t)r0 * 512, w1 + (size_t)l * 2048 * 512, b1 + l * 2048,
            nullptr, buf0f, 2048, 512, 0, 16, 32, 512, 1);
        if (uks) {
          gemm128<0, 0, 0, 1><<<4 * 32 * 4, 256, 0, stream>>>(
              buf0f, w2 + (size_t)l * 512 * 2048, nullptr, nullptr, partb, 512,
              2048, 0, 4, 32, 512, 4);
          combine_kernel<1><<<4096 * 512 / 256, 256, 0, stream>>>(
              partb, b2 + l * 512, qbuff + (size_t)r0 * 512,
              kbuff + (size_t)r0 * 512, (size_t)4096 * 512, 4);
        } else {
          gemm128<0, 1, 0, 0><<<4 * 32, 256, 0, stream>>>(
              buf0f, w2 + (size_t)l * 512 * 2048, b2 + l * 512,
              qbuff + (size_t)r0 * 512, kbuff + (size_t)r0 * 512, 512, 2048, 0,
              4, 32, 2048, 1);
        }
      }
      ln_kernel<0, 0><<<BL, 256, 0, stream>>>(kbuff, g2 + l * 512, be2 + l * 512,
                                              buf0f, nullptr, nullptr, nullptr, 1);

      if (l < 2) {
        packw_kernel<<<512 * 1536 / 256, 256, 0, stream>>>(
            dw + (size_t)l * 512 * 512 * 3, wpack);
        int ksc = (gq >= 512 || !uks) ? 1 : 2;
        if (ksc == 1) {
          gemm128<0, 0, 1, 0><<<gq, 256, 0, stream>>>(
              buf0f, wpack, db + l * 512, nullptr, kbuff, 512, 1536, L - 1, 4,
              nty, 1536, 1);
        } else {
          gemm128<0, 0, 1, 1><<<gq * 2, 256, 0, stream>>>(
              buf0f, wpack, nullptr, nullptr, partb, 512, 1536, L - 1, 4, nty,
              768, 2);
          combine_kernel<0><<<(unsigned)(MN / 256), 256, 0, stream>>>(
              partb, db + l * 512, nullptr, kbuff, MN, 2);
        }
        int nb = BL / 128;
        bnpart_kernel<<<nb, 256, 0, stream>>>(kbuff, psumf, psqf, 128);
        bnfin_kernel<<<2, 256, 0, stream>>>(psumf, psqf, muvf, varvf, nb, BL);
        bnpool_kernel<0><<<(BL / 2) * 512 / 256, 256, 0, stream>>>(
            kbuff, muvf, varvf, bng + l * 512, bnb + l * 512, buf0f, nullptr,
            nullptr, L);
        L >>= 1;
      }
    }
    int BL = B * L;
    ln_kernel<0, 0><<<BL, 256, 0, stream>>>(buf0f, lnfg, lnfb, qbuff, nullptr,
                                            nullptr, nullptr, 1);
    end_kernel<<<BL, 64, 0, stream>>>(qbuff, endw, endb, out);
  }
}

// Round 9
// 1780.092 us; speedup vs baseline: 2.1702x; 1.1045x over previous
//
#include <hip/hip_runtime.h>
#include <cstdint>
#include <cstddef>

#define DMODEL 512
#define NHEAD 8
#define HD 64

typedef _Float16 half8 __attribute__((ext_vector_type(8)));
typedef float f32x4 __attribute__((ext_vector_type(4)));

// ---------------------------------------------------------------- threefry
__device__ __forceinline__ uint32_t rotl32(uint32_t x, int r) {
  return (x << r) | (x >> (32 - r));
}

__device__ __forceinline__ void tf_block(uint32_t k0, uint32_t k1,
                                         uint32_t& x0, uint32_t& x1) {
  uint32_t ks0 = k0, ks1 = k1, ks2 = k0 ^ k1 ^ 0x1BD11BDAu;
  x0 += ks0; x1 += ks1;
  x0 += x1; x1 = rotl32(x1, 13); x1 ^= x0;
  x0 += x1; x1 = rotl32(x1, 15); x1 ^= x0;
  x0 += x1; x1 = rotl32(x1, 26); x1 ^= x0;
  x0 += x1; x1 = rotl32(x1, 6);  x1 ^= x0;
  x0 += ks1; x1 += ks2 + 1u;
  x0 += x1; x1 = rotl32(x1, 17); x1 ^= x0;
  x0 += x1; x1 = rotl32(x1, 29); x1 ^= x0;
  x0 += x1; x1 = rotl32(x1, 16); x1 ^= x0;
  x0 += x1; x1 = rotl32(x1, 24); x1 ^= x0;
  x0 += ks2; x1 += ks0 + 2u;
  x0 += x1; x1 = rotl32(x1, 13); x1 ^= x0;
  x0 += x1; x1 = rotl32(x1, 15); x1 ^= x0;
  x0 += x1; x1 = rotl32(x1, 26); x1 ^= x0;
  x0 += x1; x1 = rotl32(x1, 6);  x1 ^= x0;
  x0 += ks0; x1 += ks1 + 3u;
  x0 += x1; x1 = rotl32(x1, 17); x1 ^= x0;
  x0 += x1; x1 = rotl32(x1, 29); x1 ^= x0;
  x0 += x1; x1 = rotl32(x1, 16); x1 ^= x0;
  x0 += x1; x1 = rotl32(x1, 24); x1 ^= x0;
  x0 += ks1; x1 += ks2 + 4u;
  x0 += x1; x1 = rotl32(x1, 13); x1 ^= x0;
  x0 += x1; x1 = rotl32(x1, 15); x1 ^= x0;
  x0 += x1; x1 = rotl32(x1, 26); x1 ^= x0;
  x0 += x1; x1 = rotl32(x1, 6);  x1 ^= x0;
  x0 += ks2; x1 += ks0 + 5u;
}

__global__ void idx_kernel(int* __restrict__ idxb, int n, int layer, int mask) {
  int e = blockIdx.x * 256 + threadIdx.x;
  if (e >= n) return;
  uint32_t f0 = 0u, f1 = (uint32_t)layer;
  tf_block(0u, 42u, f0, f1);
  uint32_t s0 = 0u, s1 = 1u;
  tf_block(f0, f1, s0, s1);
  uint32_t x0 = 0u, x1 = (uint32_t)e;
  tf_block(s0, s1, x0, x1);
  uint32_t bits = x0 ^ x1;
  idxb[e] = (int)(bits & (uint32_t)mask);
}

// ---------------------------------------------------------------- fp16 hi/lo split helpers
__device__ __forceinline__ void f2hsplit(float v, unsigned short& h,
                                         unsigned short& l) {
  _Float16 hh = (_Float16)v;          // RNE
  float r = v - (float)hh;            // exact
  _Float16 ll = (_Float16)r;
  h = __builtin_bit_cast(unsigned short, hh);
  l = __builtin_bit_cast(unsigned short, ll);
}

__device__ __forceinline__ float gelu_f(float v) {
  return 0.5f * v * (1.0f + erff(v * 0.7071067811865476f));
}

// address-space cast helpers for global_load_lds
#define AS1G(p) ((const __attribute__((address_space(1))) void*)(size_t)(p))
#define AS3L(p) ((__attribute__((address_space(3))) void*)(unsigned)(size_t)(p))
#define GLD16(g, l) __builtin_amdgcn_global_load_lds(AS1G(g), AS3L(l), 16, 0, 0)

// ---------------------------------------------------------------- fp32 -> fp16 hi/lo conversion
__device__ __forceinline__ void cvt_body(const float* __restrict__ X,
                                         unsigned short* __restrict__ H,
                                         unsigned short* __restrict__ Lo,
                                         int i) {
  const float4* xp = (const float4*)X + 2 * (size_t)i;
  float4 a = xp[0], b = xp[1];
  float v[8] = {a.x, a.y, a.z, a.w, b.x, b.y, b.z, b.w};
  unsigned hu[4], lu[4];
#pragma unroll
  for (int q = 0; q < 4; ++q) {
    unsigned short h0, l0, h1, l1;
    f2hsplit(v[2 * q], h0, l0);
    f2hsplit(v[2 * q + 1], h1, l1);
    hu[q] = (unsigned)h0 | ((unsigned)h1 << 16);
    lu[q] = (unsigned)l0 | ((unsigned)l1 << 16);
  }
  uint4 hv; hv.x = hu[0]; hv.y = hu[1]; hv.z = hu[2]; hv.w = hu[3];
  uint4 lv; lv.x = lu[0]; lv.y = lu[1]; lv.z = lu[2]; lv.w = lu[3];
  *(uint4*)(H + 8 * (size_t)i) = hv;
  *(uint4*)(Lo + 8 * (size_t)i) = lv;
}

__global__ __launch_bounds__(256) void cvt_kernel(const float* __restrict__ X,
                                                  unsigned short* __restrict__ H,
                                                  unsigned short* __restrict__ Lo,
                                                  int n8) {
  int i = blockIdx.x * 256 + threadIdx.x;
  if (i >= n8) return;
  cvt_body(X, H, Lo, i);
}

// merged per-layer weight conversion: Wq/Wk/Wv -> Wqkv (3x128 blocks),
// w1 (512), w2 (512). Grid = 1408, all ranges exact.
__global__ __launch_bounds__(256) void cvt5_kernel(
    const float* __restrict__ Wq, const float* __restrict__ Wk,
    const float* __restrict__ Wv, const float* __restrict__ w1,
    const float* __restrict__ w2, unsigned short* __restrict__ Qh,
    unsigned short* __restrict__ Ql, unsigned short* __restrict__ w1h,
    unsigned short* __restrict__ w1l, unsigned short* __restrict__ w2h,
    unsigned short* __restrict__ w2l) {
  int blk = blockIdx.x;
  const float* src;
  unsigned short* H;
  unsigned short* Lo;
  int lb;
  if (blk < 384) {
    int wsel = blk >> 7;
    lb = blk & 127;
    src = (wsel == 0) ? Wq : (wsel == 1 ? Wk : Wv);
    H = Qh + (size_t)wsel * 262144;
    Lo = Ql + (size_t)wsel * 262144;
  } else if (blk < 896) {
    lb = blk - 384;
    src = w1; H = w1h; Lo = w1l;
  } else {
    lb = blk - 896;
    src = w2; H = w2h; Lo = w2l;
  }
  cvt_body(src, H, Lo, lb * 256 + threadIdx.x);
}

// conv weight pack + split: wp[o][w*512+c] = dw[o][c][w]
__global__ void packw2_kernel(const float* __restrict__ dw,
                              unsigned short* __restrict__ Hh,
                              unsigned short* __restrict__ Hl) {
  int gid = blockIdx.x * 256 + threadIdx.x;  // 512*1536
  int o = gid / 1536;
  int kk = gid - o * 1536;
  int ww = kk / 512;
  int c = kk - ww * 512;
  float v = dw[((size_t)o * 512 + c) * 3 + ww];
  unsigned short h, l;
  f2hsplit(v, h, l);
  Hh[gid] = h;
  Hl[gid] = l;
}

// ---------------------------------------------------------------- MFMA GEMM 128x128, split-fp16 3-product, BK=32
// __launch_bounds__(256,4): acc alone is 64 VGPRs; (256,5) -> spill (r5).
// LDS 32 KB. Swizzle: slot ^= (row>>1)&3 (conflict-free, r4 verified).
// PART: K-split partials (raw fp32, no bias/act) -> C + kb*M*N.
template <int ACT, int HASR, int CONV, int F16OUT, int QKV, int PART>
__global__ __launch_bounds__(256, 4) void gemm_mfma(
    const unsigned short* __restrict__ Ah, const unsigned short* __restrict__ Al,
    const unsigned short* __restrict__ Wh, const unsigned short* __restrict__ Wl,
    const float* __restrict__ bias, const float* __restrict__ bias2,
    const float* __restrict__ bias3, const float* __restrict__ Rres,
    float* __restrict__ C, float* __restrict__ C2, float* __restrict__ C3,
    unsigned short* __restrict__ Ch, unsigned short* __restrict__ Cl,
    int N, int K, int Lmask, int ntx, int nty, int kloop) {
  __shared__ __attribute__((aligned(16))) unsigned short AsH[4096];
  __shared__ __attribute__((aligned(16))) unsigned short AsL[4096];
  __shared__ __attribute__((aligned(16))) unsigned short WsH[4096];
  __shared__ __attribute__((aligned(16))) unsigned short WsL[4096];
  const int tid = threadIdx.x;
  int blk = blockIdx.x;
  int kb = 0;
  if (PART) {
    const int tiles = ntx * nty;
    kb = blk / tiles;
    blk -= kb * tiles;
  }
  const int koff = PART ? kb * kloop : 0;
  const int xcd = blk & 7;
  const int j = blk >> 3;
  const int jr = j / ntx;
  const int row_t = xcd * (nty >> 3) + jr;
  const int col_t = j - jr * ntx;
  const int row0 = row_t << 7, col0 = col_t << 7;
  const int lane = tid & 63;
  const int wv = tid >> 6;
  const int wr = wv >> 1, wc = wv & 1;  // wave's 64x64 quadrant
  const int srow = lane >> 2;                          // 0..15
  const int skoff = (((lane & 3) ^ ((lane >> 3) & 3)) << 3);
  const int l15 = lane & 15, lg = lane >> 4;
  const int slotx = ((lg ^ ((l15 >> 1) & 3)) << 4);
  int oa[4], ow[4];
#pragma unroll
  for (int t = 0; t < 4; ++t) {
    oa[t] = (((wr << 6) + (t << 4) + l15) << 6) + slotx;
    ow[t] = (((wc << 6) + (t << 4) + l15) << 6) + slotx;
  }
  f32x4 acc[4][4] = {};
  const int T = (PART ? kloop : K) >> 5;
  for (int it = 0; it < T; ++it) {
    const int k0 = koff + (it << 5);
    int wwin = 0, kc = k0;
    if (CONV) { wwin = k0 >> 9; kc = k0 & 511; }
#pragma unroll
    for (int g = 0; g < 2; ++g) {
      const int R0 = (wv << 5) + (g << 4);
      const int rr = R0 + srow;
      size_t aoff;
      if (CONV) {
        int t0 = row0 + rr;
        int tcv = t0 & Lmask, bb = t0 & ~Lmask;
        int src = bb | ((tcv - 1 + wwin) & Lmask);
        aoff = (size_t)src * 512 + (kc + skoff);
      } else {
        aoff = (size_t)(row0 + rr) * K + (k0 + skoff);
      }
      size_t woff = (size_t)(col0 + rr) * K + (k0 + skoff);
      GLD16(Ah + aoff, AsH + R0 * 32);
      GLD16(Al + aoff, AsL + R0 * 32);
      GLD16(Wh + woff, WsH + R0 * 32);
      GLD16(Wl + woff, WsL + R0 * 32);
    }
    __syncthreads();
    half8 fah[4], fal[4];
#pragma unroll
    for (int t = 0; t < 4; ++t) {
      fah[t] = *(const half8*)((const char*)AsH + oa[t]);
      fal[t] = *(const half8*)((const char*)AsL + oa[t]);
    }
#pragma unroll
    for (int ni = 0; ni < 4; ++ni) {
      half8 bh = *(const half8*)((const char*)WsH + ow[ni]);
      half8 bl = *(const half8*)((const char*)WsL + ow[ni]);
#pragma unroll
      for (int mi = 0; mi < 4; ++mi) {
        acc[mi][ni] = __builtin_amdgcn_mfma_f32_16x16x32_f16(
            fah[mi], bh, acc[mi][ni], 0, 0, 0);
        acc[mi][ni] = __builtin_amdgcn_mfma_f32_16x16x32_f16(
            fah[mi], bl, acc[mi][ni], 0, 0, 0);
        acc[mi][ni] = __builtin_amdgcn_mfma_f32_16x16x32_f16(
            fal[mi], bh, acc[mi][ni], 0, 0, 0);
      }
    }
    __syncthreads();
  }
  // epilogue: D lane mapping col=l15, row=lg*4+q
  if (PART) {
    float* Cp = C + (size_t)kb * ((size_t)(nty << 7)) * N;
#pragma unroll
    for (int mi = 0; mi < 4; ++mi)
#pragma unroll
      for (int q = 0; q < 4; ++q) {
        const int m = row0 + (wr << 6) + (mi << 4) + (lg << 2) + q;
#pragma unroll
        for (int ni = 0; ni < 4; ++ni) {
          const int col = col0 + (wc << 6) + (ni << 4) + l15;
          Cp[(size_t)m * N + col] = acc[mi][ni][q];
        }
      }
    return;
  }
  int cbase = col0;
  float* Cb = C;
  const float* bb = bias;
  if (QKV) {
    const int cb = col0 >> 9;
    cbase = col0 & 511;
    Cb = (cb == 0) ? C : ((cb == 1) ? C2 : C3);
    bb = (cb == 0) ? bias : ((cb == 1) ? bias2 : bias3);
  }
  const int OSTR = QKV ? 512 : N;
  float bsv[4];
#pragma unroll
  for (int ni = 0; ni < 4; ++ni)
    bsv[ni] = bb[cbase + (wc << 6) + (ni << 4) + l15];
#pragma unroll
  for (int mi = 0; mi < 4; ++mi) {
#pragma unroll
    for (int q = 0; q < 4; ++q) {
      const int m = row0 + (wr << 6) + (mi << 4) + (lg << 2) + q;
#pragma unroll
      for (int ni = 0; ni < 4; ++ni) {
        const int col = cbase + (wc << 6) + (ni << 4) + l15;
        float v = acc[mi][ni][q] + bsv[ni];
        if (HASR) v += Rres[(size_t)m * OSTR + col];
        if (ACT == 1) v = gelu_f(v);
        if (F16OUT) {
          unsigned short h, lo;
          f2hsplit(v, h, lo);
          Ch[(size_t)m * OSTR + col] = h;
          Cl[(size_t)m * OSTR + col] = lo;
        } else {
          Cb[(size_t)m * OSTR + col] = v;
        }
      }
    }
  }
}

// ---------------------------------------------------------------- fp32 GEMM (fallback path only)
template <int ACT, int HASR, int CONV, int PART>
__global__ __launch_bounds__(256, 2) void gemm128(
    const float* __restrict__ A, const float* __restrict__ W,
    const float* __restrict__ bias, const float* Rres, float* C,
    int N, int K, int Lmask, int ntx, int nty, int kloop, int ks) {
  __shared__ float As[16][140];
  __shared__ float Ws[16][140];
  const int tid = threadIdx.x;
  int blk = blockIdx.x;
  const int tiles = ntx * nty;
  int kb = 0;
  if (PART) { kb = blk / tiles; blk -= kb * tiles; }
  const int koff = kb * kloop;
  const int xcd = blk & 7;
  const int j = blk >> 3;
  const int jr = j / ntx;
  const int row_t = xcd * (nty >> 3) + jr;
  const int col_t = j - jr * ntx;
  const int row0 = row_t * 128, col0 = col_t * 128;

  const int ar = tid >> 1;
  const int ac = (tid & 1) << 3;
  const int arp = ar + ((ar >> 5) << 2);
  const int tx = tid & 15, ty = tid >> 4;
  const int wcol = tx * 8 + ((tx >> 2) << 2);
  const int acol = ty * 8 + ((ty >> 2) << 2);
  const int arow = row0 + ar;
  const float* Wp = W + (size_t)(col0 + ar) * K + koff + ac;
  const float* Ap = A + (size_t)arow * K + koff + ac;
  int tcv = 0, bbase = 0;
  if (CONV) { tcv = arow & Lmask; bbase = arow & ~Lmask; }
  float4 ra0, ra1, rw0, rw1;
  float acc[8][8] = {};
  const int T = kloop >> 4;

  {
    const float* ap;
    if (CONV) {
      int kabs = koff;
      int w = kabs >> 9;
      int src = bbase | ((tcv - 1 + w) & Lmask);
      ap = A + (size_t)src * 512 + (kabs & 511) + ac;
    } else {
      ap = Ap;
    }
    ra0 = *(const float4*)(ap);
    ra1 = *(const float4*)(ap + 4);
    rw0 = *(const float4*)(Wp);
    rw1 = *(const float4*)(Wp + 4);
  }

  for (int it = 0; it < T; ++it) {
#pragma unroll
    for (int q = 0; q < 4; q++) {
      As[ac + q][arp] = ((float*)&ra0)[q];
      As[ac + 4 + q][arp] = ((float*)&ra1)[q];
      Ws[ac + q][arp] = ((float*)&rw0)[q];
      Ws[ac + 4 + q][arp] = ((float*)&rw1)[q];
    }
    __syncthreads();
    if (it + 1 < T) {
      const int k0 = (it + 1) << 4;
      const float* ap;
      if (CONV) {
        int kabs = koff + k0;
        int w = kabs >> 9;
        int src = bbase | ((tcv - 1 + w) & Lmask);
        ap = A + (size_t)src * 512 + (kabs & 511) + ac;
      } else {
        ap = Ap + k0;
      }
      ra0 = *(const float4*)(ap);
      ra1 = *(const float4*)(ap + 4);
      rw0 = *(const float4*)(Wp + k0);
      rw1 = *(const float4*)(Wp + k0 + 4);
    }
#pragma unroll
    for (int k = 0; k < 16; k++) {
      float av[8], wvv[8];
      *(float4*)(av) = *(const float4*)&As[k][acol];
      *(float4*)(av + 4) = *(const float4*)&As[k][acol + 4];
      *(float4*)(wvv) = *(const float4*)&Ws[k][wcol];
      *(float4*)(wvv + 4) = *(const float4*)&Ws[k][wcol + 4];
#pragma unroll
      for (int i = 0; i < 8; i++)
#pragma unroll
        for (int q = 0; q < 8; q++) acc[i][q] += av[i] * wvv[q];
    }
    __syncthreads();
  }

  if (PART) {
    float* Cp = C + (size_t)kb * (nty << 7) * N;
#pragma unroll
    for (int i = 0; i < 8; i++) {
      const int m = row0 + ty * 8 + i;
      const int c0 = col0 + tx * 8;
      *(float4*)(Cp + (size_t)m * N + c0) = *(float4*)(&acc[i][0]);
      *(float4*)(Cp + (size_t)m * N + c0 + 4) = *(float4*)(&acc[i][4]);
    }
  } else {
#pragma unroll
    for (int i = 0; i < 8; i++) {
      const int m = row0 + ty * 8 + i;
      const int c0 = col0 + tx * 8;
      float vout[8];
#pragma unroll
      for (int q = 0; q < 8; q++) {
        float v = acc[i][q] + bias[c0 + q];
        if (HASR) v += Rres[(size_t)m * N + c0 + q];
        if (ACT == 1) v = gelu_f(v);
        vout[q] = v;
      }
      *(float4*)(C + (size_t)m * N + c0) = *(float4*)(vout);
      *(float4*)(C + (size_t)m * N + c0 + 4) = *(float4*)(vout + 4);
    }
  }
}

template <int HASR>
__global__ __launch_bounds__(256) void combine_kernel(
    const float* __restrict__ part, const float* __restrict__ bias,
    const float* Rres, float* __restrict__ Cout, size_t MN, int ks) {
  size_t gid = (size_t)blockIdx.x * 256 + threadIdx.x;
  int c = (int)(gid & 511);
  float v = 0.f;
  for (int kb = 0; kb < ks; kb++) v += part[kb * MN + gid];
  v += bias[c];
  if (HASR) v += Rres[gid];
  Cout[gid] = v;
}

// ---------------------------------------------------------------- positional-encoding table (batch-invariant)
__global__ void petab_kernel(float* __restrict__ pe, int S) {
  int gid = blockIdx.x * 256 + threadIdx.x;  // S*512
  int o = gid & 511;
  int t = gid >> 9;
  int i2 = o >> 1;
  float dv = expf((float)(2 * i2) * (-9.210340371976184f / 512.0f));
  float ang = (float)t * dv;
  pe[gid] = (o & 1) ? cosf(ang) : sinf(ang);
}

// ---------------------------------------------------------------- token conv + pos embed (+hi/lo)
template <int EMIT, int PE>
__global__ void tokpe_kernel(const float* __restrict__ xe,
                             const float* __restrict__ w,
                             const float* __restrict__ pe,
                             float* __restrict__ out,
                             unsigned short* __restrict__ Hh,
                             unsigned short* __restrict__ Hl, int S) {
  int gid = blockIdx.x * 256 + threadIdx.x;  // B*S*512
  int o = gid & 511;
  int bt = gid >> 9;
  int t = bt % S, b = bt / S;
  float acc = 0.f;
#pragma unroll
  for (int ww = 0; ww < 3; ww++) {
    int tt = t - 1 + ww;
    tt = (tt < 0) ? tt + S : (tt >= S ? tt - S : tt);
    const float* xr = xe + ((size_t)(b * S + tt)) * 7;
#pragma unroll
    for (int i = 0; i < 7; i++) acc += xr[i] * w[o * 21 + i * 3 + ww];
  }
  if (PE) {
    acc += pe[(t << 9) | o];
  } else {
    int i2 = o >> 1;
    float dv = expf((float)(2 * i2) * (-9.210340371976184f / 512.0f));
    float ang = (float)t * dv;
    acc += (o & 1) ? cosf(ang) : sinf(ang);
  }
  out[gid] = acc;
  if (EMIT) {
    unsigned short h, l;
    f2hsplit(acc, h, l);
    Hh[gid] = h;
    Hl[gid] = l;
  }
}

// ---------------------------------------------------------------- conv weight pack (fallback fp32)
__global__ void packw_kernel(const float* __restrict__ dw, float* __restrict__ wp) {
  int gid = blockIdx.x * 256 + threadIdx.x;  // 512*1536
  int o = gid / 1536;
  int kk = gid - o * 1536;
  int ww = kk / 512;
  int c = kk - ww * 512;
  wp[gid] = dw[((size_t)o * 512 + c) * 3 + ww];
}

// ---------------------------------------------------------------- M score, 4 lanes per query, threefry fused
__global__ __launch_bounds__(256) void mscore4_kernel(
    const float* __restrict__ Q, const float* __restrict__ Kb,
    float* __restrict__ Mout, int L, int U, int layer) {
  __shared__ int sidx[64 * 24];
  int i = blockIdx.x;  // b + 8*(h*chunks + c), 64 queries per block
  int b = i & 7;
  int j = i >> 3;
  int chunks = L >> 6;
  int h = j / chunks;
  int c = j - h * chunks;
  int t0 = c << 6;
  int tid = threadIdx.x;
  const int nidx = 64 * U;
  const int mask = L - 1;
  {
    uint32_t f0 = 0u, f1 = (uint32_t)layer;
    tf_block(0u, 42u, f0, f1);
    uint32_t s0 = 0u, s1 = 1u;
    tf_block(f0, f1, s0, s1);
    for (int k = tid; k < nidx; k += 256) {
      int e = t0 * U + k;
      uint32_t x0 = 0u, x1 = (uint32_t)e;
      tf_block(s0, s1, x0, x1);
      sidx[k] = (int)((x0 ^ x1) & (uint32_t)mask);
    }
  }
  __syncthreads();
  int tsub = tid >> 2, sub = tid & 3;
  int t = t0 + tsub;
  const float4* qr =
      (const float4*)(Q + ((size_t)(b * L + t)) * DMODEL + h * HD + sub * 16);
  float4 q0 = qr[0], q1 = qr[1], q2 = qr[2], q3 = qr[3];
  const float* Kh = Kb + (size_t)b * L * DMODEL + h * HD + sub * 16;
  float mx = -3.4e38f, sm = 0.f;
  int krn = sidx[tsub * U];
  for (int jj = 0; jj < U; ++jj) {
    const float4* kp = (const float4*)(Kh + (size_t)krn * DMODEL);
    krn = sidx[tsub * U + ((jj + 1 < U) ? jj + 1 : jj)];
    float4 k0 = kp[0], k1 = kp[1], k2 = kp[2], k3 = kp[3];
    float dot = q0.x * k0.x + q0.y * k0.y + q0.z * k0.z + q0.w * k0.w +
                q1.x * k1.x + q1.y * k1.y + q1.z * k1.z + q1.w * k1.w +
                q2.x * k2.x + q2.y * k2.y + q2.z * k2.z + q2.w * k2.w +
                q3.x * k3.x + q3.y * k3.y + q3.z * k3.z + q3.w * k3.w;
    dot += __shfl_xor(dot, 1);
    dot += __shfl_xor(dot, 2);
    mx = fmaxf(mx, dot);
    sm += dot;
  }
  if (sub == 0) Mout[(size_t)(b * 8 + h) * L + t] = mx - sm / (float)L;
}

// ---------------------------------------------------------------- M score (fallback)
__global__ __launch_bounds__(256) void mscore_kernel(
    const float* __restrict__ Q, const float* __restrict__ Kb,
    const int* __restrict__ idxb, float* __restrict__ Mout, int L, int U) {
  int i = blockIdx.x;
  int b = i & 7;
  int j = i >> 3;
  int chunks = L >> 8;
  int h = j / chunks;
  int c = j - h * chunks;
  int t = c * 256 + threadIdx.x;
  const float4* qr = (const float4*)(Q + ((size_t)(b * L + t)) * DMODEL + h * HD);
  float4 qv[16];
#pragma unroll
  for (int ii = 0; ii < 16; ii++) qv[ii] = qr[ii];
  float mx = -3.4e38f, sm = 0.f;
  for (int jj = 0; jj < U; jj++) {
    int kr = idxb[t * U + jj];
    const float4* kp =
        (const float4*)(Kb + ((size_t)(b * L + kr)) * DMODEL + h * HD);
    float dot = 0.f;
#pragma unroll
    for (int ii = 0; ii < 16; ii++) {
      float4 kv = kp[ii];
      dot += qv[ii].x * kv.x + qv[ii].y * kv.y + qv[ii].z * kv.z + qv[ii].w * kv.w;
    }
    mx = fmaxf(mx, dot);
    sm += dot;
  }
  Mout[(size_t)(b * 8 + h) * L + t] = mx - sm / (float)L;
}

// ---------------------------------------------------------------- top-k
__global__ __launch_bounds__(256) void topk_kernel(const float* __restrict__ Mv,
                                                   int* __restrict__ topb, int L,
                                                   int u) {
  __shared__ float wv_s[4];
  __shared__ int wi_s[4];
  __shared__ int best_s;
  int bh = blockIdx.x, tid = threadIdx.x;
  int lane = tid & 63, w = tid >> 6;
  int cnt = L >> 8;
  float lv[8];
  for (int i = 0; i < cnt; i++) lv[i] = Mv[(size_t)bh * L + i * 256 + tid];
  for (int r = 0; r < u; r++) {
    float bv = -3.4e38f;
    int bi = 0x7fffffff;
    for (int i = 0; i < cnt; i++) {
      if (lv[i] > bv) { bv = lv[i]; bi = i * 256 + tid; }
    }
    for (int s = 32; s > 0; s >>= 1) {
      float ov = __shfl_down(bv, s);
      int oi = __shfl_down(bi, s);
      if (ov > bv || (ov == bv && oi < bi)) { bv = ov; bi = oi; }
    }
    if (lane == 0) { wv_s[w] = bv; wi_s[w] = bi; }
    __syncthreads();
    if (tid == 0) {
      float fv = wv_s[0];
      int fi = wi_s[0];
      for (int q = 1; q < 4; q++) {
        if (wv_s[q] > fv || (wv_s[q] == fv && wi_s[q] < fi)) {
          fv = wv_s[q];
          fi = wi_s[q];
        }
      }
      best_s = fi;
      topb[bh * u + r] = fi;
    }
    __syncthreads();
    int win = best_s;
    if ((win & 255) == tid) lv[win >> 8] = -3.4e38f;
  }
}

// ---------------------------------------------------------------- gather selected q rows (fallback paths)
__global__ void gatherq_kernel(const float* __restrict__ Q,
                               const int* __restrict__ topb,
                               float* __restrict__ qsel, int L, int u) {
  int i = blockIdx.x;
  int bh = i / u;
  int b = bh >> 3, h = bh & 7;
  int t = topb[i];
  qsel[i * HD + threadIdx.x] =
      Q[((size_t)(b * L + t)) * DMODEL + h * HD + threadIdx.x];
}

// ---------------------------------------------------------------- mean of x rows per batch
// 32 groups/batch -> grid 256 (MFMA path)
__global__ __launch_bounds__(256) void xmean32_kernel(const float* __restrict__ x,
                                                      float* __restrict__ psumx,
                                                      int L) {
  int i = blockIdx.x;  // 256: b*32+g
  int b = i >> 5, g = i & 31;
  int rows = L >> 5;
  int tid = threadIdx.x;
  const float* base = x + ((size_t)b * L + (size_t)g * rows) * DMODEL;
  float s0 = 0.f, s1 = 0.f;
  for (int t = 0; t < rows; t++) {
    s0 += base[(size_t)t * DMODEL + tid];
    s1 += base[(size_t)t * DMODEL + tid + 256];
  }
  psumx[i * DMODEL + tid] = s0;
  psumx[i * DMODEL + tid + 256] = s1;
}

// fallback: 8 groups/batch (grid 64)
__global__ __launch_bounds__(256) void xmean_kernel(const float* __restrict__ x,
                                                    float* __restrict__ psumx,
                                                    int L) {
  int i = blockIdx.x;
  int b = i >> 3, g = i & 7;
  int rows = L >> 3;
  int tid = threadIdx.x;
  const float* base = x + ((size_t)b * L + (size_t)g * rows) * DMODEL;
  float s0 = 0.f, s1 = 0.f;
  for (int t = 0; t < rows; t++) {
    s0 += base[(size_t)t * DMODEL + tid];
    s1 += base[(size_t)t * DMODEL + tid + 256];
  }
  psumx[i * DMODEL + tid] = s0;
  psumx[i * DMODEL + tid + 256] = s1;
}

// mv = xm@Wv^T + bv : grid 64 (8 b x 8 ngroups), 4 lanes per output
__global__ __launch_bounds__(256) void mvmake1_kernel(
    const float* __restrict__ psumx, const float* __restrict__ Wv,
    const float* __restrict__ bv, float* __restrict__ mvg, int L, int ng) {
  __shared__ float xm[512];
  int blk = blockIdx.x;
  int b = blk >> 3, grp = blk & 7;
  int tid = threadIdx.x;
  float inv = 1.0f / (float)L;
  for (int nn = 0; nn < 2; nn++) {
    int c = tid + nn * 256;
    float s = 0.f;
    for (int g = 0; g < ng; g++) s += psumx[(b * ng + g) * DMODEL + c];
    xm[c] = s * inv;
  }
  __syncthreads();
  int n = grp * 64 + (tid >> 2);
  int sub = tid & 3;
  const float* wr = Wv + (size_t)n * 512 + sub * 128;
  const float* xp = xm + sub * 128;
  float s = 0.f;
  for (int k = 0; k < 128; k += 4) {
    float4 w4 = *(const float4*)(wr + k);
    s += xp[k] * w4.x + xp[k + 1] * w4.y + xp[k + 2] * w4.z + xp[k + 3] * w4.w;
  }
  s += __shfl_xor(s, 1);
  s += __shfl_xor(s, 2);
  if (sub == 0) mvg[b * DMODEL + n] = s + bv[n];
}

// mvWo = mv@Wo^T + bo : grid 64
__global__ __launch_bounds__(256) void mvmake2_kernel(
    const float* __restrict__ mvg, const float* __restrict__ Wo,
    const float* __restrict__ bo, float* __restrict__ mvWog) {
  __shared__ float mv[512];
  int blk = blockIdx.x;
  int b = blk >> 3, grp = blk & 7;
  int tid = threadIdx.x;
  mv[tid] = mvg[b * DMODEL + tid];
  mv[tid + 256] = mvg[b * DMODEL + tid + 256];
  __syncthreads();
  int n = grp * 64 + (tid >> 2);
  int sub = tid & 3;
  const float* wr = Wo + (size_t)n * 512 + sub * 128;
  const float* xp = mv + sub * 128;
  float s = 0.f;
  for (int k = 0; k < 128; k += 4) {
    float4 w4 = *(const float4*)(wr + k);
    s += xp[k] * w4.x + xp[k + 1] * w4.y + xp[k + 2] * w4.z + xp[k + 3] * w4.w;
  }
  s += __shfl_xor(s, 1);
  s += __shfl_xor(s, 2);
  if (sub == 0) mvWog[b * DMODEL + n] = s + bo[n];
}

// fallback mvmake (8 blocks, original order)
__global__ __launch_bounds__(256) void mvmake_kernel(
    const float* __restrict__ psumx, const float* __restrict__ Wv,
    const float* __restrict__ bv, const float* __restrict__ Wo,
    const float* __restrict__ bo, float* __restrict__ mvg,
    float* __restrict__ mvWog, int L) {
  __shared__ float xm[512];
  __shared__ float mvs[512];
  int b = blockIdx.x, tid = threadIdx.x;
  float inv = 1.0f / (float)L;
  for (int nn = 0; nn < 2; nn++) {
    int c = tid + nn * 256;
    float s = 0.f;
    for (int g = 0; g < 8; g++) s += psumx[(b * 8 + g) * DMODEL + c];
    xm[c] = s * inv;
  }
  __syncthreads();
  for (int nn = 0; nn < 2; nn++) {
    int n = tid + nn * 256;
    const float* wr = Wv + (size_t)n * 512;
    float s = bv[n];
    for (int k = 0; k < 512; k += 4) {
      float4 w4 = *(const float4*)(wr + k);
      s += xm[k] * w4.x + xm[k + 1] * w4.y + xm[k + 2] * w4.z + xm[k + 3] * w4.w;
    }
    mvs[n] = s;
    mvg[b * DMODEL + n] = s;
  }
  __syncthreads();
  for (int nn = 0; nn < 2; nn++) {
    int n = tid + nn * 256;
    const float* wr = Wo + (size_t)n * 512;
    float s = bo[n];
    for (int k = 0; k < 512; k += 4) {
      float4 w4 = *(const float4*)(wr + k);
      s += mvs[k] * w4.x + mvs[k + 1] * w4.y + mvs[k + 2] * w4.z +
           mvs[k + 3] * w4.w;
    }
    mvWog[b * DMODEL + n] = s;
  }
}

__global__ void x1bcast_kernel(const float* __restrict__ x,
                               const float* __restrict__ mvWog,
                               float* __restrict__ x1, int L) {
  int gid = blockIdx.x * 256 + threadIdx.x;
  int c = gid & 511;
  int r = gid >> 9;
  int b = r / L;
  x1[gid] = x[gid] + mvWog[b * DMODEL + c];
}

// ---------------------------------------------------------------- chunked flash attention for selected rows
template <int GQ>
__global__ __launch_bounds__(256) void attnflash_kernel(
    const float* __restrict__ qsrc, const int* __restrict__ topb,
    const float* __restrict__ Kb, const float* __restrict__ Vb,
    float* __restrict__ pm, float* __restrict__ pl, float* __restrict__ pO,
    int L, int u, int nchunk) {
  __shared__ float qs[24][64];
  __shared__ float Kt[64][68];
  __shared__ float Ps[24][68];
  int blk = blockIdx.x;
  int bh = blk / nchunk;
  int c = blk - bh * nchunk;
  int b = bh >> 3, h = bh & 7;
  int cs = L / nchunk;
  int tid = threadIdx.x;
  int lane = tid & 63;
  int w = tid >> 6;
  if (GQ) {
    for (int i = tid; i < u * 64; i += 256) {
      int r = i >> 6, d = i & 63;
      int t = topb[bh * u + r];
      qs[r][d] = qsrc[((size_t)(b * L + t)) * DMODEL + h * HD + d];
    }
  } else {
    for (int i = tid; i < u * 64; i += 256)
      qs[i >> 6][i & 63] = qsrc[(size_t)bh * u * 64 + i];
  }
  float m[6], l[6], O[6];
#pragma unroll
  for (int k = 0; k < 6; k++) { m[k] = -3.4e38f; l[k] = 0.f; O[k] = 0.f; }
  const float* Kbase = Kb + (size_t)b * L * DMODEL + h * HD;
  const float* Vbase = Vb + (size_t)b * L * DMODEL + h * HD;
  const int jrow = tid & 63;
  const int dch = (tid >> 6) << 4;
  for (int j0 = c * cs; j0 < (c + 1) * cs; j0 += 64) {
    __syncthreads();
    const float* kr = Kbase + (size_t)(j0 + jrow) * DMODEL + dch;
    float4 k0 = *(const float4*)(kr);
    float4 k1 = *(const float4*)(kr + 4);
    float4 k2 = *(const float4*)(kr + 8);
    float4 k3 = *(const float4*)(kr + 12);
#pragma unroll
    for (int q = 0; q < 4; q++) {
      Kt[dch + q][jrow] = ((float*)&k0)[q];
      Kt[dch + 4 + q][jrow] = ((float*)&k1)[q];
      Kt[dch + 8 + q][jrow] = ((float*)&k2)[q];
      Kt[dch + 12 + q][jrow] = ((float*)&k3)[q];
    }
    __syncthreads();
#pragma unroll
    for (int k = 0; k < 6; k++) {
      int qi = 4 * k + w;
      if (qi >= u) break;
      float s = 0.f;
#pragma unroll
      for (int d = 0; d < 64; d++) s += qs[qi][d] * Kt[d][lane];
      s *= 0.125f;
      float mx = s;
#pragma unroll
      for (int off = 32; off > 0; off >>= 1)
        mx = fmaxf(mx, __shfl_down(mx, off));
      mx = __shfl(mx, 0);
      float mnew = fmaxf(m[k], mx);
      float p = expf(s - mnew);
      float ps = p;
#pragma unroll
      for (int off = 32; off > 0; off >>= 1) ps += __shfl_down(ps, off);
      ps = __shfl(ps, 0);
      float alpha = expf(m[k] - mnew);
      l[k] = l[k] * alpha + ps;
      m[k] = mnew;
      O[k] *= alpha;
      Ps[qi][lane] = p;
    }
    for (int jj = 0; jj < 64; jj += 4) {
      float v0 = Vbase[(size_t)(j0 + jj) * DMODEL + lane];
      float v1 = Vbase[(size_t)(j0 + jj + 1) * DMODEL + lane];
      float v2 = Vbase[(size_t)(j0 + jj + 2) * DMODEL + lane];
      float v3 = Vbase[(size_t)(j0 + jj + 3) * DMODEL + lane];
#pragma unroll
      for (int k = 0; k < 6; k++) {
        int qi = 4 * k + w;
        if (qi >= u) break;
        O[k] += Ps[qi][jj] * v0 + Ps[qi][jj + 1] * v1 + Ps[qi][jj + 2] * v2 +
                Ps[qi][jj + 3] * v3;
      }
    }
  }
#pragma unroll
  for (int k = 0; k < 6; k++) {
    int qi = 4 * k + w;
    if (qi < u) {
      int p = (bh * nchunk + c) * u + qi;
      if (lane == 0) { pm[p] = m[k]; pl[p] = l[k]; }
      pO[(size_t)p * 64 + lane] = O[k];
    }
  }
}

__global__ __launch_bounds__(256) void deltaWo_kernel(
    const float* __restrict__ pm, const float* __restrict__ pl,
    const float* __restrict__ pO, const float* __restrict__ mvg,
    const int* __restrict__ topb, const float* __restrict__ Wo, float* x1,
    int L, int u, int nchunk) {
  __shared__ float ds[64];
  int sel = blockIdx.x;
  int bh = sel / u;
  int qi = sel - bh * u;
  int b = bh >> 3, h = bh & 7;
  int t = topb[sel];
  int tid = threadIdx.x;
  if (tid < 64) {
    float mstar = -3.4e38f;
    for (int c = 0; c < nchunk; c++)
      mstar = fmaxf(mstar, pm[(bh * nchunk + c) * u + qi]);
    float lstar = 0.f, O = 0.f;
    for (int c = 0; c < nchunk; c++) {
      int p = (bh * nchunk + c) * u + qi;
      float wgt = expf(pm[p] - mstar);
      lstar += wgt * pl[p];
      O += wgt * pO[(size_t)p * 64 + tid];
    }
    ds[tid] = O / lstar - mvg[b * DMODEL + h * HD + tid];
  }
  __syncthreads();
  float* row = x1 + ((size_t)(b * L + t)) * DMODEL;
  for (int nn = 0; nn < 2; nn++) {
    int n = tid + nn * 256;
    const float* wr = Wo + (size_t)n * 512 + h * HD;
    float a = 0.f;
#pragma unroll
    for (int k = 0; k < 64; k += 4) {
      float4 w4 = *(const float4*)(wr + k);
      a += ds[k] * w4.x + ds[k + 1] * w4.y + ds[k + 2] * w4.z + ds[k + 3] * w4.w;
    }
    atomicAdd(row + n, a);
  }
}

// ---------------------------------------------------------------- layernorm (512 cols; wave-shuffle reduce; optional hi/lo emit; optional bcast add)
template <int EMIT, int ADDB>
__global__ __launch_bounds__(256) void ln_kernel(const float* __restrict__ X,
                                                 const float* __restrict__ g,
                                                 const float* __restrict__ bta,
                                                 float* __restrict__ Y,
                                                 unsigned short* __restrict__ Hh,
                                                 unsigned short* __restrict__ Hl,
                                                 const float* __restrict__ mvW,
                                                 int Lr) {
  __shared__ float ws[4];
  __shared__ float ws2[4];
  int row = blockIdx.x, tid = threadIdx.x;
  int lane = tid & 63, w = tid >> 6;
  size_t base = (size_t)row * DMODEL;
  float x0 = X[base + tid], x1 = X[base + tid + 256];
  if (ADDB) {
    int b = row / Lr;
    x0 += mvW[b * DMODEL + tid];
    x1 += mvW[b * DMODEL + tid + 256];
  }
  float s = x0 + x1;
#pragma unroll
  for (int off = 32; off > 0; off >>= 1) s += __shfl_xor(s, off);
  if (lane == 0) ws[w] = s;
  __syncthreads();
  float mean = (ws[0] + ws[1] + ws[2] + ws[3]) * (1.0f / 512.0f);
  float d0 = x0 - mean, d1 = x1 - mean;
  float q = d0 * d0 + d1 * d1;
#pragma unroll
  for (int off = 32; off > 0; off >>= 1) q += __shfl_xor(q, off);
  if (lane == 0) ws2[w] = q;
  __syncthreads();
  float inv =
      1.0f / sqrtf((ws2[0] + ws2[1] + ws2[2] + ws2[3]) * (1.0f / 512.0f) + 1e-5f);
  float y0 = d0 * inv * g[tid] + bta[tid];
  float y1 = d1 * inv * g[tid + 256] + bta[tid + 256];
  Y[base + tid] = y0;
  Y[base + tid + 256] = y1;
  if (EMIT) {
    unsigned short h, l;
    f2hsplit(y0, h, l);
    Hh[base + tid] = h;
    Hl[base + tid] = l;
    f2hsplit(y1, h, l);
    Hh[base + tid + 256] = h;
    Hl[base + tid + 256] = l;
  }
}

// ---------------------------------------------------------------- combine K-split partials + residual + LN2, fused (per chunk)
template <int EMIT>
__global__ __launch_bounds__(256) void lncomb_kernel(
    const float* __restrict__ part, const float* __restrict__ bias,
    const float* __restrict__ resid, const float* __restrict__ g,
    const float* __restrict__ bta, float* __restrict__ Y,
    unsigned short* __restrict__ Hh, unsigned short* __restrict__ Hl, int r0,
    size_t MNc, int ks) {
  __shared__ float ws[4];
  __shared__ float ws2[4];
  int lrow = blockIdx.x, tid = threadIdx.x;
  int lane = tid & 63, w = tid >> 6;
  size_t lbase = (size_t)lrow * DMODEL;
  size_t gbase = (size_t)(r0 + lrow) * DMODEL;
  float x0 = 0.f, x1 = 0.f;
  for (int kb = 0; kb < ks; kb++) {
    x0 += part[kb * MNc + lbase + tid];
    x1 += part[kb * MNc + lbase + tid + 256];
  }
  x0 += bias[tid];
  x1 += bias[tid + 256];
  x0 += resid[gbase + tid];
  x1 += resid[gbase + tid + 256];
  float s = x0 + x1;
#pragma unroll
  for (int off = 32; off > 0; off >>= 1) s += __shfl_xor(s, off);
  if (lane == 0) ws[w] = s;
  __syncthreads();
  float mean = (ws[0] + ws[1] + ws[2] + ws[3]) * (1.0f / 512.0f);
  float d0 = x0 - mean, d1 = x1 - mean;
  float q = d0 * d0 + d1 * d1;
#pragma unroll
  for (int off = 32; off > 0; off >>= 1) q += __shfl_xor(q, off);
  if (lane == 0) ws2[w] = q;
  __syncthreads();
  float inv =
      1.0f / sqrtf((ws2[0] + ws2[1] + ws2[2] + ws2[3]) * (1.0f / 512.0f) + 1e-5f);
  float y0 = d0 * inv * g[tid] + bta[tid];
  float y1 = d1 * inv * g[tid + 256] + bta[tid + 256];
  if (EMIT) {
    unsigned short h, l;
    f2hsplit(y0, h, l);
    Hh[gbase + tid] = h;
    Hl[gbase + tid] = l;
    f2hsplit(y1, h, l);
    Hh[gbase + tid + 256] = h;
    Hl[gbase + tid + 256] = l;
  } else {
    Y[gbase + tid] = y0;
    Y[gbase + tid + 256] = y1;
  }
}

// ---------------------------------------------------------------- BN stats + pool
__global__ __launch_bounds__(256) void bnpart_kernel(const float* __restrict__ z,
                                                     float* __restrict__ psum,
                                                     float* __restrict__ psq,
                                                     int rowsPer) {
  int blk = blockIdx.x, tid = threadIdx.x;
  size_t r0 = (size_t)blk * rowsPer;
  float s0 = 0, q0 = 0, s1 = 0, q1 = 0;
  for (int r = 0; r < rowsPer; r++) {
    const float* zp = z + (r0 + r) * DMODEL;
    float a = zp[tid];
    s0 += a; q0 += a * a;
    float c = zp[tid + 256];
    s1 += c; q1 += c * c;
  }
  psum[blk * DMODEL + tid] = s0;
  psum[blk * DMODEL + tid + 256] = s1;
  psq[blk * DMODEL + tid] = q0;
  psq[blk * DMODEL + tid + 256] = q1;
}

__global__ void bnfin_kernel(const float* __restrict__ psum,
                             const float* __restrict__ psq, float* __restrict__ mu,
                             float* __restrict__ var, int nb, int Rtot) {
  int c = blockIdx.x * 256 + threadIdx.x;
  float s = 0, q = 0;
  for (int b = 0; b < nb; b++) {
    s += psum[b * DMODEL + c];
    q += psq[b * DMODEL + c];
  }
  float m = s / (float)Rtot;
  mu[c] = m;
  var[c] = fmaxf(q / (float)Rtot - m * m, 0.f);
}

template <int EMIT>
__global__ void bnpool_kernel(const float* __restrict__ z,
                              const float* __restrict__ mu,
                              const float* __restrict__ var,
                              const float* __restrict__ g,
                              const float* __restrict__ bta,
                              float* __restrict__ out,
                              unsigned short* __restrict__ Hh,
                              unsigned short* __restrict__ Hl, int L) {
  int gid = blockIdx.x * 256 + threadIdx.x;
  int c = gid & 511;
  int bt = gid >> 9;
  int L2 = L >> 1;
  int t2 = bt % L2, b = bt / L2;
  float m = mu[c];
  float inv = 1.0f / sqrtf(var[c] + 1e-5f);
  float gg = g[c], bb = bta[c];
  float best = -3.4e38f;
#pragma unroll
  for (int ww = 0; ww < 3; ww++) {
    int t = 2 * t2 - 1 + ww;
    if (t < 0 || t >= L) continue;
    float yv = (z[((size_t)(b * L + t)) * DMODEL + c] - m) * inv * gg + bb;
    yv = (yv > 0.f) ? yv : expm1f(yv);
    best = fmaxf(best, yv);
  }
  out[gid] = best;
  if (EMIT) {
    unsigned short h, l;
    f2hsplit(best, h, l);
    Hh[gid] = h;
    Hl[gid] = l;
  }
}

// ---------------------------------------------------------------- final LN + projection (512 -> 7), fused
__global__ __launch_bounds__(64) void end_kernel(const float* __restrict__ xn,
                                                 const float* __restrict__ lg,
                                                 const float* __restrict__ lb,
                                                 const float* __restrict__ ew,
                                                 const float* __restrict__ eb,
                                                 float* __restrict__ out) {
  __shared__ float xs[512];
  __shared__ float red[64];
  int row = blockIdx.x, tid = threadIdx.x;
  float s = 0.f;
#pragma unroll
  for (int i = 0; i < 8; i++) {
    float x = xn[(size_t)row * DMODEL + tid + 64 * i];
    xs[tid + 64 * i] = x;
    s += x;
  }
  red[tid] = s;
  __syncthreads();
  for (int st = 32; st > 0; st >>= 1) {
    if (tid < st) red[tid] += red[tid + st];
    __syncthreads();
  }
  float mean = red[0] * (1.0f / 512.0f);
  __syncthreads();
  float q = 0.f;
#pragma unroll
  for (int i = 0; i < 8; i++) {
    float d = xs[tid + 64 * i] - mean;
    q += d * d;
  }
  red[tid] = q;
  __syncthreads();
  for (int st = 32; st > 0; st >>= 1) {
    if (tid < st) red[tid] += red[tid + st];
    __syncthreads();
  }
  float inv = 1.0f / sqrtf(red[0] * (1.0f / 512.0f) + 1e-5f);
  __syncthreads();
#pragma unroll
  for (int i = 0; i < 8; i++) {
    int c = tid + 64 * i;
    xs[c] = (xs[c] - mean) * inv * lg[c] + lb[c];
  }
  __syncthreads();
  for (int c = 0; c < 7; c++) {
    float p = 0.f;
    for (int d = tid; d < 512; d += 64) p += xs[d] * ew[c * DMODEL + d];
    red[tid] = p;
    __syncthreads();
    for (int st = 32; st > 0; st >>= 1) {
      if (tid < st) red[tid] += red[tid + st];
      __syncthreads();
    }
    if (tid == 0) out[row * 7 + c] = red[0] + eb[c];
    __syncthreads();
  }
}

// ---------------------------------------------------------------- host
extern "C" void kernel_launch(void* const* d_in, const int* in_sizes, int n_in,
                              void* d_out, int out_size, void* d_ws,
                              size_t ws_size, hipStream_t stream) {
  (void)in_sizes; (void)n_in; (void)out_size;
  const float* x_enc = (const float*)d_in[0];
  const float* tok_w = (const float*)d_in[1];
  const float* Wq = (const float*)d_in[2];
  const float* bq = (const float*)d_in[3];
  const float* Wk = (const float*)d_in[4];
  const float* bk = (const float*)d_in[5];
  const float* Wv = (const float*)d_in[6];
  const float* bv = (const float*)d_in[7];
  const float* Wo = (const float*)d_in[8];
  const float* bo = (const float*)d_in[9];
  const float* w1 = (const float*)d_in[10];
  const float* b1 = (const float*)d_in[11];
  const float* w2 = (const float*)d_in[12];
  const float* b2 = (const float*)d_in[13];
  const float* g1 = (const float*)d_in[14];
  const float* be1 = (const float*)d_in[15];
  const float* g2 = (const float*)d_in[16];
  const float* be2 = (const float*)d_in[17];
  const float* dw = (const float*)d_in[18];
  const float* db = (const float*)d_in[19];
  const float* bng = (const float*)d_in[20];
  const float* bnb = (const float*)d_in[21];
  const float* lnfg = (const float*)d_in[22];
  const float* lnfb = (const float*)d_in[23];
  const float* endw = (const float*)d_in[24];
  const float* endb = (const float*)d_in[25];
  float* out = (float*)d_out;
  char* ws = (char*)d_ws;

  const int B = 8;
  const int S = 2048;
  const int Uarr[3] = {24, 21, 21};
  const int NCHMAX = 32;

  // ---- MFMA-path arena ----
  size_t o = 0;
  float* buf0 = (float*)(ws + o); o += (size_t)16384 * 512 * 4;
  float* qbuf = (float*)(ws + o); o += (size_t)16384 * 512 * 4;
  float* kbuf = (float*)(ws + o); o += (size_t)16384 * 512 * 4;
  float* Mb    = (float*)(ws + o); o += (size_t)64 * 2048 * 4;
  int*   idxb  = (int*)(ws + o);   o += (size_t)2048 * 24 * 4;
  int*   topb  = (int*)(ws + o);   o += 8192;
  float* qsel  = (float*)(ws + o); o += (size_t)64 * 24 * 64 * 4;
  float* mvg   = (float*)(ws + o); o += (size_t)8 * 512 * 4;
  float* mvWog = (float*)(ws + o); o += (size_t)8 * 512 * 4;
  float* psumx = (float*)(ws + o); o += (size_t)256 * 512 * 4;
  float* psum  = (float*)(ws + o); o += (size_t)128 * 512 * 4;
  float* psq   = (float*)(ws + o); o += (size_t)128 * 512 * 4;
  float* muv   = (float*)(ws + o); o += 2048;
  float* varv  = (float*)(ws + o); o += 2048;
  float* pmb   = (float*)(ws + o); o += (size_t)64 * NCHMAX * 24 * 4;
  float* plb   = (float*)(ws + o); o += (size_t)64 * NCHMAX * 24 * 4;
  float* pOb   = (float*)(ws + o); o += (size_t)64 * NCHMAX * 24 * 64 * 4;
  unsigned short* P1h = (unsigned short*)(ws + o); o += (size_t)16384 * 512 * 2;
  unsigned short* P1l = (unsigned short*)(ws + o); o += (size_t)16384 * 512 * 2;
  unsigned short* P2h = (unsigned short*)(ws + o); o += (size_t)16384 * 512 * 2;
  unsigned short* P2l = (unsigned short*)(ws + o); o += (size_t)16384 * 512 * 2;
  unsigned short* Wqkvh = (unsigned short*)(ws + o); o += (size_t)1536 * 512 * 2;
  unsigned short* Wqkvl = (unsigned short*)(ws + o); o += (size_t)1536 * 512 * 2;
  unsigned short* w1h = (unsigned short*)(ws + o); o += (size_t)2048 * 512 * 2;
  unsigned short* w1l = (unsigned short*)(ws + o); o += (size_t)2048 * 512 * 2;
  unsigned short* w2h = (unsigned short*)(ws + o); o += (size_t)512 * 2048 * 2;
  unsigned short* w2l = (unsigned short*)(ws + o); o += (size_t)512 * 2048 * 2;
  unsigned short* wph = (unsigned short*)(ws + o); o += (size_t)512 * 1536 * 2;
  unsigned short* wpl = (unsigned short*)(ws + o); o += (size_t)512 * 1536 * 2;
  const bool use_mfma = (ws_size >= o);
  float* vbuf = (float*)(ws + o); o += (size_t)16384 * 512 * 4;
  const bool fuseqkv = (ws_size >= o);
  unsigned short* CHh = (unsigned short*)(ws + o); o += (size_t)16384 * 2048 * 2;
  unsigned short* CHl = (unsigned short*)(ws + o); o += (size_t)16384 * 2048 * 2;
  const bool fullffn = (ws_size >= o);
  unsigned short* CHb0 = (unsigned short*)buf0;
  float* partmP1 = (float*)P1h;
  float* petab = (float*)pOb;  // 4MB <= pOb (12.6MB), dead at start

  if (use_mfma) {
    petab_kernel<<<S * DMODEL / 256, 256, 0, stream>>>(petab, S);
    tokpe_kernel<1, 1><<<B * S * DMODEL / 256, 256, 0, stream>>>(
        x_enc, tok_w, petab, buf0, P1h, P1l, S);
    int L = S;
    for (int l = 0; l < 3; l++) {
      int U = Uarr[l];
      int u = Uarr[l];
      int BL = B * L;
      int nty = BL >> 7;
      int nch = L >> 6;
      if (nch > NCHMAX) nch = NCHMAX;
      // all 5 weight conversions in one launch
      cvt5_kernel<<<1408, 256, 0, stream>>>(
          Wq + (size_t)l * 262144, Wk + (size_t)l * 262144,
          Wv + (size_t)l * 262144, w1 + (size_t)l * 1048576,
          w2 + (size_t)l * 1048576, Wqkvh, Wqkvl, w1h, w1l, w2h, w2l);
      if (fuseqkv) {
        gemm_mfma<0, 0, 0, 0, 1, 0><<<12 * nty, 256, 0, stream>>>(
            P1h, P1l, Wqkvh, Wqkvl, bq + l * 512, bk + l * 512, bv + l * 512,
            nullptr, qbuf, kbuf, vbuf, nullptr, nullptr, 1536, 512, 0, 12, nty,
            512);
      } else {
        idx_kernel<<<(L * U + 255) / 256, 256, 0, stream>>>(idxb, L * U, l, L - 1);
        gemm_mfma<0, 0, 0, 0, 0, 0><<<4 * nty, 256, 0, stream>>>(
            P1h, P1l, Wqkvh, Wqkvl, bq + l * 512, nullptr, nullptr, nullptr,
            qbuf, nullptr, nullptr, nullptr, nullptr, 512, 512, 0, 4, nty, 512);
        gemm_mfma<0, 0, 0, 0, 0, 0><<<4 * nty, 256, 0, stream>>>(
            P1h, P1l, Wqkvh + 262144, Wqkvl + 262144, bk + l * 512, nullptr,
            nullptr, nullptr, kbuf, nullptr, nullptr, nullptr, nullptr, 512,
            512, 0, 4, nty, 512);
      }
      mscore4_kernel<<<64 * (L >> 6), 256, 0, stream>>>(qbuf, kbuf, Mb, L, U, l);
      topk_kernel<<<64, 256, 0, stream>>>(Mb, topb, L, u);
      xmean32_kernel<<<256, 256, 0, stream>>>(buf0, psumx, L);
      mvmake1_kernel<<<64, 256, 0, stream>>>(psumx, Wv + (size_t)l * 262144,
                                             bv + l * 512, mvg, L, 32);
      mvmake2_kernel<<<64, 256, 0, stream>>>(mvg, Wo + (size_t)l * 262144,
                                             bo + l * 512, mvWog);
      if (fuseqkv) {
        attnflash_kernel<1><<<64 * nch, 256, 0, stream>>>(
            qbuf, topb, kbuf, vbuf, pmb, plb, pOb, L, u, nch);
      } else {
        gatherq_kernel<<<64 * u, 64, 0, stream>>>(qbuf, topb, qsel, L, u);
        gemm_mfma<0, 0, 0, 0, 0, 0><<<4 * nty, 256, 0, stream>>>(
            P1h, P1l, Wqkvh + 524288, Wqkvl + 524288, bv + l * 512, nullptr,
            nullptr, nullptr, qbuf, nullptr, nullptr, nullptr, nullptr, 512,
            512, 0, 4, nty, 512);
        attnflash_kernel<0><<<64 * nch, 256, 0, stream>>>(
            qsel, nullptr, kbuf, qbuf, pmb, plb, pOb, L, u, nch);
      }
      deltaWo_kernel<<<64 * u, 256, 0, stream>>>(pmb, plb, pOb, mvg, topb,
                                                 Wo + (size_t)l * 262144, buf0, L,
                                                 u, nch);
      ln_kernel<1, 1><<<BL, 256, 0, stream>>>(buf0, g1 + l * 512, be1 + l * 512,
                                              qbuf, P2h, P2l, mvWog, L);
      if (fullffn) {
        gemm_mfma<1, 0, 0, 1, 0, 0><<<16 * nty, 256, 0, stream>>>(
            P2h, P2l, w1h, w1l, b1 + l * 2048, nullptr, nullptr, nullptr,
            nullptr, nullptr, nullptr, CHh, CHl, 2048, 512, 0, 16, nty, 512);
        gemm_mfma<0, 1, 0, 0, 0, 0><<<4 * nty, 256, 0, stream>>>(
            CHh, CHl, w2h, w2l, b2 + l * 512, nullptr, nullptr, qbuf, kbuf,
            nullptr, nullptr, nullptr, nullptr, 512, 2048, 0, 4, nty, 2048);
        if (l < 2) {
          ln_kernel<1, 0><<<BL, 256, 0, stream>>>(kbuf, g2 + l * 512,
                                                  be2 + l * 512, buf0, P1h, P1l,
                                                  nullptr, 1);
        } else {
          ln_kernel<0, 0><<<BL, 256, 0, stream>>>(kbuf, g2 + l * 512,
                                                  be2 + l * 512, buf0, nullptr,
                                                  nullptr, nullptr, 1);
        }
      } else if (fuseqkv) {
        if (l < 2) {
          const int R = 8192;
          const int Rt = R >> 7;  // 64
          unsigned short* CHhp = (unsigned short*)vbuf;
          unsigned short* CHlp = (unsigned short*)kbuf;
          float* partp = buf0;
          for (int r0 = 0; r0 < BL; r0 += R) {
            gemm_mfma<1, 0, 0, 1, 0, 0><<<16 * Rt, 256, 0, stream>>>(
                P2h + (size_t)r0 * 512, P2l + (size_t)r0 * 512, w1h, w1l,
                b1 + l * 2048, nullptr, nullptr, nullptr, nullptr, nullptr,
                nullptr, CHhp, CHlp, 2048, 512, 0, 16, Rt, 512);
            gemm_mfma<0, 0, 0, 0, 0, 1><<<4 * Rt * 2, 256, 0, stream>>>(
                CHhp, CHlp, w2h, w2l, nullptr, nullptr, nullptr, nullptr, partp,
                nullptr, nullptr, nullptr, nullptr, 512, 2048, 0, 4, Rt, 1024);
            lncomb_kernel<1><<<R, 256, 0, stream>>>(
                partp, b2 + l * 512, qbuf, g2 + l * 512, be2 + l * 512, nullptr,
                P1h, P1l, r0, (size_t)R * 512, 2);
          }
        } else {
          unsigned short* CHhp = (unsigned short*)vbuf;
          unsigned short* CHlp = CHhp + (size_t)4096 * 2048;
          gemm_mfma<1, 0, 0, 1, 0, 0><<<16 * 32, 256, 0, stream>>>(
              P2h, P2l, w1h, w1l, b1 + l * 2048, nullptr, nullptr, nullptr,
              nullptr, nullptr, nullptr, CHhp, CHlp, 2048, 512, 0, 16, 32, 512);
          gemm_mfma<0, 0, 0, 0, 0, 1><<<4 * 32 * 4, 256, 0, stream>>>(
              CHhp, CHlp, w2h, w2l, nullptr, nullptr, nullptr, nullptr, kbuf,
              nullptr, nullptr, nullptr, nullptr, 512, 2048, 0, 4, 32, 512);
          lncomb_kernel<0><<<4096, 256, 0, stream>>>(
              kbuf, b2 + l * 512, qbuf, g2 + l * 512, be2 + l * 512, buf0,
              nullptr, nullptr, 0, (size_t)4096 * 512, 4);
        }
      } else {
        unsigned short* CHlch = CHb0 + (size_t)4096 * 2048;
        for (int r0 = 0; r0 < BL; r0 += 4096) {
          gemm_mfma<1, 0, 0, 1, 0, 0><<<16 * 32, 256, 0, stream>>>(
              P2h + (size_t)r0 * 512, P2l + (size_t)r0 * 512, w1h, w1l,
              b1 + l * 2048, nullptr, nullptr, nullptr, nullptr, nullptr,
              nullptr, CHb0, CHlch, 2048, 512, 0, 16, 32, 512);
          gemm_mfma<0, 0, 0, 0, 0, 1><<<4 * 32 * 4, 256, 0, stream>>>(
              CHb0, CHlch, w2h, w2l, nullptr, nullptr, nullptr, nullptr,
              partmP1, nullptr, nullptr, nullptr, nullptr, 512, 2048, 0, 4, 32,
              512);
          combine_kernel<1><<<4096 * 512 / 256, 256, 0, stream>>>(
              partmP1, b2 + l * 512, qbuf + (size_t)r0 * 512,
              kbuf + (size_t)r0 * 512, (size_t)4096 * 512, 4);
        }
        if (l < 2) {
          ln_kernel<1, 0><<<BL, 256, 0, stream>>>(kbuf, g2 + l * 512,
                                                  be2 + l * 512, buf0, P1h, P1l,
                                                  nullptr, 1);
        } else {
          ln_kernel<0, 0><<<BL, 256, 0, stream>>>(kbuf, g2 + l * 512,
                                                  be2 + l * 512, buf0, nullptr,
                                                  nullptr, nullptr, 1);
        }
      }
      if (l < 2) {
        packw2_kernel<<<512 * 1536 / 256, 256, 0, stream>>>(
            dw + (size_t)l * 512 * 512 * 3, wph, wpl);
        gemm_mfma<0, 0, 1, 0, 0, 0><<<4 * nty, 256, 0, stream>>>(
            P1h, P1l, wph, wpl, db + l * 512, nullptr, nullptr, nullptr, kbuf,
            nullptr, nullptr, nullptr, nullptr, 512, 1536, L - 1, 4, nty, 1536);
        int nb = BL / 128;
        bnpart_kernel<<<nb, 256, 0, stream>>>(kbuf, psum, psq, 128);
        bnfin_kernel<<<2, 256, 0, stream>>>(psum, psq, muv, varv, nb, BL);
        bnpool_kernel<1><<<(BL / 2) * 512 / 256, 256, 0, stream>>>(
            kbuf, muv, varv, bng + l * 512, bnb + l * 512, buf0, P1h, P1l, L);
        L >>= 1;
      }
    }
    int BL = B * L;  // 4096
    end_kernel<<<BL, 64, 0, stream>>>(buf0, lnfg, lnfb, endw, endb, out);
    return;
  }

  // ================= fallback: verified fp32 path =================
  {
    const int NCH = 8;
    size_t o2 = 0;
    float* buf0f = (float*)(ws + o2); o2 += (size_t)16384 * 512 * 4;
    float* qbuff = (float*)(ws + o2); o2 += (size_t)16384 * 512 * 4;
    float* kbuff = (float*)(ws + o2); o2 += (size_t)16384 * 512 * 4;
    float* wpack = (float*)(ws + o2); o2 += (size_t)512 * 1536 * 4;
    float* Mbf    = (float*)(ws + o2); o2 += (size_t)64 * 2048 * 4;
    int*   idxbf  = (int*)(ws + o2);   o2 += (size_t)2048 * 24 * 4;
    int*   topbf  = (int*)(ws + o2);   o2 += 8192;
    float* qself  = (float*)(ws + o2); o2 += (size_t)64 * 24 * 64 * 4;
    float* mvgf   = (float*)(ws + o2); o2 += (size_t)8 * 512 * 4;
    float* mvWogf = (float*)(ws + o2); o2 += (size_t)8 * 512 * 4;
    float* psumxf = (float*)(ws + o2); o2 += (size_t)64 * 512 * 4;
    float* psumf  = (float*)(ws + o2); o2 += (size_t)128 * 512 * 4;
    float* psqf   = (float*)(ws + o2); o2 += (size_t)128 * 512 * 4;
    float* muvf   = (float*)(ws + o2); o2 += 2048;
    float* varvf  = (float*)(ws + o2); o2 += 2048;
    float* pmbf   = (float*)(ws + o2); o2 += (size_t)64 * NCH * 24 * 4;
    float* plbf   = (float*)(ws + o2); o2 += (size_t)64 * NCH * 24 * 4;
    float* pObf   = (float*)(ws + o2); o2 += (size_t)64 * NCH * 24 * 64 * 4;
    float* partb  = (float*)(ws + o2); o2 += (size_t)4 * 4096 * 2048;
    const bool uks = (ws_size >= o2);

    tokpe_kernel<0, 0><<<B * S * DMODEL / 256, 256, 0, stream>>>(
        x_enc, tok_w, nullptr, buf0f, nullptr, nullptr, S);
    int L = S;
    for (int l = 0; l < 3; l++) {
      int U = Uarr[l];
      int u = U;
      int BL = B * L;
      int nty = BL / 128;
      size_t MN = (size_t)BL * 512;
      int gq = 4 * nty;
      int ksq = (gq >= 512 || !uks) ? 1 : (512 / gq);
      idx_kernel<<<(L * U + 255) / 256, 256, 0, stream>>>(idxbf, L * U, l, L - 1);
      if (ksq == 1) {
        gemm128<0, 0, 0, 0><<<gq, 256, 0, stream>>>(
            buf0f, Wq + (size_t)l * 262144, bq + l * 512, nullptr, qbuff, 512,
            512, 0, 4, nty, 512, 1);
        gemm128<0, 0, 0, 0><<<gq, 256, 0, stream>>>(
            buf0f, Wk + (size_t)l * 262144, bk + l * 512, nullptr, kbuff, 512,
            512, 0, 4, nty, 512, 1);
      } else {
        gemm128<0, 0, 0, 1><<<gq * ksq, 256, 0, stream>>>(
            buf0f, Wq + (size_t)l * 262144, nullptr, nullptr, partb, 512, 512, 0,
            4, nty, 512 / ksq, ksq);
        combine_kernel<0><<<(unsigned)(MN / 256), 256, 0, stream>>>(
            partb, bq + l * 512, nullptr, qbuff, MN, ksq);
        gemm128<0, 0, 0, 1><<<gq * ksq, 256, 0, stream>>>(
            buf0f, Wk + (size_t)l * 262144, nullptr, nullptr, partb, 512, 512, 0,
            4, nty, 512 / ksq, ksq);
        combine_kernel<0><<<(unsigned)(MN / 256), 256, 0, stream>>>(
            partb, bk + l * 512, nullptr, kbuff, MN, ksq);
      }
      mscore_kernel<<<8 * 8 * L / 256, 256, 0, stream>>>(qbuff, kbuff, idxbf, Mbf, L, U);
      topk_kernel<<<64, 256, 0, stream>>>(Mbf, topbf, L, u);
      gatherq_kernel<<<64 * u, 64, 0, stream>>>(qbuff, topbf, qself, L, u);
      xmean_kernel<<<64, 256, 0, stream>>>(buf0f, psumxf, L);
      mvmake_kernel<<<8, 256, 0, stream>>>(psumxf, Wv + (size_t)l * 262144,
                                           bv + l * 512, Wo + (size_t)l * 262144,
                                           bo + l * 512, mvgf, mvWogf, L);
      if (ksq == 1) {
        gemm128<0, 0, 0, 0><<<gq, 256, 0, stream>>>(
            buf0f, Wv + (size_t)l * 262144, bv + l * 512, nullptr, qbuff, 512,
            512, 0, 4, nty, 512, 1);
      } else {
        gemm128<0, 0, 0, 1><<<gq * ksq, 256, 0, stream>>>(
            buf0f, Wv + (size_t)l * 262144, nullptr, nullptr, partb, 512, 512, 0,
            4, nty, 512 / ksq, ksq);
        combine_kernel<0><<<(unsigned)(MN / 256), 256, 0, stream>>>(
            partb, bv + l * 512, nullptr, qbuff, MN, ksq);
      }
      attnflash_kernel<0><<<64 * NCH, 256, 0, stream>>>(
          qself, nullptr, kbuff, qbuff, pmbf, plbf, pObf, L, u, NCH);
      x1bcast_kernel<<<(unsigned)(MN / 256), 256, 0, stream>>>(buf0f, mvWogf, kbuff, L);
      deltaWo_kernel<<<64 * u, 256, 0, stream>>>(pmbf, plbf, pObf, mvgf, topbf,
                                                 Wo + (size_t)l * 262144, kbuff,
                                                 L, u, NCH);
      ln_kernel<0, 0><<<BL, 256, 0, stream>>>(kbuff, g1 + l * 512, be1 + l * 512,
                                              qbuff, nullptr, nullptr, nullptr, 1);
      for (int r0 = 0; r0 < BL; r0 += 4096) {
        gemm128<1, 0, 0, 0><<<16 * 32, 256, 0, stream>>>(
            qbuff + (size_t)r0 * 512, w1 + (size_t)l * 2048 * 512, b1 + l * 2048,
            nullptr, buf0f, 2048, 512, 0, 16, 32, 512, 1);
        if (uks) {
          gemm128<0, 0, 0, 1><<<4 * 32 * 4, 256, 0, stream>>>(
              buf0f, w2 + (size_t)l * 512 * 2048, nullptr, nullptr, partb, 512,
              2048, 0, 4, 32, 512, 4);
          combine_kernel<1><<<4096 * 512 / 256, 256, 0, stream>>>(
              partb, b2 + l * 512, qbuff + (size_t)r0 * 512,
              kbuff + (size_t)r0 * 512, (size_t)4096 * 512, 4);
        } else {
          gemm128<0, 1, 0, 0><<<4 * 32, 256, 0, stream>>>(
              buf0f, w2 + (size_t)l * 512 * 2048, b2 + l * 512,
              qbuff + (size_t)r0 * 512, kbuff + (size_t)r0 * 512, 512, 2048, 0,
              4, 32, 2048, 1);
        }
      }
      ln_kernel<0, 0><<<BL, 256, 0, stream>>>(kbuff, g2 + l * 512, be2 + l * 512,
                                              buf0f, nullptr, nullptr, nullptr, 1);

      if (l < 2) {
        packw_kernel<<<512 * 1536 / 256, 256, 0, stream>>>(
            dw + (size_t)l * 512 * 512 * 3, wpack);
        int ksc = (gq >= 512 || !uks) ? 1 : 2;
        if (ksc == 1) {
          gemm128<0, 0, 1, 0><<<gq, 256, 0, stream>>>(
              buf0f, wpack, db + l * 512, nullptr, kbuff, 512, 1536, L - 1, 4,
              nty, 1536, 1);
        } else {
          gemm128<0, 0, 1, 1><<<gq * 2, 256, 0, stream>>>(
              buf0f, wpack, nullptr, nullptr, partb, 512, 1536, L - 1, 4, nty,
              768, 2);
          combine_kernel<0><<<(unsigned)(MN / 256), 256, 0, stream>>>(
              partb, db + l * 512, nullptr, kbuff, MN, 2);
        }
        int nb = BL / 128;
        bnpart_kernel<<<nb, 256, 0, stream>>>(kbuff, psumf, psqf, 128);
        bnfin_kernel<<<2, 256, 0, stream>>>(psumf, psqf, muvf, varvf, nb, BL);
        bnpool_kernel<0><<<(BL / 2) * 512 / 256, 256, 0, stream>>>(
            kbuff, muvf, varvf, bng + l * 512, bnb + l * 512, buf0f, nullptr,
            nullptr, L);
        L >>= 1;
      }
    }
    int BL = B * L;
    end_kernel<<<BL, 64, 0, stream>>>(buf0f, lnfg, lnfb, endw, endb, out);
  }
}

// Round 10
// 1722.778 us; speedup vs baseline: 2.2424x; 1.0333x over previous
//
#include <hip/hip_runtime.h>
#include <cstdint>
#include <cstddef>

#define DMODEL 512
#define NHEAD 8
#define HD 64

typedef _Float16 half8 __attribute__((ext_vector_type(8)));
typedef float f32x4 __attribute__((ext_vector_type(4)));

// ---------------------------------------------------------------- threefry
__device__ __forceinline__ uint32_t rotl32(uint32_t x, int r) {
  return (x << r) | (x >> (32 - r));
}

__device__ __forceinline__ void tf_block(uint32_t k0, uint32_t k1,
                                         uint32_t& x0, uint32_t& x1) {
  uint32_t ks0 = k0, ks1 = k1, ks2 = k0 ^ k1 ^ 0x1BD11BDAu;
  x0 += ks0; x1 += ks1;
  x0 += x1; x1 = rotl32(x1, 13); x1 ^= x0;
  x0 += x1; x1 = rotl32(x1, 15); x1 ^= x0;
  x0 += x1; x1 = rotl32(x1, 26); x1 ^= x0;
  x0 += x1; x1 = rotl32(x1, 6);  x1 ^= x0;
  x0 += ks1; x1 += ks2 + 1u;
  x0 += x1; x1 = rotl32(x1, 17); x1 ^= x0;
  x0 += x1; x1 = rotl32(x1, 29); x1 ^= x0;
  x0 += x1; x1 = rotl32(x1, 16); x1 ^= x0;
  x0 += x1; x1 = rotl32(x1, 24); x1 ^= x0;
  x0 += ks2; x1 += ks0 + 2u;
  x0 += x1; x1 = rotl32(x1, 13); x1 ^= x0;
  x0 += x1; x1 = rotl32(x1, 15); x1 ^= x0;
  x0 += x1; x1 = rotl32(x1, 26); x1 ^= x0;
  x0 += x1; x1 = rotl32(x1, 6);  x1 ^= x0;
  x0 += ks0; x1 += ks1 + 3u;
  x0 += x1; x1 = rotl32(x1, 17); x1 ^= x0;
  x0 += x1; x1 = rotl32(x1, 29); x1 ^= x0;
  x0 += x1; x1 = rotl32(x1, 16); x1 ^= x0;
  x0 += x1; x1 = rotl32(x1, 24); x1 ^= x0;
  x0 += ks1; x1 += ks2 + 4u;
  x0 += x1; x1 = rotl32(x1, 13); x1 ^= x0;
  x0 += x1; x1 = rotl32(x1, 15); x1 ^= x0;
  x0 += x1; x1 = rotl32(x1, 26); x1 ^= x0;
  x0 += x1; x1 = rotl32(x1, 6);  x1 ^= x0;
  x0 += ks2; x1 += ks0 + 5u;
}

__global__ void idx_kernel(int* __restrict__ idxb, int n, int layer, int mask) {
  int e = blockIdx.x * 256 + threadIdx.x;
  if (e >= n) return;
  uint32_t f0 = 0u, f1 = (uint32_t)layer;
  tf_block(0u, 42u, f0, f1);
  uint32_t s0 = 0u, s1 = 1u;
  tf_block(f0, f1, s0, s1);
  uint32_t x0 = 0u, x1 = (uint32_t)e;
  tf_block(s0, s1, x0, x1);
  uint32_t bits = x0 ^ x1;
  idxb[e] = (int)(bits & (uint32_t)mask);
}

// ---------------------------------------------------------------- fp16 hi/lo split helpers
__device__ __forceinline__ void f2hsplit(float v, unsigned short& h,
                                         unsigned short& l) {
  _Float16 hh = (_Float16)v;          // RNE
  float r = v - (float)hh;            // exact
  _Float16 ll = (_Float16)r;
  h = __builtin_bit_cast(unsigned short, hh);
  l = __builtin_bit_cast(unsigned short, ll);
}

__device__ __forceinline__ float gelu_f(float v) {
  return 0.5f * v * (1.0f + erff(v * 0.7071067811865476f));
}

// address-space cast helpers for global_load_lds
#define AS1G(p) ((const __attribute__((address_space(1))) void*)(size_t)(p))
#define AS3L(p) ((__attribute__((address_space(3))) void*)(unsigned)(size_t)(p))
#define GLD16(g, l) __builtin_amdgcn_global_load_lds(AS1G(g), AS3L(l), 16, 0, 0)

// ---------------------------------------------------------------- fp32 -> fp16 hi/lo conversion
__device__ __forceinline__ void cvt_body(const float* __restrict__ X,
                                         unsigned short* __restrict__ H,
                                         unsigned short* __restrict__ Lo,
                                         int i) {
  const float4* xp = (const float4*)X + 2 * (size_t)i;
  float4 a = xp[0], b = xp[1];
  float v[8] = {a.x, a.y, a.z, a.w, b.x, b.y, b.z, b.w};
  unsigned hu[4], lu[4];
#pragma unroll
  for (int q = 0; q < 4; ++q) {
    unsigned short h0, l0, h1, l1;
    f2hsplit(v[2 * q], h0, l0);
    f2hsplit(v[2 * q + 1], h1, l1);
    hu[q] = (unsigned)h0 | ((unsigned)h1 << 16);
    lu[q] = (unsigned)l0 | ((unsigned)l1 << 16);
  }
  uint4 hv; hv.x = hu[0]; hv.y = hu[1]; hv.z = hu[2]; hv.w = hu[3];
  uint4 lv; lv.x = lu[0]; lv.y = lu[1]; lv.z = lu[2]; lv.w = lu[3];
  *(uint4*)(H + 8 * (size_t)i) = hv;
  *(uint4*)(Lo + 8 * (size_t)i) = lv;
}

__global__ __launch_bounds__(256) void cvt_kernel(const float* __restrict__ X,
                                                  unsigned short* __restrict__ H,
                                                  unsigned short* __restrict__ Lo,
                                                  int n8) {
  int i = blockIdx.x * 256 + threadIdx.x;
  if (i >= n8) return;
  cvt_body(X, H, Lo, i);
}

// merged per-layer weight conversion: Wq/Wk/Wv -> Wqkv (3x128 blocks),
// w1 (512), w2 (512) = 1408 blocks; if dw != nullptr, tail 3072 blocks do the
// conv-weight pack+split (wp[o][w*512+c] = dw[o][c][w]). Grid = 1408 or 4480.
__global__ __launch_bounds__(256) void cvt6_kernel(
    const float* __restrict__ Wq, const float* __restrict__ Wk,
    const float* __restrict__ Wv, const float* __restrict__ w1,
    const float* __restrict__ w2, const float* __restrict__ dw,
    unsigned short* __restrict__ Qh, unsigned short* __restrict__ Ql,
    unsigned short* __restrict__ w1h, unsigned short* __restrict__ w1l,
    unsigned short* __restrict__ w2h, unsigned short* __restrict__ w2l,
    unsigned short* __restrict__ wph, unsigned short* __restrict__ wpl) {
  int blk = blockIdx.x;
  if (blk >= 1408) {
    int gid = (blk - 1408) * 256 + threadIdx.x;  // 512*1536
    int o = gid / 1536;
    int kk = gid - o * 1536;
    int ww = kk / 512;
    int c = kk - ww * 512;
    float v = dw[((size_t)o * 512 + c) * 3 + ww];
    unsigned short h, l;
    f2hsplit(v, h, l);
    wph[gid] = h;
    wpl[gid] = l;
    return;
  }
  const float* src;
  unsigned short* H;
  unsigned short* Lo;
  int lb;
  if (blk < 384) {
    int wsel = blk >> 7;
    lb = blk & 127;
    src = (wsel == 0) ? Wq : (wsel == 1 ? Wk : Wv);
    H = Qh + (size_t)wsel * 262144;
    Lo = Ql + (size_t)wsel * 262144;
  } else if (blk < 896) {
    lb = blk - 384;
    src = w1; H = w1h; Lo = w1l;
  } else {
    lb = blk - 896;
    src = w2; H = w2h; Lo = w2l;
  }
  cvt_body(src, H, Lo, lb * 256 + threadIdx.x);
}

// ---------------------------------------------------------------- MFMA GEMM 128x128, split-fp16 3-product, BK=32
// __launch_bounds__(256,4): acc alone is 64 VGPRs; (256,5) -> spill (r5).
// LDS 32 KB. Swizzle: slot ^= (row>>1)&3 (conflict-free, r4 verified).
// PART: K-split partials (raw fp32, no bias/act) -> C + kb*M*N.
template <int ACT, int HASR, int CONV, int F16OUT, int QKV, int PART>
__global__ __launch_bounds__(256, 4) void gemm_mfma(
    const unsigned short* __restrict__ Ah, const unsigned short* __restrict__ Al,
    const unsigned short* __restrict__ Wh, const unsigned short* __restrict__ Wl,
    const float* __restrict__ bias, const float* __restrict__ bias2,
    const float* __restrict__ bias3, const float* __restrict__ Rres,
    float* __restrict__ C, float* __restrict__ C2, float* __restrict__ C3,
    unsigned short* __restrict__ Ch, unsigned short* __restrict__ Cl,
    int N, int K, int Lmask, int ntx, int nty, int kloop) {
  __shared__ __attribute__((aligned(16))) unsigned short AsH[4096];
  __shared__ __attribute__((aligned(16))) unsigned short AsL[4096];
  __shared__ __attribute__((aligned(16))) unsigned short WsH[4096];
  __shared__ __attribute__((aligned(16))) unsigned short WsL[4096];
  const int tid = threadIdx.x;
  int blk = blockIdx.x;
  int kb = 0;
  if (PART) {
    const int tiles = ntx * nty;
    kb = blk / tiles;
    blk -= kb * tiles;
  }
  const int koff = PART ? kb * kloop : 0;
  const int xcd = blk & 7;
  const int j = blk >> 3;
  const int jr = j / ntx;
  const int row_t = xcd * (nty >> 3) + jr;
  const int col_t = j - jr * ntx;
  const int row0 = row_t << 7, col0 = col_t << 7;
  const int lane = tid & 63;
  const int wv = tid >> 6;
  const int wr = wv >> 1, wc = wv & 1;  // wave's 64x64 quadrant
  const int srow = lane >> 2;                          // 0..15
  const int skoff = (((lane & 3) ^ ((lane >> 3) & 3)) << 3);
  const int l15 = lane & 15, lg = lane >> 4;
  const int slotx = ((lg ^ ((l15 >> 1) & 3)) << 4);
  int oa[4], ow[4];
#pragma unroll
  for (int t = 0; t < 4; ++t) {
    oa[t] = (((wr << 6) + (t << 4) + l15) << 6) + slotx;
    ow[t] = (((wc << 6) + (t << 4) + l15) << 6) + slotx;
  }
  f32x4 acc[4][4] = {};
  const int T = (PART ? kloop : K) >> 5;
  for (int it = 0; it < T; ++it) {
    const int k0 = koff + (it << 5);
    int wwin = 0, kc = k0;
    if (CONV) { wwin = k0 >> 9; kc = k0 & 511; }
#pragma unroll
    for (int g = 0; g < 2; ++g) {
      const int R0 = (wv << 5) + (g << 4);
      const int rr = R0 + srow;
      size_t aoff;
      if (CONV) {
        int t0 = row0 + rr;
        int tcv = t0 & Lmask, bb = t0 & ~Lmask;
        int src = bb | ((tcv - 1 + wwin) & Lmask);
        aoff = (size_t)src * 512 + (kc + skoff);
      } else {
        aoff = (size_t)(row0 + rr) * K + (k0 + skoff);
      }
      size_t woff = (size_t)(col0 + rr) * K + (k0 + skoff);
      GLD16(Ah + aoff, AsH + R0 * 32);
      GLD16(Al + aoff, AsL + R0 * 32);
      GLD16(Wh + woff, WsH + R0 * 32);
      GLD16(Wl + woff, WsL + R0 * 32);
    }
    __syncthreads();
    half8 fah[4], fal[4];
#pragma unroll
    for (int t = 0; t < 4; ++t) {
      fah[t] = *(const half8*)((const char*)AsH + oa[t]);
      fal[t] = *(const half8*)((const char*)AsL + oa[t]);
    }
#pragma unroll
    for (int ni = 0; ni < 4; ++ni) {
      half8 bh = *(const half8*)((const char*)WsH + ow[ni]);
      half8 bl = *(const half8*)((const char*)WsL + ow[ni]);
#pragma unroll
      for (int mi = 0; mi < 4; ++mi) {
        acc[mi][ni] = __builtin_amdgcn_mfma_f32_16x16x32_f16(
            fah[mi], bh, acc[mi][ni], 0, 0, 0);
        acc[mi][ni] = __builtin_amdgcn_mfma_f32_16x16x32_f16(
            fah[mi], bl, acc[mi][ni], 0, 0, 0);
        acc[mi][ni] = __builtin_amdgcn_mfma_f32_16x16x32_f16(
            fal[mi], bh, acc[mi][ni], 0, 0, 0);
      }
    }
    __syncthreads();
  }
  // epilogue: D lane mapping col=l15, row=lg*4+q
  if (PART) {
    float* Cp = C + (size_t)kb * ((size_t)(nty << 7)) * N;
#pragma unroll
    for (int mi = 0; mi < 4; ++mi)
#pragma unroll
      for (int q = 0; q < 4; ++q) {
        const int m = row0 + (wr << 6) + (mi << 4) + (lg << 2) + q;
#pragma unroll
        for (int ni = 0; ni < 4; ++ni) {
          const int col = col0 + (wc << 6) + (ni << 4) + l15;
          Cp[(size_t)m * N + col] = acc[mi][ni][q];
        }
      }
    return;
  }
  int cbase = col0;
  float* Cb = C;
  const float* bb = bias;
  if (QKV) {
    const int cb = col0 >> 9;
    cbase = col0 & 511;
    Cb = (cb == 0) ? C : ((cb == 1) ? C2 : C3);
    bb = (cb == 0) ? bias : ((cb == 1) ? bias2 : bias3);
  }
  const int OSTR = QKV ? 512 : N;
  float bsv[4];
#pragma unroll
  for (int ni = 0; ni < 4; ++ni)
    bsv[ni] = bb[cbase + (wc << 6) + (ni << 4) + l15];
#pragma unroll
  for (int mi = 0; mi < 4; ++mi) {
#pragma unroll
    for (int q = 0; q < 4; ++q) {
      const int m = row0 + (wr << 6) + (mi << 4) + (lg << 2) + q;
#pragma unroll
      for (int ni = 0; ni < 4; ++ni) {
        const int col = cbase + (wc << 6) + (ni << 4) + l15;
        float v = acc[mi][ni][q] + bsv[ni];
        if (HASR) v += Rres[(size_t)m * OSTR + col];
        if (ACT == 1) v = gelu_f(v);
        if (F16OUT) {
          unsigned short h, lo;
          f2hsplit(v, h, lo);
          Ch[(size_t)m * OSTR + col] = h;
          Cl[(size_t)m * OSTR + col] = lo;
        } else {
          Cb[(size_t)m * OSTR + col] = v;
        }
      }
    }
  }
}

// ---------------------------------------------------------------- fp32 GEMM (fallback path only)
template <int ACT, int HASR, int CONV, int PART>
__global__ __launch_bounds__(256, 2) void gemm128(
    const float* __restrict__ A, const float* __restrict__ W,
    const float* __restrict__ bias, const float* Rres, float* C,
    int N, int K, int Lmask, int ntx, int nty, int kloop, int ks) {
  __shared__ float As[16][140];
  __shared__ float Ws[16][140];
  const int tid = threadIdx.x;
  int blk = blockIdx.x;
  const int tiles = ntx * nty;
  int kb = 0;
  if (PART) { kb = blk / tiles; blk -= kb * tiles; }
  const int koff = kb * kloop;
  const int xcd = blk & 7;
  const int j = blk >> 3;
  const int jr = j / ntx;
  const int row_t = xcd * (nty >> 3) + jr;
  const int col_t = j - jr * ntx;
  const int row0 = row_t * 128, col0 = col_t * 128;

  const int ar = tid >> 1;
  const int ac = (tid & 1) << 3;
  const int arp = ar + ((ar >> 5) << 2);
  const int tx = tid & 15, ty = tid >> 4;
  const int wcol = tx * 8 + ((tx >> 2) << 2);
  const int acol = ty * 8 + ((ty >> 2) << 2);
  const int arow = row0 + ar;
  const float* Wp = W + (size_t)(col0 + ar) * K + koff + ac;
  const float* Ap = A + (size_t)arow * K + koff + ac;
  int tcv = 0, bbase = 0;
  if (CONV) { tcv = arow & Lmask; bbase = arow & ~Lmask; }
  float4 ra0, ra1, rw0, rw1;
  float acc[8][8] = {};
  const int T = kloop >> 4;

  {
    const float* ap;
    if (CONV) {
      int kabs = koff;
      int w = kabs >> 9;
      int src = bbase | ((tcv - 1 + w) & Lmask);
      ap = A + (size_t)src * 512 + (kabs & 511) + ac;
    } else {
      ap = Ap;
    }
    ra0 = *(const float4*)(ap);
    ra1 = *(const float4*)(ap + 4);
    rw0 = *(const float4*)(Wp);
    rw1 = *(const float4*)(Wp + 4);
  }

  for (int it = 0; it < T; ++it) {
#pragma unroll
    for (int q = 0; q < 4; q++) {
      As[ac + q][arp] = ((float*)&ra0)[q];
      As[ac + 4 + q][arp] = ((float*)&ra1)[q];
      Ws[ac + q][arp] = ((float*)&rw0)[q];
      Ws[ac + 4 + q][arp] = ((float*)&rw1)[q];
    }
    __syncthreads();
    if (it + 1 < T) {
      const int k0 = (it + 1) << 4;
      const float* ap;
      if (CONV) {
        int kabs = koff + k0;
        int w = kabs >> 9;
        int src = bbase | ((tcv - 1 + w) & Lmask);
        ap = A + (size_t)src * 512 + (kabs & 511) + ac;
      } else {
        ap = Ap + k0;
      }
      ra0 = *(const float4*)(ap);
      ra1 = *(const float4*)(ap + 4);
      rw0 = *(const float4*)(Wp + k0);
      rw1 = *(const float4*)(Wp + k0 + 4);
    }
#pragma unroll
    for (int k = 0; k < 16; k++) {
      float av[8], wvv[8];
      *(float4*)(av) = *(const float4*)&As[k][acol];
      *(float4*)(av + 4) = *(const float4*)&As[k][acol + 4];
      *(float4*)(wvv) = *(const float4*)&Ws[k][wcol];
      *(float4*)(wvv + 4) = *(const float4*)&Ws[k][wcol + 4];
#pragma unroll
      for (int i = 0; i < 8; i++)
#pragma unroll
        for (int q = 0; q < 8; q++) acc[i][q] += av[i] * wvv[q];
    }
    __syncthreads();
  }

  if (PART) {
    float* Cp = C + (size_t)kb * (nty << 7) * N;
#pragma unroll
    for (int i = 0; i < 8; i++) {
      const int m = row0 + ty * 8 + i;
      const int c0 = col0 + tx * 8;
      *(float4*)(Cp + (size_t)m * N + c0) = *(float4*)(&acc[i][0]);
      *(float4*)(Cp + (size_t)m * N + c0 + 4) = *(float4*)(&acc[i][4]);
    }
  } else {
#pragma unroll
    for (int i = 0; i < 8; i++) {
      const int m = row0 + ty * 8 + i;
      const int c0 = col0 + tx * 8;
      float vout[8];
#pragma unroll
      for (int q = 0; q < 8; q++) {
        float v = acc[i][q] + bias[c0 + q];
        if (HASR) v += Rres[(size_t)m * N + c0 + q];
        if (ACT == 1) v = gelu_f(v);
        vout[q] = v;
      }
      *(float4*)(C + (size_t)m * N + c0) = *(float4*)(vout);
      *(float4*)(C + (size_t)m * N + c0 + 4) = *(float4*)(vout + 4);
    }
  }
}

template <int HASR>
__global__ __launch_bounds__(256) void combine_kernel(
    const float* __restrict__ part, const float* __restrict__ bias,
    const float* Rres, float* __restrict__ Cout, size_t MN, int ks) {
  size_t gid = (size_t)blockIdx.x * 256 + threadIdx.x;
  int c = (int)(gid & 511);
  float v = 0.f;
  for (int kb = 0; kb < ks; kb++) v += part[kb * MN + gid];
  v += bias[c];
  if (HASR) v += Rres[gid];
  Cout[gid] = v;
}

// ---------------------------------------------------------------- positional-encoding table (batch-invariant)
__global__ void petab_kernel(float* __restrict__ pe, int S) {
  int gid = blockIdx.x * 256 + threadIdx.x;  // S*512
  int o = gid & 511;
  int t = gid >> 9;
  int i2 = o >> 1;
  float dv = expf((float)(2 * i2) * (-9.210340371976184f / 512.0f));
  float ang = (float)t * dv;
  pe[gid] = (o & 1) ? cosf(ang) : sinf(ang);
}

// ---------------------------------------------------------------- token conv + pos embed (+hi/lo)
template <int EMIT, int PE>
__global__ void tokpe_kernel(const float* __restrict__ xe,
                             const float* __restrict__ w,
                             const float* __restrict__ pe,
                             float* __restrict__ out,
                             unsigned short* __restrict__ Hh,
                             unsigned short* __restrict__ Hl, int S) {
  int gid = blockIdx.x * 256 + threadIdx.x;  // B*S*512
  int o = gid & 511;
  int bt = gid >> 9;
  int t = bt % S, b = bt / S;
  float acc = 0.f;
#pragma unroll
  for (int ww = 0; ww < 3; ww++) {
    int tt = t - 1 + ww;
    tt = (tt < 0) ? tt + S : (tt >= S ? tt - S : tt);
    const float* xr = xe + ((size_t)(b * S + tt)) * 7;
#pragma unroll
    for (int i = 0; i < 7; i++) acc += xr[i] * w[o * 21 + i * 3 + ww];
  }
  if (PE) {
    acc += pe[(t << 9) | o];
  } else {
    int i2 = o >> 1;
    float dv = expf((float)(2 * i2) * (-9.210340371976184f / 512.0f));
    float ang = (float)t * dv;
    acc += (o & 1) ? cosf(ang) : sinf(ang);
  }
  out[gid] = acc;
  if (EMIT) {
    unsigned short h, l;
    f2hsplit(acc, h, l);
    Hh[gid] = h;
    Hl[gid] = l;
  }
}

// ---------------------------------------------------------------- conv weight pack (fallback fp32)
__global__ void packw_kernel(const float* __restrict__ dw, float* __restrict__ wp) {
  int gid = blockIdx.x * 256 + threadIdx.x;  // 512*1536
  int o = gid / 1536;
  int kk = gid - o * 1536;
  int ww = kk / 512;
  int c = kk - ww * 512;
  wp[gid] = dw[((size_t)o * 512 + c) * 3 + ww];
}

// ---------------------------------------------------------------- M score, 4 lanes per query, threefry fused
__global__ __launch_bounds__(256) void mscore4_kernel(
    const float* __restrict__ Q, const float* __restrict__ Kb,
    float* __restrict__ Mout, int L, int U, int layer) {
  __shared__ int sidx[64 * 24];
  int i = blockIdx.x;  // b + 8*(h*chunks + c), 64 queries per block
  int b = i & 7;
  int j = i >> 3;
  int chunks = L >> 6;
  int h = j / chunks;
  int c = j - h * chunks;
  int t0 = c << 6;
  int tid = threadIdx.x;
  const int nidx = 64 * U;
  const int mask = L - 1;
  {
    uint32_t f0 = 0u, f1 = (uint32_t)layer;
    tf_block(0u, 42u, f0, f1);
    uint32_t s0 = 0u, s1 = 1u;
    tf_block(f0, f1, s0, s1);
    for (int k = tid; k < nidx; k += 256) {
      int e = t0 * U + k;
      uint32_t x0 = 0u, x1 = (uint32_t)e;
      tf_block(s0, s1, x0, x1);
      sidx[k] = (int)((x0 ^ x1) & (uint32_t)mask);
    }
  }
  __syncthreads();
  int tsub = tid >> 2, sub = tid & 3;
  int t = t0 + tsub;
  const float4* qr =
      (const float4*)(Q + ((size_t)(b * L + t)) * DMODEL + h * HD + sub * 16);
  float4 q0 = qr[0], q1 = qr[1], q2 = qr[2], q3 = qr[3];
  const float* Kh = Kb + (size_t)b * L * DMODEL + h * HD + sub * 16;
  float mx = -3.4e38f, sm = 0.f;
  int krn = sidx[tsub * U];
  for (int jj = 0; jj < U; ++jj) {
    const float4* kp = (const float4*)(Kh + (size_t)krn * DMODEL);
    krn = sidx[tsub * U + ((jj + 1 < U) ? jj + 1 : jj)];
    float4 k0 = kp[0], k1 = kp[1], k2 = kp[2], k3 = kp[3];
    float dot = q0.x * k0.x + q0.y * k0.y + q0.z * k0.z + q0.w * k0.w +
                q1.x * k1.x + q1.y * k1.y + q1.z * k1.z + q1.w * k1.w +
                q2.x * k2.x + q2.y * k2.y + q2.z * k2.z + q2.w * k2.w +
                q3.x * k3.x + q3.y * k3.y + q3.z * k3.z + q3.w * k3.w;
    dot += __shfl_xor(dot, 1);
    dot += __shfl_xor(dot, 2);
    mx = fmaxf(mx, dot);
    sm += dot;
  }
  if (sub == 0) Mout[(size_t)(b * 8 + h) * L + t] = mx - sm / (float)L;
}

// ---------------------------------------------------------------- M score (fallback)
__global__ __launch_bounds__(256) void mscore_kernel(
    const float* __restrict__ Q, const float* __restrict__ Kb,
    const int* __restrict__ idxb, float* __restrict__ Mout, int L, int U) {
  int i = blockIdx.x;
  int b = i & 7;
  int j = i >> 3;
  int chunks = L >> 8;
  int h = j / chunks;
  int c = j - h * chunks;
  int t = c * 256 + threadIdx.x;
  const float4* qr = (const float4*)(Q + ((size_t)(b * L + t)) * DMODEL + h * HD);
  float4 qv[16];
#pragma unroll
  for (int ii = 0; ii < 16; ii++) qv[ii] = qr[ii];
  float mx = -3.4e38f, sm = 0.f;
  for (int jj = 0; jj < U; jj++) {
    int kr = idxb[t * U + jj];
    const float4* kp =
        (const float4*)(Kb + ((size_t)(b * L + kr)) * DMODEL + h * HD);
    float dot = 0.f;
#pragma unroll
    for (int ii = 0; ii < 16; ii++) {
      float4 kv = kp[ii];
      dot += qv[ii].x * kv.x + qv[ii].y * kv.y + qv[ii].z * kv.z + qv[ii].w * kv.w;
    }
    mx = fmaxf(mx, dot);
    sm += dot;
  }
  Mout[(size_t)(b * 8 + h) * L + t] = mx - sm / (float)L;
}

// ---------------------------------------------------------------- top-k, single wave (no barriers)
// Selection identical to the 256-thread version: reduce by (max val, min idx);
// per-lane candidates are at lane+64*i (index increasing with i), so the first
// max occurrence per lane is its lowest index; cross-lane tie-break keeps the
// globally lowest index. Register-resident via compile-time CNT (rule #20).
template <int CNT>
__global__ __launch_bounds__(64) void topk64_kernel(const float* __restrict__ Mv,
                                                    int* __restrict__ topb,
                                                    int L, int u) {
  int bh = blockIdx.x;
  int lane = threadIdx.x;
  float lv[CNT];
#pragma unroll
  for (int i = 0; i < CNT; i++) lv[i] = Mv[(size_t)bh * L + i * 64 + lane];
  for (int r = 0; r < u; r++) {
    float bv = -3.4e38f;
    int bi = 0x7fffffff;
#pragma unroll
    for (int i = 0; i < CNT; i++) {
      if (lv[i] > bv) { bv = lv[i]; bi = i * 64 + lane; }
    }
#pragma unroll
    for (int s = 32; s > 0; s >>= 1) {
      float ov = __shfl_down(bv, s);
      int oi = __shfl_down(bi, s);
      if (ov > bv || (ov == bv && oi < bi)) { bv = ov; bi = oi; }
    }
    bi = __shfl(bi, 0);
    if (lane == 0) topb[bh * u + r] = bi;
#pragma unroll
    for (int i = 0; i < CNT; i++) {
      if (i * 64 + lane == bi) lv[i] = -3.4e38f;
    }
  }
}

// ---------------------------------------------------------------- top-k (fallback, 256-thread)
__global__ __launch_bounds__(256) void topk_kernel(const float* __restrict__ Mv,
                                                   int* __restrict__ topb, int L,
                                                   int u) {
  __shared__ float wv_s[4];
  __shared__ int wi_s[4];
  __shared__ int best_s;
  int bh = blockIdx.x, tid = threadIdx.x;
  int lane = tid & 63, w = tid >> 6;
  int cnt = L >> 8;
  float lv[8];
  for (int i = 0; i < cnt; i++) lv[i] = Mv[(size_t)bh * L + i * 256 + tid];
  for (int r = 0; r < u; r++) {
    float bv = -3.4e38f;
    int bi = 0x7fffffff;
    for (int i = 0; i < cnt; i++) {
      if (lv[i] > bv) { bv = lv[i]; bi = i * 256 + tid; }
    }
    for (int s = 32; s > 0; s >>= 1) {
      float ov = __shfl_down(bv, s);
      int oi = __shfl_down(bi, s);
      if (ov > bv || (ov == bv && oi < bi)) { bv = ov; bi = oi; }
    }
    if (lane == 0) { wv_s[w] = bv; wi_s[w] = bi; }
    __syncthreads();
    if (tid == 0) {
      float fv = wv_s[0];
      int fi = wi_s[0];
      for (int q = 1; q < 4; q++) {
        if (wv_s[q] > fv || (wv_s[q] == fv && wi_s[q] < fi)) {
          fv = wv_s[q];
          fi = wi_s[q];
        }
      }
      best_s = fi;
      topb[bh * u + r] = fi;
    }
    __syncthreads();
    int win = best_s;
    if ((win & 255) == tid) lv[win >> 8] = -3.4e38f;
  }
}

// ---------------------------------------------------------------- gather selected q rows (fallback paths)
__global__ void gatherq_kernel(const float* __restrict__ Q,
                               const int* __restrict__ topb,
                               float* __restrict__ qsel, int L, int u) {
  int i = blockIdx.x;
  int bh = i / u;
  int b = bh >> 3, h = bh & 7;
  int t = topb[i];
  qsel[i * HD + threadIdx.x] =
      Q[((size_t)(b * L + t)) * DMODEL + h * HD + threadIdx.x];
}

// ---------------------------------------------------------------- mean of x rows per batch
// 32 groups/batch -> grid 256 (MFMA path)
__global__ __launch_bounds__(256) void xmean32_kernel(const float* __restrict__ x,
                                                      float* __restrict__ psumx,
                                                      int L) {
  int i = blockIdx.x;  // 256: b*32+g
  int b = i >> 5, g = i & 31;
  int rows = L >> 5;
  int tid = threadIdx.x;
  const float* base = x + ((size_t)b * L + (size_t)g * rows) * DMODEL;
  float s0 = 0.f, s1 = 0.f;
  for (int t = 0; t < rows; t++) {
    s0 += base[(size_t)t * DMODEL + tid];
    s1 += base[(size_t)t * DMODEL + tid + 256];
  }
  psumx[i * DMODEL + tid] = s0;
  psumx[i * DMODEL + tid + 256] = s1;
}

// fallback: 8 groups/batch (grid 64)
__global__ __launch_bounds__(256) void xmean_kernel(const float* __restrict__ x,
                                                    float* __restrict__ psumx,
                                                    int L) {
  int i = blockIdx.x;
  int b = i >> 3, g = i & 7;
  int rows = L >> 3;
  int tid = threadIdx.x;
  const float* base = x + ((size_t)b * L + (size_t)g * rows) * DMODEL;
  float s0 = 0.f, s1 = 0.f;
  for (int t = 0; t < rows; t++) {
    s0 += base[(size_t)t * DMODEL + tid];
    s1 += base[(size_t)t * DMODEL + tid + 256];
  }
  psumx[i * DMODEL + tid] = s0;
  psumx[i * DMODEL + tid + 256] = s1;
}

// mv = xm@Wv^T + bv : grid 64 (8 b x 8 ngroups), 4 lanes per output
__global__ __launch_bounds__(256) void mvmake1_kernel(
    const float* __restrict__ psumx, const float* __restrict__ Wv,
    const float* __restrict__ bv, float* __restrict__ mvg, int L, int ng) {
  __shared__ float xm[512];
  int blk = blockIdx.x;
  int b = blk >> 3, grp = blk & 7;
  int tid = threadIdx.x;
  float inv = 1.0f / (float)L;
  for (int nn = 0; nn < 2; nn++) {
    int c = tid + nn * 256;
    float s = 0.f;
    for (int g = 0; g < ng; g++) s += psumx[(b * ng + g) * DMODEL + c];
    xm[c] = s * inv;
  }
  __syncthreads();
  int n = grp * 64 + (tid >> 2);
  int sub = tid & 3;
  const float* wr = Wv + (size_t)n * 512 + sub * 128;
  const float* xp = xm + sub * 128;
  float s = 0.f;
  for (int k = 0; k < 128; k += 4) {
    float4 w4 = *(const float4*)(wr + k);
    s += xp[k] * w4.x + xp[k + 1] * w4.y + xp[k + 2] * w4.z + xp[k + 3] * w4.w;
  }
  s += __shfl_xor(s, 1);
  s += __shfl_xor(s, 2);
  if (sub == 0) mvg[b * DMODEL + n] = s + bv[n];
}

// mvWo = mv@Wo^T + bo : grid 64
__global__ __launch_bounds__(256) void mvmake2_kernel(
    const float* __restrict__ mvg, const float* __restrict__ Wo,
    const float* __restrict__ bo, float* __restrict__ mvWog) {
  __shared__ float mv[512];
  int blk = blockIdx.x;
  int b = blk >> 3, grp = blk & 7;
  int tid = threadIdx.x;
  mv[tid] = mvg[b * DMODEL + tid];
  mv[tid + 256] = mvg[b * DMODEL + tid + 256];
  __syncthreads();
  int n = grp * 64 + (tid >> 2);
  int sub = tid & 3;
  const float* wr = Wo + (size_t)n * 512 + sub * 128;
  const float* xp = mv + sub * 128;
  float s = 0.f;
  for (int k = 0; k < 128; k += 4) {
    float4 w4 = *(const float4*)(wr + k);
    s += xp[k] * w4.x + xp[k + 1] * w4.y + xp[k + 2] * w4.z + xp[k + 3] * w4.w;
  }
  s += __shfl_xor(s, 1);
  s += __shfl_xor(s, 2);
  if (sub == 0) mvWog[b * DMODEL + n] = s + bo[n];
}

// fallback mvmake (8 blocks, original order)
__global__ __launch_bounds__(256) void mvmake_kernel(
    const float* __restrict__ psumx, const float* __restrict__ Wv,
    const float* __restrict__ bv, const float* __restrict__ Wo,
    const float* __restrict__ bo, float* __restrict__ mvg,
    float* __restrict__ mvWog, int L) {
  __shared__ float xm[512];
  __shared__ float mvs[512];
  int b = blockIdx.x, tid = threadIdx.x;
  float inv = 1.0f / (float)L;
  for (int nn = 0; nn < 2; nn++) {
    int c = tid + nn * 256;
    float s = 0.f;
    for (int g = 0; g < 8; g++) s += psumx[(b * 8 + g) * DMODEL + c];
    xm[c] = s * inv;
  }
  __syncthreads();
  for (int nn = 0; nn < 2; nn++) {
    int n = tid + nn * 256;
    const float* wr = Wv + (size_t)n * 512;
    float s = bv[n];
    for (int k = 0; k < 512; k += 4) {
      float4 w4 = *(const float4*)(wr + k);
      s += xm[k] * w4.x + xm[k + 1] * w4.y + xm[k + 2] * w4.z + xm[k + 3] * w4.w;
    }
    mvs[n] = s;
    mvg[b * DMODEL + n] = s;
  }
  __syncthreads();
  for (int nn = 0; nn < 2; nn++) {
    int n = tid + nn * 256;
    const float* wr = Wo + (size_t)n * 512;
    float s = bo[n];
    for (int k = 0; k < 512; k += 4) {
      float4 w4 = *(const float4*)(wr + k);
      s += mvs[k] * w4.x + mvs[k + 1] * w4.y + mvs[k + 2] * w4.z +
           mvs[k + 3] * w4.w;
    }
    mvWog[b * DMODEL + n] = s;
  }
}

__global__ void x1bcast_kernel(const float* __restrict__ x,
                               const float* __restrict__ mvWog,
                               float* __restrict__ x1, int L) {
  int gid = blockIdx.x * 256 + threadIdx.x;
  int c = gid & 511;
  int r = gid >> 9;
  int b = r / L;
  x1[gid] = x[gid] + mvWog[b * DMODEL + c];
}

// ---------------------------------------------------------------- chunked flash attention for selected rows
template <int GQ>
__global__ __launch_bounds__(256) void attnflash_kernel(
    const float* __restrict__ qsrc, const int* __restrict__ topb,
    const float* __restrict__ Kb, const float* __restrict__ Vb,
    float* __restrict__ pm, float* __restrict__ pl, float* __restrict__ pO,
    int L, int u, int nchunk) {
  __shared__ float qs[24][64];
  __shared__ float Kt[64][68];
  __shared__ float Ps[24][68];
  int blk = blockIdx.x;
  int bh = blk / nchunk;
  int c = blk - bh * nchunk;
  int b = bh >> 3, h = bh & 7;
  int cs = L / nchunk;
  int tid = threadIdx.x;
  int lane = tid & 63;
  int w = tid >> 6;
  if (GQ) {
    for (int i = tid; i < u * 64; i += 256) {
      int r = i >> 6, d = i & 63;
      int t = topb[bh * u + r];
      qs[r][d] = qsrc[((size_t)(b * L + t)) * DMODEL + h * HD + d];
    }
  } else {
    for (int i = tid; i < u * 64; i += 256)
      qs[i >> 6][i & 63] = qsrc[(size_t)bh * u * 64 + i];
  }
  float m[6], l[6], O[6];
#pragma unroll
  for (int k = 0; k < 6; k++) { m[k] = -3.4e38f; l[k] = 0.f; O[k] = 0.f; }
  const float* Kbase = Kb + (size_t)b * L * DMODEL + h * HD;
  const float* Vbase = Vb + (size_t)b * L * DMODEL + h * HD;
  const int jrow = tid & 63;
  const int dch = (tid >> 6) << 4;
  for (int j0 = c * cs; j0 < (c + 1) * cs; j0 += 64) {
    __syncthreads();
    const float* kr = Kbase + (size_t)(j0 + jrow) * DMODEL + dch;
    float4 k0 = *(const float4*)(kr);
    float4 k1 = *(const float4*)(kr + 4);
    float4 k2 = *(const float4*)(kr + 8);
    float4 k3 = *(const float4*)(kr + 12);
#pragma unroll
    for (int q = 0; q < 4; q++) {
      Kt[dch + q][jrow] = ((float*)&k0)[q];
      Kt[dch + 4 + q][jrow] = ((float*)&k1)[q];
      Kt[dch + 8 + q][jrow] = ((float*)&k2)[q];
      Kt[dch + 12 + q][jrow] = ((float*)&k3)[q];
    }
    __syncthreads();
#pragma unroll
    for (int k = 0; k < 6; k++) {
      int qi = 4 * k + w;
      if (qi >= u) break;
      float s = 0.f;
#pragma unroll
      for (int d = 0; d < 64; d++) s += qs[qi][d] * Kt[d][lane];
      s *= 0.125f;
      float mx = s;
#pragma unroll
      for (int off = 32; off > 0; off >>= 1)
        mx = fmaxf(mx, __shfl_down(mx, off));
      mx = __shfl(mx, 0);
      float mnew = fmaxf(m[k], mx);
      float p = expf(s - mnew);
      float ps = p;
#pragma unroll
      for (int off = 32; off > 0; off >>= 1) ps += __shfl_down(ps, off);
      ps = __shfl(ps, 0);
      float alpha = expf(m[k] - mnew);
      l[k] = l[k] * alpha + ps;
      m[k] = mnew;
      O[k] *= alpha;
      Ps[qi][lane] = p;
    }
    for (int jj = 0; jj < 64; jj += 4) {
      float v0 = Vbase[(size_t)(j0 + jj) * DMODEL + lane];
      float v1 = Vbase[(size_t)(j0 + jj + 1) * DMODEL + lane];
      float v2 = Vbase[(size_t)(j0 + jj + 2) * DMODEL + lane];
      float v3 = Vbase[(size_t)(j0 + jj + 3) * DMODEL + lane];
#pragma unroll
      for (int k = 0; k < 6; k++) {
        int qi = 4 * k + w;
        if (qi >= u) break;
        O[k] += Ps[qi][jj] * v0 + Ps[qi][jj + 1] * v1 + Ps[qi][jj + 2] * v2 +
                Ps[qi][jj + 3] * v3;
      }
    }
  }
#pragma unroll
  for (int k = 0; k < 6; k++) {
    int qi = 4 * k + w;
    if (qi < u) {
      int p = (bh * nchunk + c) * u + qi;
      if (lane == 0) { pm[p] = m[k]; pl[p] = l[k]; }
      pO[(size_t)p * 64 + lane] = O[k];
    }
  }
}

__global__ __launch_bounds__(256) void deltaWo_kernel(
    const float* __restrict__ pm, const float* __restrict__ pl,
    const float* __restrict__ pO, const float* __restrict__ mvg,
    const int* __restrict__ topb, const float* __restrict__ Wo, float* x1,
    int L, int u, int nchunk) {
  __shared__ float ds[64];
  int sel = blockIdx.x;
  int bh = sel / u;
  int qi = sel - bh * u;
  int b = bh >> 3, h = bh & 7;
  int t = topb[sel];
  int tid = threadIdx.x;
  if (tid < 64) {
    float mstar = -3.4e38f;
    for (int c = 0; c < nchunk; c++)
      mstar = fmaxf(mstar, pm[(bh * nchunk + c) * u + qi]);
    float lstar = 0.f, O = 0.f;
    for (int c = 0; c < nchunk; c++) {
      int p = (bh * nchunk + c) * u + qi;
      float wgt = expf(pm[p] - mstar);
      lstar += wgt * pl[p];
      O += wgt * pO[(size_t)p * 64 + tid];
    }
    ds[tid] = O / lstar - mvg[b * DMODEL + h * HD + tid];
  }
  __syncthreads();
  float* row = x1 + ((size_t)(b * L + t)) * DMODEL;
  for (int nn = 0; nn < 2; nn++) {
    int n = tid + nn * 256;
    const float* wr = Wo + (size_t)n * 512 + h * HD;
    float a = 0.f;
#pragma unroll
    for (int k = 0; k < 64; k += 4) {
      float4 w4 = *(const float4*)(wr + k);
      a += ds[k] * w4.x + ds[k + 1] * w4.y + ds[k + 2] * w4.z + ds[k + 3] * w4.w;
    }
    atomicAdd(row + n, a);
  }
}

// ---------------------------------------------------------------- layernorm (512 cols; wave-shuffle reduce; optional hi/lo emit; optional bcast add)
template <int EMIT, int ADDB>
__global__ __launch_bounds__(256) void ln_kernel(const float* __restrict__ X,
                                                 const float* __restrict__ g,
                                                 const float* __restrict__ bta,
                                                 float* __restrict__ Y,
                                                 unsigned short* __restrict__ Hh,
                                                 unsigned short* __restrict__ Hl,
                                                 const float* __restrict__ mvW,
                                                 int Lr) {
  __shared__ float ws[4];
  __shared__ float ws2[4];
  int row = blockIdx.x, tid = threadIdx.x;
  int lane = tid & 63, w = tid >> 6;
  size_t base = (size_t)row * DMODEL;
  float x0 = X[base + tid], x1 = X[base + tid + 256];
  if (ADDB) {
    int b = row / Lr;
    x0 += mvW[b * DMODEL + tid];
    x1 += mvW[b * DMODEL + tid + 256];
  }
  float s = x0 + x1;
#pragma unroll
  for (int off = 32; off > 0; off >>= 1) s += __shfl_xor(s, off);
  if (lane == 0) ws[w] = s;
  __syncthreads();
  float mean = (ws[0] + ws[1] + ws[2] + ws[3]) * (1.0f / 512.0f);
  float d0 = x0 - mean, d1 = x1 - mean;
  float q = d0 * d0 + d1 * d1;
#pragma unroll
  for (int off = 32; off > 0; off >>= 1) q += __shfl_xor(q, off);
  if (lane == 0) ws2[w] = q;
  __syncthreads();
  float inv =
      1.0f / sqrtf((ws2[0] + ws2[1] + ws2[2] + ws2[3]) * (1.0f / 512.0f) + 1e-5f);
  float y0 = d0 * inv * g[tid] + bta[tid];
  float y1 = d1 * inv * g[tid + 256] + bta[tid + 256];
  Y[base + tid] = y0;
  Y[base + tid + 256] = y1;
  if (EMIT) {
    unsigned short h, l;
    f2hsplit(y0, h, l);
    Hh[base + tid] = h;
    Hl[base + tid] = l;
    f2hsplit(y1, h, l);
    Hh[base + tid + 256] = h;
    Hl[base + tid + 256] = l;
  }
}

// ---------------------------------------------------------------- combine K-split partials + residual + LN2, fused (per chunk)
template <int EMIT>
__global__ __launch_bounds__(256) void lncomb_kernel(
    const float* __restrict__ part, const float* __restrict__ bias,
    const float* __restrict__ resid, const float* __restrict__ g,
    const float* __restrict__ bta, float* __restrict__ Y,
    unsigned short* __restrict__ Hh, unsigned short* __restrict__ Hl, int r0,
    size_t MNc, int ks) {
  __shared__ float ws[4];
  __shared__ float ws2[4];
  int lrow = blockIdx.x, tid = threadIdx.x;
  int lane = tid & 63, w = tid >> 6;
  size_t lbase = (size_t)lrow * DMODEL;
  size_t gbase = (size_t)(r0 + lrow) * DMODEL;
  float x0 = 0.f, x1 = 0.f;
  for (int kb = 0; kb < ks; kb++) {
    x0 += part[kb * MNc + lbase + tid];
    x1 += part[kb * MNc + lbase + tid + 256];
  }
  x0 += bias[tid];
  x1 += bias[tid + 256];
  x0 += resid[gbase + tid];
  x1 += resid[gbase + tid + 256];
  float s = x0 + x1;
#pragma unroll
  for (int off = 32; off > 0; off >>= 1) s += __shfl_xor(s, off);
  if (lane == 0) ws[w] = s;
  __syncthreads();
  float mean = (ws[0] + ws[1] + ws[2] + ws[3]) * (1.0f / 512.0f);
  float d0 = x0 - mean, d1 = x1 - mean;
  float q = d0 * d0 + d1 * d1;
#pragma unroll
  for (int off = 32; off > 0; off >>= 1) q += __shfl_xor(q, off);
  if (lane == 0) ws2[w] = q;
  __syncthreads();
  float inv =
      1.0f / sqrtf((ws2[0] + ws2[1] + ws2[2] + ws2[3]) * (1.0f / 512.0f) + 1e-5f);
  float y0 = d0 * inv * g[tid] + bta[tid];
  float y1 = d1 * inv * g[tid + 256] + bta[tid + 256];
  if (EMIT) {
    unsigned short h, l;
    f2hsplit(y0, h, l);
    Hh[gbase + tid] = h;
    Hl[gbase + tid] = l;
    f2hsplit(y1, h, l);
    Hh[gbase + tid + 256] = h;
    Hl[gbase + tid + 256] = l;
  } else {
    Y[gbase + tid] = y0;
    Y[gbase + tid + 256] = y1;
  }
}

// ---------------------------------------------------------------- BN stats + pool
__global__ __launch_bounds__(256) void bnpart_kernel(const float* __restrict__ z,
                                                     float* __restrict__ psum,
                                                     float* __restrict__ psq,
                                                     int rowsPer) {
  int blk = blockIdx.x, tid = threadIdx.x;
  size_t r0 = (size_t)blk * rowsPer;
  float s0 = 0, q0 = 0, s1 = 0, q1 = 0;
  for (int r = 0; r < rowsPer; r++) {
    const float* zp = z + (r0 + r) * DMODEL;
    float a = zp[tid];
    s0 += a; q0 += a * a;
    float c = zp[tid + 256];
    s1 += c; q1 += c * c;
  }
  psum[blk * DMODEL + tid] = s0;
  psum[blk * DMODEL + tid + 256] = s1;
  psq[blk * DMODEL + tid] = q0;
  psq[blk * DMODEL + tid + 256] = q1;
}

__global__ void bnfin_kernel(const float* __restrict__ psum,
                             const float* __restrict__ psq, float* __restrict__ mu,
                             float* __restrict__ var, int nb, int Rtot) {
  int c = blockIdx.x * 256 + threadIdx.x;
  float s = 0, q = 0;
  for (int b = 0; b < nb; b++) {
    s += psum[b * DMODEL + c];
    q += psq[b * DMODEL + c];
  }
  float m = s / (float)Rtot;
  mu[c] = m;
  var[c] = fmaxf(q / (float)Rtot - m * m, 0.f);
}

template <int EMIT>
__global__ void bnpool_kernel(const float* __restrict__ z,
                              const float* __restrict__ mu,
                              const float* __restrict__ var,
                              const float* __restrict__ g,
                              const float* __restrict__ bta,
                              float* __restrict__ out,
                              unsigned short* __restrict__ Hh,
                              unsigned short* __restrict__ Hl, int L) {
  int gid = blockIdx.x * 256 + threadIdx.x;
  int c = gid & 511;
  int bt = gid >> 9;
  int L2 = L >> 1;
  int t2 = bt % L2, b = bt / L2;
  float m = mu[c];
  float inv = 1.0f / sqrtf(var[c] + 1e-5f);
  float gg = g[c], bb = bta[c];
  float best = -3.4e38f;
#pragma unroll
  for (int ww = 0; ww < 3; ww++) {
    int t = 2 * t2 - 1 + ww;
    if (t < 0 || t >= L) continue;
    float yv = (z[((size_t)(b * L + t)) * DMODEL + c] - m) * inv * gg + bb;
    yv = (yv > 0.f) ? yv : expm1f(yv);
    best = fmaxf(best, yv);
  }
  out[gid] = best;
  if (EMIT) {
    unsigned short h, l;
    f2hsplit(best, h, l);
    Hh[gid] = h;
    Hl[gid] = l;
  }
}

// ---------------------------------------------------------------- final LN + projection (512 -> 7), fused
__global__ __launch_bounds__(64) void end_kernel(const float* __restrict__ xn,
                                                 const float* __restrict__ lg,
                                                 const float* __restrict__ lb,
                                                 const float* __restrict__ ew,
                                                 const float* __restrict__ eb,
                                                 float* __restrict__ out) {
  __shared__ float xs[512];
  __shared__ float red[64];
  int row = blockIdx.x, tid = threadIdx.x;
  float s = 0.f;
#pragma unroll
  for (int i = 0; i < 8; i++) {
    float x = xn[(size_t)row * DMODEL + tid + 64 * i];
    xs[tid + 64 * i] = x;
    s += x;
  }
  red[tid] = s;
  __syncthreads();
  for (int st = 32; st > 0; st >>= 1) {
    if (tid < st) red[tid] += red[tid + st];
    __syncthreads();
  }
  float mean = red[0] * (1.0f / 512.0f);
  __syncthreads();
  float q = 0.f;
#pragma unroll
  for (int i = 0; i < 8; i++) {
    float d = xs[tid + 64 * i] - mean;
    q += d * d;
  }
  red[tid] = q;
  __syncthreads();
  for (int st = 32; st > 0; st >>= 1) {
    if (tid < st) red[tid] += red[tid + st];
    __syncthreads();
  }
  float inv = 1.0f / sqrtf(red[0] * (1.0f / 512.0f) + 1e-5f);
  __syncthreads();
#pragma unroll
  for (int i = 0; i < 8; i++) {
    int c = tid + 64 * i;
    xs[c] = (xs[c] - mean) * inv * lg[c] + lb[c];
  }
  __syncthreads();
  for (int c = 0; c < 7; c++) {
    float p = 0.f;
    for (int d = tid; d < 512; d += 64) p += xs[d] * ew[c * DMODEL + d];
    red[tid] = p;
    __syncthreads();
    for (int st = 32; st > 0; st >>= 1) {
      if (tid < st) red[tid] += red[tid + st];
      __syncthreads();
    }
    if (tid == 0) out[row * 7 + c] = red[0] + eb[c];
    __syncthreads();
  }
}

// ---------------------------------------------------------------- host
extern "C" void kernel_launch(void* const* d_in, const int* in_sizes, int n_in,
                              void* d_out, int out_size, void* d_ws,
                              size_t ws_size, hipStream_t stream) {
  (void)in_sizes; (void)n_in; (void)out_size;
  const float* x_enc = (const float*)d_in[0];
  const float* tok_w = (const float*)d_in[1];
  const float* Wq = (const float*)d_in[2];
  const float* bq = (const float*)d_in[3];
  const float* Wk = (const float*)d_in[4];
  const float* bk = (const float*)d_in[5];
  const float* Wv = (const float*)d_in[6];
  const float* bv = (const float*)d_in[7];
  const float* Wo = (const float*)d_in[8];
  const float* bo = (const float*)d_in[9];
  const float* w1 = (const float*)d_in[10];
  const float* b1 = (const float*)d_in[11];
  const float* w2 = (const float*)d_in[12];
  const float* b2 = (const float*)d_in[13];
  const float* g1 = (const float*)d_in[14];
  const float* be1 = (const float*)d_in[15];
  const float* g2 = (const float*)d_in[16];
  const float* be2 = (const float*)d_in[17];
  const float* dw = (const float*)d_in[18];
  const float* db = (const float*)d_in[19];
  const float* bng = (const float*)d_in[20];
  const float* bnb = (const float*)d_in[21];
  const float* lnfg = (const float*)d_in[22];
  const float* lnfb = (const float*)d_in[23];
  const float* endw = (const float*)d_in[24];
  const float* endb = (const float*)d_in[25];
  float* out = (float*)d_out;
  char* ws = (char*)d_ws;

  const int B = 8;
  const int S = 2048;
  const int Uarr[3] = {24, 21, 21};
  const int NCHMAX = 32;

  // ---- MFMA-path arena ----
  size_t o = 0;
  float* buf0 = (float*)(ws + o); o += (size_t)16384 * 512 * 4;
  float* qbuf = (float*)(ws + o); o += (size_t)16384 * 512 * 4;
  float* kbuf = (float*)(ws + o); o += (size_t)16384 * 512 * 4;
  float* Mb    = (float*)(ws + o); o += (size_t)64 * 2048 * 4;
  int*   idxb  = (int*)(ws + o);   o += (size_t)2048 * 24 * 4;
  int*   topb  = (int*)(ws + o);   o += 8192;
  float* qsel  = (float*)(ws + o); o += (size_t)64 * 24 * 64 * 4;
  float* mvg   = (float*)(ws + o); o += (size_t)8 * 512 * 4;
  float* mvWog = (float*)(ws + o); o += (size_t)8 * 512 * 4;
  float* psumx = (float*)(ws + o); o += (size_t)256 * 512 * 4;
  float* psum  = (float*)(ws + o); o += (size_t)128 * 512 * 4;
  float* psq   = (float*)(ws + o); o += (size_t)128 * 512 * 4;
  float* muv   = (float*)(ws + o); o += 2048;
  float* varv  = (float*)(ws + o); o += 2048;
  float* pmb   = (float*)(ws + o); o += (size_t)64 * NCHMAX * 24 * 4;
  float* plb   = (float*)(ws + o); o += (size_t)64 * NCHMAX * 24 * 4;
  float* pOb   = (float*)(ws + o); o += (size_t)64 * NCHMAX * 24 * 64 * 4;
  unsigned short* P1h = (unsigned short*)(ws + o); o += (size_t)16384 * 512 * 2;
  unsigned short* P1l = (unsigned short*)(ws + o); o += (size_t)16384 * 512 * 2;
  unsigned short* P2h = (unsigned short*)(ws + o); o += (size_t)16384 * 512 * 2;
  unsigned short* P2l = (unsigned short*)(ws + o); o += (size_t)16384 * 512 * 2;
  unsigned short* Wqkvh = (unsigned short*)(ws + o); o += (size_t)1536 * 512 * 2;
  unsigned short* Wqkvl = (unsigned short*)(ws + o); o += (size_t)1536 * 512 * 2;
  unsigned short* w1h = (unsigned short*)(ws + o); o += (size_t)2048 * 512 * 2;
  unsigned short* w1l = (unsigned short*)(ws + o); o += (size_t)2048 * 512 * 2;
  unsigned short* w2h = (unsigned short*)(ws + o); o += (size_t)512 * 2048 * 2;
  unsigned short* w2l = (unsigned short*)(ws + o); o += (size_t)512 * 2048 * 2;
  unsigned short* wph = (unsigned short*)(ws + o); o += (size_t)512 * 1536 * 2;
  unsigned short* wpl = (unsigned short*)(ws + o); o += (size_t)512 * 1536 * 2;
  const bool use_mfma = (ws_size >= o);
  float* vbuf = (float*)(ws + o); o += (size_t)16384 * 512 * 4;
  const bool fuseqkv = (ws_size >= o);
  unsigned short* CHh = (unsigned short*)(ws + o); o += (size_t)16384 * 2048 * 2;
  unsigned short* CHl = (unsigned short*)(ws + o); o += (size_t)16384 * 2048 * 2;
  const bool fullffn = (ws_size >= o);
  unsigned short* CHb0 = (unsigned short*)buf0;
  float* partmP1 = (float*)P1h;
  float* petab = (float*)pOb;  // 4MB <= pOb (12.6MB), dead at start

  if (use_mfma) {
    petab_kernel<<<S * DMODEL / 256, 256, 0, stream>>>(petab, S);
    tokpe_kernel<1, 1><<<B * S * DMODEL / 256, 256, 0, stream>>>(
        x_enc, tok_w, petab, buf0, P1h, P1l, S);
    int L = S;
    for (int l = 0; l < 3; l++) {
      int U = Uarr[l];
      int u = Uarr[l];
      int BL = B * L;
      int nty = BL >> 7;
      int nch = L >> 6;
      if (nch > NCHMAX) nch = NCHMAX;
      // all weight conversions (+ conv pack for l<2) in one launch
      cvt6_kernel<<<(l < 2) ? 4480 : 1408, 256, 0, stream>>>(
          Wq + (size_t)l * 262144, Wk + (size_t)l * 262144,
          Wv + (size_t)l * 262144, w1 + (size_t)l * 1048576,
          w2 + (size_t)l * 1048576,
          (l < 2) ? (dw + (size_t)l * 512 * 512 * 3) : nullptr, Wqkvh, Wqkvl,
          w1h, w1l, w2h, w2l, wph, wpl);
      if (fuseqkv) {
        gemm_mfma<0, 0, 0, 0, 1, 0><<<12 * nty, 256, 0, stream>>>(
            P1h, P1l, Wqkvh, Wqkvl, bq + l * 512, bk + l * 512, bv + l * 512,
            nullptr, qbuf, kbuf, vbuf, nullptr, nullptr, 1536, 512, 0, 12, nty,
            512);
      } else {
        idx_kernel<<<(L * U + 255) / 256, 256, 0, stream>>>(idxb, L * U, l, L - 1);
        gemm_mfma<0, 0, 0, 0, 0, 0><<<4 * nty, 256, 0, stream>>>(
            P1h, P1l, Wqkvh, Wqkvl, bq + l * 512, nullptr, nullptr, nullptr,
            qbuf, nullptr, nullptr, nullptr, nullptr, 512, 512, 0, 4, nty, 512);
        gemm_mfma<0, 0, 0, 0, 0, 0><<<4 * nty, 256, 0, stream>>>(
            P1h, P1l, Wqkvh + 262144, Wqkvl + 262144, bk + l * 512, nullptr,
            nullptr, nullptr, kbuf, nullptr, nullptr, nullptr, nullptr, 512,
            512, 0, 4, nty, 512);
      }
      mscore4_kernel<<<64 * (L >> 6), 256, 0, stream>>>(qbuf, kbuf, Mb, L, U, l);
      if (L == 2048) {
        topk64_kernel<32><<<64, 64, 0, stream>>>(Mb, topb, L, u);
      } else if (L == 1024) {
        topk64_kernel<16><<<64, 64, 0, stream>>>(Mb, topb, L, u);
      } else {
        topk64_kernel<8><<<64, 64, 0, stream>>>(Mb, topb, L, u);
      }
      xmean32_kernel<<<256, 256, 0, stream>>>(buf0, psumx, L);
      mvmake1_kernel<<<64, 256, 0, stream>>>(psumx, Wv + (size_t)l * 262144,
                                             bv + l * 512, mvg, L, 32);
      mvmake2_kernel<<<64, 256, 0, stream>>>(mvg, Wo + (size_t)l * 262144,
                                             bo + l * 512, mvWog);
      if (fuseqkv) {
        attnflash_kernel<1><<<64 * nch, 256, 0, stream>>>(
            qbuf, topb, kbuf, vbuf, pmb, plb, pOb, L, u, nch);
      } else {
        gatherq_kernel<<<64 * u, 64, 0, stream>>>(qbuf, topb, qsel, L, u);
        gemm_mfma<0, 0, 0, 0, 0, 0><<<4 * nty, 256, 0, stream>>>(
            P1h, P1l, Wqkvh + 524288, Wqkvl + 524288, bv + l * 512, nullptr,
            nullptr, nullptr, qbuf, nullptr, nullptr, nullptr, nullptr, 512,
            512, 0, 4, nty, 512);
        attnflash_kernel<0><<<64 * nch, 256, 0, stream>>>(
            qsel, nullptr, kbuf, qbuf, pmb, plb, pOb, L, u, nch);
      }
      deltaWo_kernel<<<64 * u, 256, 0, stream>>>(pmb, plb, pOb, mvg, topb,
                                                 Wo + (size_t)l * 262144, buf0, L,
                                                 u, nch);
      ln_kernel<1, 1><<<BL, 256, 0, stream>>>(buf0, g1 + l * 512, be1 + l * 512,
                                              qbuf, P2h, P2l, mvWog, L);
      if (fullffn) {
        gemm_mfma<1, 0, 0, 1, 0, 0><<<16 * nty, 256, 0, stream>>>(
            P2h, P2l, w1h, w1l, b1 + l * 2048, nullptr, nullptr, nullptr,
            nullptr, nullptr, nullptr, CHh, CHl, 2048, 512, 0, 16, nty, 512);
        gemm_mfma<0, 1, 0, 0, 0, 0><<<4 * nty, 256, 0, stream>>>(
            CHh, CHl, w2h, w2l, b2 + l * 512, nullptr, nullptr, qbuf, kbuf,
            nullptr, nullptr, nullptr, nullptr, 512, 2048, 0, 4, nty, 2048);
        if (l < 2) {
          ln_kernel<1, 0><<<BL, 256, 0, stream>>>(kbuf, g2 + l * 512,
                                                  be2 + l * 512, buf0, P1h, P1l,
                                                  nullptr, 1);
        } else {
          ln_kernel<0, 0><<<BL, 256, 0, stream>>>(kbuf, g2 + l * 512,
                                                  be2 + l * 512, buf0, nullptr,
                                                  nullptr, nullptr, 1);
        }
      } else if (fuseqkv) {
        if (l < 2) {
          const int R = 8192;
          const int Rt = R >> 7;  // 64
          unsigned short* CHhp = (unsigned short*)vbuf;
          unsigned short* CHlp = (unsigned short*)kbuf;
          float* partp = buf0;
          for (int r0 = 0; r0 < BL; r0 += R) {
            gemm_mfma<1, 0, 0, 1, 0, 0><<<16 * Rt, 256, 0, stream>>>(
                P2h + (size_t)r0 * 512, P2l + (size_t)r0 * 512, w1h, w1l,
                b1 + l * 2048, nullptr, nullptr, nullptr, nullptr, nullptr,
                nullptr, CHhp, CHlp, 2048, 512, 0, 16, Rt, 512);
            gemm_mfma<0, 0, 0, 0, 0, 1><<<4 * Rt * 2, 256, 0, stream>>>(
                CHhp, CHlp, w2h, w2l, nullptr, nullptr, nullptr, nullptr, partp,
                nullptr, nullptr, nullptr, nullptr, 512, 2048, 0, 4, Rt, 1024);
            lncomb_kernel<1><<<R, 256, 0, stream>>>(
                partp, b2 + l * 512, qbuf, g2 + l * 512, be2 + l * 512, nullptr,
                P1h, P1l, r0, (size_t)R * 512, 2);
          }
        } else {
          unsigned short* CHhp = (unsigned short*)vbuf;
          unsigned short* CHlp = CHhp + (size_t)4096 * 2048;
          gemm_mfma<1, 0, 0, 1, 0, 0><<<16 * 32, 256, 0, stream>>>(
              P2h, P2l, w1h, w1l, b1 + l * 2048, nullptr, nullptr, nullptr,
              nullptr, nullptr, nullptr, CHhp, CHlp, 2048, 512, 0, 16, 32, 512);
          gemm_mfma<0, 0, 0, 0, 0, 1><<<4 * 32 * 4, 256, 0, stream>>>(
              CHhp, CHlp, w2h, w2l, nullptr, nullptr, nullptr, nullptr, kbuf,
              nullptr, nullptr, nullptr, nullptr, 512, 2048, 0, 4, 32, 512);
          lncomb_kernel<0><<<4096, 256, 0, stream>>>(
              kbuf, b2 + l * 512, qbuf, g2 + l * 512, be2 + l * 512, buf0,
              nullptr, nullptr, 0, (size_t)4096 * 512, 4);
        }
      } else {
        unsigned short* CHlch = CHb0 + (size_t)4096 * 2048;
        for (int r0 = 0; r0 < BL; r0 += 4096) {
          gemm_mfma<1, 0, 0, 1, 0, 0><<<16 * 32, 256, 0, stream>>>(
              P2h + (size_t)r0 * 512, P2l + (size_t)r0 * 512, w1h, w1l,
              b1 + l * 2048, nullptr, nullptr, nullptr, nullptr, nullptr,
              nullptr, CHb0, CHlch, 2048, 512, 0, 16, 32, 512);
          gemm_mfma<0, 0, 0, 0, 0, 1><<<4 * 32 * 4, 256, 0, stream>>>(
              CHb0, CHlch, w2h, w2l, nullptr, nullptr, nullptr, nullptr,
              partmP1, nullptr, nullptr, nullptr, nullptr, 512, 2048, 0, 4, 32,
              512);
          combine_kernel<1><<<4096 * 512 / 256, 256, 0, stream>>>(
              partmP1, b2 + l * 512, qbuf + (size_t)r0 * 512,
              kbuf + (size_t)r0 * 512, (size_t)4096 * 512, 4);
        }
        if (l < 2) {
          ln_kernel<1, 0><<<BL, 256, 0, stream>>>(kbuf, g2 + l * 512,
                                                  be2 + l * 512, buf0, P1h, P1l,
                                                  nullptr, 1);
        } else {
          ln_kernel<0, 0><<<BL, 256, 0, stream>>>(kbuf, g2 + l * 512,
                                                  be2 + l * 512, buf0, nullptr,
                                                  nullptr, nullptr, 1);
        }
      }
      if (l < 2) {
        gemm_mfma<0, 0, 1, 0, 0, 0><<<4 * nty, 256, 0, stream>>>(
            P1h, P1l, wph, wpl, db + l * 512, nullptr, nullptr, nullptr, kbuf,
            nullptr, nullptr, nullptr, nullptr, 512, 1536, L - 1, 4, nty, 1536);
        int nb = BL / 128;
        bnpart_kernel<<<nb, 256, 0, stream>>>(kbuf, psum, psq, 128);
        bnfin_kernel<<<2, 256, 0, stream>>>(psum, psq, muv, varv, nb, BL);
        bnpool_kernel<1><<<(BL / 2) * 512 / 256, 256, 0, stream>>>(
            kbuf, muv, varv, bng + l * 512, bnb + l * 512, buf0, P1h, P1l, L);
        L >>= 1;
      }
    }
    int BL = B * L;  // 4096
    end_kernel<<<BL, 64, 0, stream>>>(buf0, lnfg, lnfb, endw, endb, out);
    return;
  }

  // ================= fallback: verified fp32 path =================
  {
    const int NCH = 8;
    size_t o2 = 0;
    float* buf0f = (float*)(ws + o2); o2 += (size_t)16384 * 512 * 4;
    float* qbuff = (float*)(ws + o2); o2 += (size_t)16384 * 512 * 4;
    float* kbuff = (float*)(ws + o2); o2 += (size_t)16384 * 512 * 4;
    float* wpack = (float*)(ws + o2); o2 += (size_t)512 * 1536 * 4;
    float* Mbf    = (float*)(ws + o2); o2 += (size_t)64 * 2048 * 4;
    int*   idxbf  = (int*)(ws + o2);   o2 += (size_t)2048 * 24 * 4;
    int*   topbf  = (int*)(ws + o2);   o2 += 8192;
    float* qself  = (float*)(ws + o2); o2 += (size_t)64 * 24 * 64 * 4;
    float* mvgf   = (float*)(ws + o2); o2 += (size_t)8 * 512 * 4;
    float* mvWogf = (float*)(ws + o2); o2 += (size_t)8 * 512 * 4;
    float* psumxf = (float*)(ws + o2); o2 += (size_t)64 * 512 * 4;
    float* psumf  = (float*)(ws + o2); o2 += (size_t)128 * 512 * 4;
    float* psqf   = (float*)(ws + o2); o2 += (size_t)128 * 512 * 4;
    float* muvf   = (float*)(ws + o2); o2 += 2048;
    float* varvf  = (float*)(ws + o2); o2 += 2048;
    float* pmbf   = (float*)(ws + o2); o2 += (size_t)64 * NCH * 24 * 4;
    float* plbf   = (float*)(ws + o2); o2 += (size_t)64 * NCH * 24 * 4;
    float* pObf   = (float*)(ws + o2); o2 += (size_t)64 * NCH * 24 * 64 * 4;
    float* partb  = (float*)(ws + o2); o2 += (size_t)4 * 4096 * 2048;
    const bool uks = (ws_size >= o2);

    tokpe_kernel<0, 0><<<B * S * DMODEL / 256, 256, 0, stream>>>(
        x_enc, tok_w, nullptr, buf0f, nullptr, nullptr, S);
    int L = S;
    for (int l = 0; l < 3; l++) {
      int U = Uarr[l];
      int u = U;
      int BL = B * L;
      int nty = BL / 128;
      size_t MN = (size_t)BL * 512;
      int gq = 4 * nty;
      int ksq = (gq >= 512 || !uks) ? 1 : (512 / gq);
      idx_kernel<<<(L * U + 255) / 256, 256, 0, stream>>>(idxbf, L * U, l, L - 1);
      if (ksq == 1) {
        gemm128<0, 0, 0, 0><<<gq, 256, 0, stream>>>(
            buf0f, Wq + (size_t)l * 262144, bq + l * 512, nullptr, qbuff, 512,
            512, 0, 4, nty, 512, 1);
        gemm128<0, 0, 0, 0><<<gq, 256, 0, stream>>>(
            buf0f, Wk + (size_t)l * 262144, bk + l * 512, nullptr, kbuff, 512,
            512, 0, 4, nty, 512, 1);
      } else {
        gemm128<0, 0, 0, 1><<<gq * ksq, 256, 0, stream>>>(
            buf0f, Wq + (size_t)l * 262144, nullptr, nullptr, partb, 512, 512, 0,
            4, nty, 512 / ksq, ksq);
        combine_kernel<0><<<(unsigned)(MN / 256), 256, 0, stream>>>(
            partb, bq + l * 512, nullptr, qbuff, MN, ksq);
        gemm128<0, 0, 0, 1><<<gq * ksq, 256, 0, stream>>>(
            buf0f, Wk + (size_t)l * 262144, nullptr, nullptr, partb, 512, 512, 0,
            4, nty, 512 / ksq, ksq);
        combine_kernel<0><<<(unsigned)(MN / 256), 256, 0, stream>>>(
            partb, bk + l * 512, nullptr, kbuff, MN, ksq);
      }
      mscore_kernel<<<8 * 8 * L / 256, 256, 0, stream>>>(qbuff, kbuff, idxbf, Mbf, L, U);
      topk_kernel<<<64, 256, 0, stream>>>(Mbf, topbf, L, u);
      gatherq_kernel<<<64 * u, 64, 0, stream>>>(qbuff, topbf, qself, L, u);
      xmean_kernel<<<64, 256, 0, stream>>>(buf0f, psumxf, L);
      mvmake_kernel<<<8, 256, 0, stream>>>(psumxf, Wv + (size_t)l * 262144,
                                           bv + l * 512, Wo + (size_t)l * 262144,
                                           bo + l * 512, mvgf, mvWogf, L);
      if (ksq == 1) {
        gemm128<0, 0, 0, 0><<<gq, 256, 0, stream>>>(
            buf0f, Wv + (size_t)l * 262144, bv + l * 512, nullptr, qbuff, 512,
            512, 0, 4, nty, 512, 1);
      } else {
        gemm128<0, 0, 0, 1><<<gq * ksq, 256, 0, stream>>>(
            buf0f, Wv + (size_t)l * 262144, nullptr, nullptr, partb, 512, 512, 0,
            4, nty, 512 / ksq, ksq);
        combine_kernel<0><<<(unsigned)(MN / 256), 256, 0, stream>>>(
            partb, bv + l * 512, nullptr, qbuff, MN, ksq);
      }
      attnflash_kernel<0><<<64 * NCH, 256, 0, stream>>>(
          qself, nullptr, kbuff, qbuff, pmbf, plbf, pObf, L, u, NCH);
      x1bcast_kernel<<<(unsigned)(MN / 256), 256, 0, stream>>>(buf0f, mvWogf, kbuff, L);
      deltaWo_kernel<<<64 * u, 256, 0, stream>>>(pmbf, plbf, pObf, mvgf, topbf,
                                                 Wo + (size_t)l * 262144, kbuff,
                                                 L, u, NCH);
      ln_kernel<0, 0><<<BL, 256, 0, stream>>>(kbuff, g1 + l * 512, be1 + l * 512,
                                              qbuff, nullptr, nullptr, nullptr, 1);
      for (int r0 = 0; r0 < BL; r0 += 4096) {
        gemm128<1, 0, 0, 0><<<16 * 32, 256, 0, stream>>>(
            qbuff + (size_t)r0 * 512, w1 + (size_t)l * 2048 * 512, b1 + l * 2048,
            nullptr, buf0f, 2048, 512, 0, 16, 32, 512, 1);
        if (uks) {
          gemm128<0, 0, 0, 1><<<4 * 32 * 4, 256, 0, stream>>>(
              buf0f, w2 + (size_t)l * 512 * 2048, nullptr, nullptr, partb, 512,
              2048, 0, 4, 32, 512, 4);
          combine_kernel<1><<<4096 * 512 / 256, 256, 0, stream>>>(
              partb, b2 + l * 512, qbuff + (size_t)r0 * 512,
              kbuff + (size_t)r0 * 512, (size_t)4096 * 512, 4);
        } else {
          gemm128<0, 1, 0, 0><<<4 * 32, 256, 0, stream>>>(
              buf0f, w2 + (size_t)l * 512 * 2048, b2 + l * 512,
              qbuff + (size_t)r0 * 512, kbuff + (size_t)r0 * 512, 512, 2048, 0,
              4, 32, 2048, 1);
        }
      }
      ln_kernel<0, 0><<<BL, 256, 0, stream>>>(kbuff, g2 + l * 512, be2 + l * 512,
                                              buf0f, nullptr, nullptr, nullptr, 1);

      if (l < 2) {
        packw_kernel<<<512 * 1536 / 256, 256, 0, stream>>>(
            dw + (size_t)l * 512 * 512 * 3, wpack);
        int ksc = (gq >= 512 || !uks) ? 1 : 2;
        if (ksc == 1) {
          gemm128<0, 0, 1, 0><<<gq, 256, 0, stream>>>(
              buf0f, wpack, db + l * 512, nullptr, kbuff, 512, 1536, L - 1, 4,
              nty, 1536, 1);
        } else {
          gemm128<0, 0, 1, 1><<<gq * 2, 256, 0, stream>>>(
              buf0f, wpack, nullptr, nullptr, partb, 512, 1536, L - 1, 4, nty,
              768, 2);
          combine_kernel<0><<<(unsigned)(MN / 256), 256, 0, stream>>>(
              partb, db + l * 512, nullptr, kbuff, MN, 2);
        }
        int nb = BL / 128;
        bnpart_kernel<<<nb, 256, 0, stream>>>(kbuff, psumf, psqf, 128);
        bnfin_kernel<<<2, 256, 0, stream>>>(psumf, psqf, muvf, varvf, nb, BL);
        bnpool_kernel<0><<<(BL / 2) * 512 / 256, 256, 0, stream>>>(
            kbuff, muvf, varvf, bng + l * 512, bnb + l * 512, buf0f, nullptr,
            nullptr, L);
        L >>= 1;
      }
    }
    int BL = B * L;
    end_kernel<<<BL, 64, 0, stream>>>(buf0f, lnfg, lnfb, endw, endb, out);
  }
}